// Round 6
// baseline (619.764 us; speedup 1.0000x reference)
//
#include <hip/hip_runtime.h>
#include <hip/hip_bf16.h>
#include <hip/hip_fp16.h>

// ---------------- problem constants ----------------
#define BB 32
#define NN 20
#define TT 100
#define DD 4
#define HH 128
#define EE 380          // N*(N-1)
#define BE 12160        // B*E
#define L1 96           // conv1 out length
#define LP 48           // after maxpool
#define L2 44           // conv2 out length
#define NOUT 16
#define EPS 1e-5f
#define NREP 64         // stats replicas (atomic de-contention)

typedef _Float16 f16x8 __attribute__((ext_vector_type(8)));
typedef _Float16 f16x4 __attribute__((ext_vector_type(4)));
typedef _Float16 f16x2 __attribute__((ext_vector_type(2)));
typedef float f32x4 __attribute__((ext_vector_type(4)));

// stats slot indices (floats): SC at base, SH at base+128. Slots 0..127 = conv2 bias2 (BN1-fold).
#define S_BIAS2 0
#define S_BN1_SC 256
#define S_BN2_SC 768
#define S_AW2 1280      // aw2[c] = bn2_sc[c]*att_w[c]
#define S_PB2 1536      // pb2[o] = (pred_b[o] + sum_c pred_w[o][c]*bn2_sh[c]) / 44

// workspace offsets (bytes)
#define OFF_STATS 0ULL
#define OFF_SIDX 16384ULL
#define OFF_RIDX 18432ULL
#define OFF_INC 20480ULL
#define OFF_Y23 24576ULL                     // f16 [BE] slots of 6144: y2pre [48][128] then y3 t-major [44][128]
#define OFF_X 149446656ULL                   // f32 [BE][128]  (now holds pr = raw attention-pooled y3)
#define OFF_BUFA 155672576ULL                // f32 [BE][128]; rep1/rep2 live here during conv phase
#define OFF_BUFB 161898496ULL                // f32 [BE][128]
#define OFF_XN 168124416ULL                  // f32 [640][128]
#define OFF_T640 168452096ULL                // conv-phase: apack(160K)+apack1(16K)+pwt/mpred(64K)+w2sum(64K)
#define OFF_REPM 168779776ULL                // f32 3x[64][256] MLP stats replicas (repm1/repm2/repm3)
#define OFF_MP 171958272ULL                  // f16 MLP weight packs (256 KB)
#define OFF_APACK OFF_T640
#define OFF_APACK1 (OFF_T640 + 163840ULL)
#define OFF_PWT (OFF_T640 + 180224ULL)       // reused post-BN2 as mpred (f16 pred-weight pack, 32KB)
#define OFF_W2SUM (OFF_T640 + 245760ULL)
#define OFF_REP1 OFF_BUFA
#define OFF_REP2 (OFF_BUFA + 65536ULL)
// MP pack offsets in f16 units
#define MP_M1W1 0
#define MP_M1W2 16384
#define MP_M2W1 32768
#define MP_M2W2 49152
#define MP_M3W2 65536
#define MP_M3W1 81920

__device__ __forceinline__ float eluf(float v) { return v > 0.f ? v : expm1f(v); }

// ---------------- K prep: pack all MFMA weights, transpose pred_w, w2 tap-sums, init tables ----------------
// conv1 A-pack K-order c' = k*8 + ci (direct-from-time-major B, no im2col).
__global__ __launch_bounds__(256) void k_prep(const float* __restrict__ rel_rec,
                                              const float* __restrict__ rel_send,
                                              const float* __restrict__ w2,
                                              const float* __restrict__ w1,
                                              const float* __restrict__ pred_w,
                                              const float* __restrict__ m1w1,
                                              const float* __restrict__ m1w2,
                                              const float* __restrict__ m2w1,
                                              const float* __restrict__ m2w2,
                                              const float* __restrict__ m3w1,
                                              const float* __restrict__ m3w2,
                                              _Float16* __restrict__ apack,
                                              _Float16* __restrict__ apack1,
                                              float* __restrict__ pwt,
                                              float* __restrict__ w2sum,
                                              _Float16* __restrict__ mp,
                                              float* rep1, float* rep2, float* repm,
                                              int* sidx, int* ridx, int* inc) {
    int b = blockIdx.x;
    int tid = threadIdx.x;
    int l = tid & 63;
    if (b < 40) {            // conv2_w frags (raw; BN1 scale applied later by k_scale)
        int f = b * 4 + (tid >> 6);
        int m0 = f & 7, ks = f >> 3, s = ks & 3, k = ks >> 2;
        int m = m0 * 16 + (l & 15);
        int cbase = 32 * s + (l >> 4) * 8;
#pragma unroll
        for (int j = 0; j < 8; ++j)
            apack[(f * 64 + l) * 8 + j] = (_Float16)w2[m * 640 + (cbase + j) * 5 + k];
    } else if (b < 44) {     // conv1_w frags: c' = k*8+ci, taps k>=5 zero-padded
        int f = (b - 40) * 4 + (tid >> 6);
        int m0 = f & 7, s = f >> 3;
        int m = m0 * 16 + (l & 15);
        int cbase = 32 * s + (l >> 4) * 8;
#pragma unroll
        for (int j = 0; j < 8; ++j) {
            int c = cbase + j;
            int k = c >> 3, ci = c & 7;
            apack1[(f * 64 + l) * 8 + j] = (k < 5) ? (_Float16)w1[m * 40 + ci * 5 + k]
                                                   : (_Float16)0.f;
        }
    } else if (b == 44) {    // init: zero replicas (incl. 3 MLP replica sets), build edge tables
        for (int i = tid; i < NREP * 256; i += 256) { rep1[i] = 0.f; rep2[i] = 0.f; }
        for (int i = tid; i < 3 * NREP * 256; i += 256) repm[i] = 0.f;
        for (int e = tid; e < EE; e += 256) {
            int s = 0, r = 0;
            for (int n = 0; n < NN; ++n) {
                if (rel_send[e * NN + n] > 0.5f) s = n;
                if (rel_rec[e * NN + n] > 0.5f) r = n;
            }
            sidx[e] = s; ridx[e] = r;
        }
        __syncthreads();
        if (tid < NN) {
            int k = 0;
            for (int e = 0; e < EE; ++e)
                if (ridx[e] == tid) inc[tid * (NN - 1) + (k++)] = e;
        }
    } else if (b < 53) {     // transpose pred_w -> pwt[c][o]  (region reused as mpred post-BN2)
        int idx = (b - 45) * 2048 + tid;
        for (int rep = 0; rep < 8; ++rep, idx += 256) {
            int o = idx >> 7, c = idx & 127;
            pwt[c * 128 + o] = pred_w[idx];
        }
    } else if (b < 117) {    // MLP weight packs: generic [128][K] -> A-frag-linear
        int idx = b - 53;    // 0..63
        const float* W; _Float16* dst; int K;
        if (idx < 8)       { W = m1w1; dst = mp + MP_M1W1; K = 128; }
        else if (idx < 16) { W = m1w2; dst = mp + MP_M1W2; K = 128; idx -= 8; }
        else if (idx < 24) { W = m2w1; dst = mp + MP_M2W1; K = 128; idx -= 16; }
        else if (idx < 32) { W = m2w2; dst = mp + MP_M2W2; K = 128; idx -= 24; }
        else if (idx < 40) { W = m3w2; dst = mp + MP_M3W2; K = 128; idx -= 32; }
        else               { W = m3w1; dst = mp + MP_M3W1; K = 384; idx -= 40; }
        int f = idx * 4 + (tid >> 6);
        int s = f >> 3, m0 = f & 7;
        int m = m0 * 16 + (l & 15);
        int cb = 32 * s + (l >> 4) * 8;
#pragma unroll
        for (int j = 0; j < 8; ++j)
            dst[(f * 64 + l) * 8 + j] = (_Float16)W[m * K + cb + j];
    } else {                 // w2 tap-sums: w2sum[co][ci] = sum_k w2[co][ci][k]
        int idx = (b - 117) * 2048 + tid;
        for (int rep = 0; rep < 8; ++rep, idx += 256) {
            const float* wr = w2 + idx * 5;
            w2sum[idx] = wr[0] + wr[1] + wr[2] + wr[3] + wr[4];
        }
    }
}

// ---------------- K1: conv1 (MFMA, direct-from-LDS B) + relu -> BN1 stats + PRE-BN maxpool ----------------
// pool-before-BN exact: bn1_g=1 -> BN scale>0 -> max commutes with fma.
__global__ __launch_bounds__(256) void k_conv1_stats(const float* __restrict__ inputs,
                                                     const _Float16* __restrict__ apack1,
                                                     const float* __restrict__ conv1_b,
                                                     const int* __restrict__ sidx,
                                                     const int* __restrict__ ridx,
                                                     float* rep1,
                                                     _Float16* __restrict__ y2p) {
    __shared__ __align__(16) _Float16 s_edgesT[104 * 8];
    __shared__ __align__(16) _Float16 s_y2t[48 * 136];
    int be = blockIdx.x;
    int b = be / EE, e = be - b * EE;
    int sn = sidx[e], rn = ridx[e];
    float* rep = rep1 + (be & (NREP - 1)) * 256;
    for (int i = threadIdx.x; i < 200; i += 256) {
        int side = (i >= 100) ? 1 : 0;
        int t = i - side * 100;
        int n = side ? rn : sn;
        float4 v = *(const float4*)(inputs + ((long long)(b * NN + n) * TT + t) * DD);
        f16x4 o = {(_Float16)v.x, (_Float16)v.y, (_Float16)v.z, (_Float16)v.w};
        *(f16x4*)(&s_edgesT[t * 8 + side * 4]) = o;
    }
    if (threadIdx.x < 32) s_edgesT[800 + threadIdx.x] = (_Float16)0.f;
    __syncthreads();
    int w = threadIdx.x >> 6, lane = threadIdx.x & 63;
    int quad = lane >> 4, l15 = lane & 15;
    f32x4 acc1[2][6];
#pragma unroll
    for (int m = 0; m < 2; ++m)
#pragma unroll
        for (int nt = 0; nt < 6; ++nt) acc1[m][nt] = (f32x4){0.f, 0.f, 0.f, 0.f};
    {
        const f16x8* Ap = (const f16x8*)apack1;
#pragma unroll
        for (int s = 0; s < 2; ++s) {
            f16x8 a0 = Ap[(s * 8 + 2 * w) * 64 + lane];
            f16x8 a1 = Ap[(s * 8 + 2 * w + 1) * 64 + lane];
#pragma unroll
            for (int nt = 0; nt < 6; ++nt) {
                f16x8 bfr = *(const f16x8*)(&s_edgesT[(nt * 16 + l15 + 4 * s + quad) * 8]);
                acc1[0][nt] = __builtin_amdgcn_mfma_f32_16x16x32_f16(a0, bfr, acc1[0][nt], 0, 0, 0);
                acc1[1][nt] = __builtin_amdgcn_mfma_f32_16x16x32_f16(a1, bfr, acc1[1][nt], 0, 0, 0);
            }
        }
    }
#pragma unroll
    for (int m = 0; m < 2; ++m) {
        int co0 = (2 * w + m) * 16 + quad * 4;
        float ss[4] = {0.f, 0.f, 0.f, 0.f}, qq[4] = {0.f, 0.f, 0.f, 0.f};
#pragma unroll
        for (int nt = 0; nt < 6; ++nt) {
            int t = nt * 16 + l15;
#pragma unroll
            for (int r = 0; r < 4; ++r) {
                float v = fmaxf(acc1[m][nt][r] + conv1_b[co0 + r], 0.f);
                ss[r] += v; qq[r] += v * v;
                float p = __shfl_xor(v, 1);
                if ((l15 & 1) == 0)
                    s_y2t[(t >> 1) * 136 + co0 + r] = (_Float16)fmaxf(v, p);
            }
        }
#pragma unroll
        for (int r = 0; r < 4; ++r) {
            float s = ss[r], q = qq[r];
            s += __shfl_xor(s, 1); s += __shfl_xor(s, 2); s += __shfl_xor(s, 4); s += __shfl_xor(s, 8);
            q += __shfl_xor(q, 1); q += __shfl_xor(q, 2); q += __shfl_xor(q, 4); q += __shfl_xor(q, 8);
            if (l15 == 0) {
                atomicAdd(&rep[co0 + r], s);
                atomicAdd(&rep[128 + co0 + r], q);
            }
        }
    }
    __syncthreads();
    _Float16* dst = y2p + (long long)be * 6144;
    for (int chunk = threadIdx.x; chunk < 768; chunk += 256) {
        int row = chunk >> 4, off = (chunk & 15) * 8;
        *(f16x8*)(dst + row * 128 + off) = *(const f16x8*)(&s_y2t[row * 136 + off]);
    }
}

// ---------------- finalize BN from 64 replicas -> scale/shift (re-zero replicas) ----------------
__global__ void k_finalize_rep(float* __restrict__ rep, float* stats, int scIdx,
                               const float* __restrict__ g, const float* __restrict__ bb,
                               float inv_count) {
    int j = threadIdx.x;
    float s = 0.f, q = 0.f;
    for (int i = 0; i < NREP; ++i) {
        s += rep[i * 256 + j];
        q += rep[i * 256 + 128 + j];
    }
    for (int i = 0; i < NREP; ++i) {
        rep[i * 256 + j] = 0.f;
        rep[i * 256 + 128 + j] = 0.f;
    }
    float m = s * inv_count;
    float v = fmaxf(q * inv_count - m * m, 0.f);
    float sc = g[j] * rsqrtf(v + EPS);
    stats[scIdx + j] = sc;
    stats[scIdx + 128 + j] = bb[j] - m * sc;
}

// ---------------- finalize BN1 + conv2 fused bias2[co] = conv2_b + sum_ci w2sum*sh ----------------
// Valid: every conv2 output t uses all 5 taps (VALID conv over 48 rows).
__global__ void k_finalize_bn1(float* __restrict__ rep, float* stats,
                               const float* __restrict__ g, const float* __restrict__ bb,
                               const float* __restrict__ w2sum, const float* __restrict__ conv2_b,
                               float inv_count) {
    __shared__ float s_sh[128];
    int j = threadIdx.x;  // 128
    float s = 0.f, q = 0.f;
    for (int i = 0; i < NREP; ++i) {
        s += rep[i * 256 + j];
        q += rep[i * 256 + 128 + j];
    }
    for (int i = 0; i < NREP; ++i) {
        rep[i * 256 + j] = 0.f;
        rep[i * 256 + 128 + j] = 0.f;
    }
    float m = s * inv_count;
    float v = fmaxf(q * inv_count - m * m, 0.f);
    float sc = g[j] * rsqrtf(v + EPS);
    float sh = bb[j] - m * sc;
    stats[S_BN1_SC + j] = sc;
    stats[S_BN1_SC + 128 + j] = sh;
    s_sh[j] = sh;
    __syncthreads();
    float acc = conv2_b[j];
    for (int ci = 0; ci < 128; ++ci)
        acc = fmaf(w2sum[j * 128 + ci], s_sh[ci], acc);
    stats[S_BIAS2 + j] = acc;
}

// ---------------- K scale: apack *= BN1 scale (per input channel), in place ----------------
__global__ __launch_bounds__(256) void k_scale(_Float16* __restrict__ apack,
                                               const float* __restrict__ stats) {
    int tid = threadIdx.x, l = tid & 63;
    int f = blockIdx.x * 4 + (tid >> 6);
    int s = (f >> 3) & 3;
    int cbase = 32 * s + (l >> 4) * 8;
    _Float16* p = apack + (f * 64 + l) * 8;
#pragma unroll
    for (int j = 0; j < 8; ++j)
        p[j] = (_Float16)((float)p[j] * stats[S_BN1_SC + cbase + j]);
}

// ---------------- K3 (best-measured 151.0us shape, setprio REVERTED): 2 edges/block, 256 threads ----------------
// [Plateau ledger: r1 4-edge ILP 161us; r2 8-thin-wave occ 58% 152us (2x LDS reads, same time
//  => not LDS-BW-bound); r3 reg pipeline SPILLED 650us; r4 setprio 159us (m190-consistent
//  negative). 151us invariant across occupancy/A-traffic/LDS-traffic/registers => structural
//  plateau at HIP level. DO NOT touch without a fundamentally different schedule.]
__global__ __launch_bounds__(256) void k_conv2(_Float16* __restrict__ y23,
                                               const _Float16* __restrict__ apack,
                                               const float* __restrict__ stats,
                                               float* rep2) {
    __shared__ __align__(16) _Float16 s_y2t[2][48 * 136];
    int tid = threadIdx.x;
    int be0 = blockIdx.x * 2;
    for (int i = tid; i < 1536; i += 256) {
        int ed = i / 768, rem = i - ed * 768;
        int row = rem >> 4, c0 = (rem & 15) * 8;
        *(f16x8*)(&s_y2t[ed][row * 136 + c0]) =
            *(const f16x8*)(y23 + (long long)(be0 + ed) * 6144 + rem * 8);
    }
    __syncthreads();
    int w = tid >> 6, lane = tid & 63;
    int quad = lane >> 4, l15 = lane & 15;
    int g = w & 1, e = w >> 1;
    f32x4 acc[4][3];
#pragma unroll
    for (int m = 0; m < 4; ++m)
#pragma unroll
        for (int nt = 0; nt < 3; ++nt) acc[m][nt] = (f32x4){0.f, 0.f, 0.f, 0.f};
    const f16x8* Ap = (const f16x8*)apack;
    const char* base = (const char*)&s_y2t[e][0];
#pragma unroll
    for (int k = 0; k < 5; ++k) {
#pragma unroll
        for (int s = 0; s < 4; ++s) {
            f16x8 am[4];
#pragma unroll
            for (int m = 0; m < 4; ++m)
                am[m] = Ap[((k * 4 + s) * 8 + g * 4 + m) * 64 + lane];
#pragma unroll
            for (int nt = 0; nt < 3; ++nt) {
                int r = nt * 16 + l15 + k;
                if (nt == 2) r = (r > 47) ? 47 : r;   // clamp: t>=44 outputs are discarded
                f16x8 bfr = *(const f16x8*)(base + r * 272 + 64 * s + quad * 16);
#pragma unroll
                for (int m = 0; m < 4; ++m)
                    acc[m][nt] = __builtin_amdgcn_mfma_f32_16x16x32_f16(am[m], bfr, acc[m][nt], 0, 0, 0);
            }
        }
    }
    // epilogue: bias2 + relu, store y3 t-major [44][128] (f16x4), BN2 stats
    int be = be0 + e;
    _Float16* y3 = y23 + (long long)be * 6144;
    float* rep = rep2 + (be & (NREP - 1)) * 256;
#pragma unroll
    for (int m = 0; m < 4; ++m) {
        int co0 = (g * 4 + m) * 16 + quad * 4;
        float4 bs = *(const float4*)(stats + S_BIAS2 + co0);
        float ssum[4] = {0.f, 0.f, 0.f, 0.f}, qsum[4] = {0.f, 0.f, 0.f, 0.f};
#pragma unroll
        for (int nt = 0; nt < 3; ++nt) {
            int t = nt * 16 + l15;
            if (t < 44) {
                float v0 = fmaxf(acc[m][nt][0] + bs.x, 0.f);
                float v1 = fmaxf(acc[m][nt][1] + bs.y, 0.f);
                float v2 = fmaxf(acc[m][nt][2] + bs.z, 0.f);
                float v3 = fmaxf(acc[m][nt][3] + bs.w, 0.f);
                f16x4 o = {(_Float16)v0, (_Float16)v1, (_Float16)v2, (_Float16)v3};
                *(f16x4*)(y3 + t * 128 + co0) = o;
                ssum[0] += v0; qsum[0] += v0 * v0;
                ssum[1] += v1; qsum[1] += v1 * v1;
                ssum[2] += v2; qsum[2] += v2 * v2;
                ssum[3] += v3; qsum[3] += v3 * v3;
            }
        }
#pragma unroll
        for (int r = 0; r < 4; ++r) {
            float s = ssum[r], q = qsum[r];
            s += __shfl_xor(s, 1); s += __shfl_xor(s, 2); s += __shfl_xor(s, 4); s += __shfl_xor(s, 8);
            q += __shfl_xor(q, 1); q += __shfl_xor(q, 2); q += __shfl_xor(q, 4); q += __shfl_xor(q, 8);
            if (l15 == 0) {
                atomicAdd(&rep[co0 + r], s);
                atomicAdd(&rep[128 + co0 + r], q);
            }
        }
    }
}

// ---------------- K predpack (post-BN2): pred-weight MFMA pack with BN2-scale + 1/44 fold,
// pb2 bias fold, aw2 attention-weight fold. Runs after k_finalize_rep(BN2). ----------------
// Math: x[o] = (1/44)(sum_c pred_w[o][c]*(sc[c]*pr[c]+sh[c]) + pred_b[o])  [since sum(att)=1]
//           = sum_c pw2[o][c]*pr[c] + pb2[o],  pw2 = pred_w*sc/44, pb2 = (pred_b + pred_w.sh)/44.
// att logits: sum_c y3[t][c]*(sc[c]*att_w[c]) + const  -> const drops (softmax shift-invariant).
__global__ __launch_bounds__(256) void k_predpack(float* __restrict__ stats,
                                                  const float* __restrict__ pred_w,
                                                  const float* __restrict__ pred_b,
                                                  const float* __restrict__ att_w,
                                                  _Float16* __restrict__ mpred) {
    int b = blockIdx.x, tid = threadIdx.x, l = tid & 63;
    if (b < 8) {             // A-frag pack: f = 0..31, same layout as K=128 MLP packs
        int f = b * 4 + (tid >> 6);
        int m = (f & 7) * 16 + (l & 15);
        int cb = 32 * (f >> 3) + (l >> 4) * 8;
#pragma unroll
        for (int j = 0; j < 8; ++j) {
            int c = cb + j;
            mpred[(f * 64 + l) * 8 + j] =
                (_Float16)(pred_w[m * 128 + c] * stats[S_BN2_SC + c] * (1.0f / 44.0f));
        }
    } else if (tid < 128) {  // pb2 + aw2
        float a = pred_b[tid];
        for (int c = 0; c < 128; ++c)
            a = fmaf(pred_w[tid * 128 + c], stats[S_BN2_SC + 128 + c], a);
        stats[S_PB2 + tid] = a * (1.0f / 44.0f);
        stats[S_AW2 + tid] = stats[S_BN2_SC + tid] * att_w[tid];
    }
}

// ---------------- K5 v2: attention-pool on RAW y3 (BN2 folded downstream) -> pr [BE][128] ----------------
// [BN2-apply phase and 128x128 pred GEMV removed from this kernel (~70% of its VALU and the
//  796MB pwt L2 traffic); pred matmul is now MFMA layer-0 of k_mlp1x. LDS 23KB->12KB.]
__global__ __launch_bounds__(256) void k_predatt(const _Float16* __restrict__ y23,
                                                 const float* __restrict__ stats,
                                                 float* __restrict__ x) {
    __shared__ __align__(16) _Float16 s_y3[44 * 136];
    __shared__ float s_att[48];
    __shared__ float s_p1[256];
    __shared__ float s_aw[128];
    int be = blockIdx.x, tid = threadIdx.x;
    if (tid < 128) s_aw[tid] = stats[S_AW2 + tid];
    const _Float16* yp = y23 + (long long)be * 6144;
    for (int i = tid; i < 704; i += 256) {   // 44 rows x 16 chunks of 8 (raw copy)
        int t = i >> 4, c0 = (i & 15) * 8;
        *(f16x8*)(&s_y3[t * 136 + c0]) = *(const f16x8*)(yp + i * 8);
    }
    __syncthreads();
    int w = tid >> 6, lane = tid & 63;
    {
        float aw0 = s_aw[lane], aw1 = s_aw[64 + lane];
        for (int tt = 0; tt < 11; ++tt) {
            int t = w * 11 + tt;
            float p = (float)s_y3[t * 136 + lane] * aw0 + (float)s_y3[t * 136 + 64 + lane] * aw1;
            p += __shfl_xor(p, 1); p += __shfl_xor(p, 2); p += __shfl_xor(p, 4);
            p += __shfl_xor(p, 8); p += __shfl_xor(p, 16); p += __shfl_xor(p, 32);
            if (lane == 0) s_att[t] = p;
        }
    }
    __syncthreads();
    if (w == 0) {
        float v = (lane < 44) ? s_att[lane] : -1e30f;
        float m = v;
        m = fmaxf(m, __shfl_xor(m, 1)); m = fmaxf(m, __shfl_xor(m, 2));
        m = fmaxf(m, __shfl_xor(m, 4)); m = fmaxf(m, __shfl_xor(m, 8));
        m = fmaxf(m, __shfl_xor(m, 16)); m = fmaxf(m, __shfl_xor(m, 32));
        float ev = (lane < 44) ? expf(v - m) : 0.f;
        float ss = ev;
        ss += __shfl_xor(ss, 1); ss += __shfl_xor(ss, 2); ss += __shfl_xor(ss, 4);
        ss += __shfl_xor(ss, 8); ss += __shfl_xor(ss, 16); ss += __shfl_xor(ss, 32);
        if (lane < 44) s_att[lane] = ev / ss;
    }
    __syncthreads();
    {
        int c = tid & 127, hh = tid >> 7;
        float a = 0.f;
        for (int t = hh * 22; t < hh * 22 + 22; ++t)
            a = fmaf((float)s_y3[t * 136 + c], s_att[t], a);
        s_p1[tid] = a;
    }
    __syncthreads();
    if (tid < 128)
        x[(long long)be * 128 + tid] = s_p1[tid] + s_p1[128 + tid];
}

// ---------------- fused 3-layer MFMA MLP for mlp1: pred(linear) -> L1(ELU) -> L2(ELU) + stats ----------------
// layer0 = BN2-folded pred matmul (pw2, pb2) on pooled-raw pr; x stays in LDS f16 (as before:
// the old pipeline also rounded x to f16 at mlp1 staging).
__global__ __launch_bounds__(256) void k_mlp1x(const float* __restrict__ in,
                                               const _Float16* __restrict__ wp0,
                                               const float* __restrict__ stats,
                                               const _Float16* __restrict__ wp1,
                                               const float* __restrict__ b1,
                                               const _Float16* __restrict__ wp2,
                                               const float* __restrict__ b2,
                                               float* __restrict__ out,
                                               float* __restrict__ repm) {
    __shared__ __align__(16) _Float16 s_a[64 * 136];
    __shared__ __align__(16) _Float16 s_b[64 * 136];
    int tid = threadIdx.x;
    long long r0 = (long long)blockIdx.x * 64;
    {
        const float4* src = (const float4*)(in + r0 * 128);
        for (int i = tid; i < 2048; i += 256) {
            int row = i >> 5, c0 = (i & 31) * 4;
            float4 v = src[i];
            f16x4 o = {(_Float16)v.x, (_Float16)v.y, (_Float16)v.z, (_Float16)v.w};
            *(f16x4*)(&s_a[row * 136 + c0]) = o;
        }
    }
    __syncthreads();
    int w = tid >> 6, lane = tid & 63, quad = lane >> 4, l15 = lane & 15;
    // layer 0: pred (linear, bias pb2, no activation), s_a -> s_b
    {
        f32x4 acc[2][4];
#pragma unroll
        for (int m = 0; m < 2; ++m)
#pragma unroll
            for (int nt = 0; nt < 4; ++nt) acc[m][nt] = (f32x4){0.f, 0.f, 0.f, 0.f};
        const f16x8* Ap = (const f16x8*)wp0;
#pragma unroll
        for (int s = 0; s < 4; ++s) {
            f16x8 a0 = Ap[(s * 8 + 2 * w) * 64 + lane];
            f16x8 a1 = Ap[(s * 8 + 2 * w + 1) * 64 + lane];
#pragma unroll
            for (int nt = 0; nt < 4; ++nt) {
                f16x8 bfr = *(const f16x8*)((const char*)s_a + (nt * 16 + l15) * 272 + 64 * s + quad * 16);
                acc[0][nt] = __builtin_amdgcn_mfma_f32_16x16x32_f16(a0, bfr, acc[0][nt], 0, 0, 0);
                acc[1][nt] = __builtin_amdgcn_mfma_f32_16x16x32_f16(a1, bfr, acc[1][nt], 0, 0, 0);
            }
        }
#pragma unroll
        for (int m = 0; m < 2; ++m) {
            int j0 = (2 * w + m) * 16 + quad * 4;
            float4 bs = *(const float4*)(stats + S_PB2 + j0);
#pragma unroll
            for (int nt = 0; nt < 4; ++nt) {
                int row = nt * 16 + l15;
                f16x4 o = {(_Float16)(acc[m][nt][0] + bs.x),
                           (_Float16)(acc[m][nt][1] + bs.y),
                           (_Float16)(acc[m][nt][2] + bs.z),
                           (_Float16)(acc[m][nt][3] + bs.w)};
                *(f16x4*)(&s_b[row * 136 + j0]) = o;
            }
        }
    }
    __syncthreads();
    // layer 1: s_b -> s_a, ELU
    {
        f32x4 acc[2][4];
#pragma unroll
        for (int m = 0; m < 2; ++m)
#pragma unroll
            for (int nt = 0; nt < 4; ++nt) acc[m][nt] = (f32x4){0.f, 0.f, 0.f, 0.f};
        const f16x8* Ap = (const f16x8*)wp1;
#pragma unroll
        for (int s = 0; s < 4; ++s) {
            f16x8 a0 = Ap[(s * 8 + 2 * w) * 64 + lane];
            f16x8 a1 = Ap[(s * 8 + 2 * w + 1) * 64 + lane];
#pragma unroll
            for (int nt = 0; nt < 4; ++nt) {
                f16x8 bfr = *(const f16x8*)((const char*)s_b + (nt * 16 + l15) * 272 + 64 * s + quad * 16);
                acc[0][nt] = __builtin_amdgcn_mfma_f32_16x16x32_f16(a0, bfr, acc[0][nt], 0, 0, 0);
                acc[1][nt] = __builtin_amdgcn_mfma_f32_16x16x32_f16(a1, bfr, acc[1][nt], 0, 0, 0);
            }
        }
#pragma unroll
        for (int m = 0; m < 2; ++m) {
            int j0 = (2 * w + m) * 16 + quad * 4;
            float4 bs = *(const float4*)(b1 + j0);
#pragma unroll
            for (int nt = 0; nt < 4; ++nt) {
                int row = nt * 16 + l15;
                f16x4 o = {(_Float16)eluf(acc[m][nt][0] + bs.x),
                           (_Float16)eluf(acc[m][nt][1] + bs.y),
                           (_Float16)eluf(acc[m][nt][2] + bs.z),
                           (_Float16)eluf(acc[m][nt][3] + bs.w)};
                *(f16x4*)(&s_a[row * 136 + j0]) = o;
            }
        }
    }
    __syncthreads();
    // layer 2 + stats: s_a -> out
    {
        f32x4 acc[2][4];
#pragma unroll
        for (int m = 0; m < 2; ++m)
#pragma unroll
            for (int nt = 0; nt < 4; ++nt) acc[m][nt] = (f32x4){0.f, 0.f, 0.f, 0.f};
        const f16x8* Ap = (const f16x8*)wp2;
#pragma unroll
        for (int s = 0; s < 4; ++s) {
            f16x8 a0 = Ap[(s * 8 + 2 * w) * 64 + lane];
            f16x8 a1 = Ap[(s * 8 + 2 * w + 1) * 64 + lane];
#pragma unroll
            for (int nt = 0; nt < 4; ++nt) {
                f16x8 bfr = *(const f16x8*)((const char*)s_a + (nt * 16 + l15) * 272 + 64 * s + quad * 16);
                acc[0][nt] = __builtin_amdgcn_mfma_f32_16x16x32_f16(a0, bfr, acc[0][nt], 0, 0, 0);
                acc[1][nt] = __builtin_amdgcn_mfma_f32_16x16x32_f16(a1, bfr, acc[1][nt], 0, 0, 0);
            }
        }
#pragma unroll
        for (int m = 0; m < 2; ++m) {
            int j0 = (2 * w + m) * 16 + quad * 4;
            float4 bs = *(const float4*)(b2 + j0);
            float ss[4] = {0.f, 0.f, 0.f, 0.f}, qq[4] = {0.f, 0.f, 0.f, 0.f};
#pragma unroll
            for (int nt = 0; nt < 4; ++nt) {
                int row = nt * 16 + l15;
                float v0 = eluf(acc[m][nt][0] + bs.x);
                float v1 = eluf(acc[m][nt][1] + bs.y);
                float v2 = eluf(acc[m][nt][2] + bs.z);
                float v3 = eluf(acc[m][nt][3] + bs.w);
                float4 o = {v0, v1, v2, v3};
                *(float4*)(out + (r0 + row) * 128 + j0) = o;
                ss[0] += v0; qq[0] += v0 * v0;
                ss[1] += v1; qq[1] += v1 * v1;
                ss[2] += v2; qq[2] += v2 * v2;
                ss[3] += v3; qq[3] += v3 * v3;
            }
            float* rep = repm + (blockIdx.x & (NREP - 1)) * 256;
#pragma unroll
            for (int r = 0; r < 4; ++r) {
                float s = ss[r], q = qq[r];
                s += __shfl_xor(s, 1); s += __shfl_xor(s, 2); s += __shfl_xor(s, 4); s += __shfl_xor(s, 8);
                q += __shfl_xor(q, 1); q += __shfl_xor(q, 2); q += __shfl_xor(q, 4); q += __shfl_xor(q, 8);
                if (l15 == 0) {
                    atomicAdd(&rep[j0 + r], s);
                    atomicAdd(&rep[128 + j0 + r], q);
                }
            }
        }
    }
}

// ---------------- fused 2-layer MFMA MLP (128->128->128), 64 rows/block (mlp2) ----------------
__global__ __launch_bounds__(256) void k_mlp2x(const float* __restrict__ in,
                                               const _Float16* __restrict__ wp1,
                                               const float* __restrict__ b1,
                                               const _Float16* __restrict__ wp2,
                                               const float* __restrict__ b2,
                                               float* __restrict__ out,
                                               float* __restrict__ repm) {
    __shared__ __align__(16) _Float16 s_in[64 * 136];
    __shared__ __align__(16) _Float16 s_mid[64 * 136];
    int tid = threadIdx.x;
    long long r0 = (long long)blockIdx.x * 64;
    {
        const float4* src = (const float4*)(in + r0 * 128);
        for (int i = tid; i < 2048; i += 256) {
            int row = i >> 5, c0 = (i & 31) * 4;
            float4 v = src[i];
            f16x4 o = {(_Float16)v.x, (_Float16)v.y, (_Float16)v.z, (_Float16)v.w};
            *(f16x4*)(&s_in[row * 136 + c0]) = o;
        }
    }
    __syncthreads();
    int w = tid >> 6, lane = tid & 63, quad = lane >> 4, l15 = lane & 15;
    // layer 1
    {
        f32x4 acc[2][4];
#pragma unroll
        for (int m = 0; m < 2; ++m)
#pragma unroll
            for (int nt = 0; nt < 4; ++nt) acc[m][nt] = (f32x4){0.f, 0.f, 0.f, 0.f};
        const f16x8* Ap = (const f16x8*)wp1;
#pragma unroll
        for (int s = 0; s < 4; ++s) {
            f16x8 a0 = Ap[(s * 8 + 2 * w) * 64 + lane];
            f16x8 a1 = Ap[(s * 8 + 2 * w + 1) * 64 + lane];
#pragma unroll
            for (int nt = 0; nt < 4; ++nt) {
                f16x8 bfr = *(const f16x8*)((const char*)s_in + (nt * 16 + l15) * 272 + 64 * s + quad * 16);
                acc[0][nt] = __builtin_amdgcn_mfma_f32_16x16x32_f16(a0, bfr, acc[0][nt], 0, 0, 0);
                acc[1][nt] = __builtin_amdgcn_mfma_f32_16x16x32_f16(a1, bfr, acc[1][nt], 0, 0, 0);
            }
        }
#pragma unroll
        for (int m = 0; m < 2; ++m) {
            int j0 = (2 * w + m) * 16 + quad * 4;
            float4 bs = *(const float4*)(b1 + j0);
#pragma unroll
            for (int nt = 0; nt < 4; ++nt) {
                int row = nt * 16 + l15;
                f16x4 o = {(_Float16)eluf(acc[m][nt][0] + bs.x),
                           (_Float16)eluf(acc[m][nt][1] + bs.y),
                           (_Float16)eluf(acc[m][nt][2] + bs.z),
                           (_Float16)eluf(acc[m][nt][3] + bs.w)};
                *(f16x4*)(&s_mid[row * 136 + j0]) = o;
            }
        }
    }
    __syncthreads();
    // layer 2 + stats
    {
        f32x4 acc[2][4];
#pragma unroll
        for (int m = 0; m < 2; ++m)
#pragma unroll
            for (int nt = 0; nt < 4; ++nt) acc[m][nt] = (f32x4){0.f, 0.f, 0.f, 0.f};
        const f16x8* Ap = (const f16x8*)wp2;
#pragma unroll
        for (int s = 0; s < 4; ++s) {
            f16x8 a0 = Ap[(s * 8 + 2 * w) * 64 + lane];
            f16x8 a1 = Ap[(s * 8 + 2 * w + 1) * 64 + lane];
#pragma unroll
            for (int nt = 0; nt < 4; ++nt) {
                f16x8 bfr = *(const f16x8*)((const char*)s_mid + (nt * 16 + l15) * 272 + 64 * s + quad * 16);
                acc[0][nt] = __builtin_amdgcn_mfma_f32_16x16x32_f16(a0, bfr, acc[0][nt], 0, 0, 0);
                acc[1][nt] = __builtin_amdgcn_mfma_f32_16x16x32_f16(a1, bfr, acc[1][nt], 0, 0, 0);
            }
        }
#pragma unroll
        for (int m = 0; m < 2; ++m) {
            int j0 = (2 * w + m) * 16 + quad * 4;
            float4 bs = *(const float4*)(b2 + j0);
            float ss[4] = {0.f, 0.f, 0.f, 0.f}, qq[4] = {0.f, 0.f, 0.f, 0.f};
#pragma unroll
            for (int nt = 0; nt < 4; ++nt) {
                int row = nt * 16 + l15;
                float v0 = eluf(acc[m][nt][0] + bs.x);
                float v1 = eluf(acc[m][nt][1] + bs.y);
                float v2 = eluf(acc[m][nt][2] + bs.z);
                float v3 = eluf(acc[m][nt][3] + bs.w);
                float4 o = {v0, v1, v2, v3};
                *(float4*)(out + (r0 + row) * 128 + j0) = o;
                ss[0] += v0; qq[0] += v0 * v0;
                ss[1] += v1; qq[1] += v1 * v1;
                ss[2] += v2; qq[2] += v2 * v2;
                ss[3] += v3; qq[3] += v3 * v3;
            }
            float* rep = repm + (blockIdx.x & (NREP - 1)) * 256;
#pragma unroll
            for (int r = 0; r < 4; ++r) {
                float s = ss[r], q = qq[r];
                s += __shfl_xor(s, 1); s += __shfl_xor(s, 2); s += __shfl_xor(s, 4); s += __shfl_xor(s, 8);
                q += __shfl_xor(q, 1); q += __shfl_xor(q, 2); q += __shfl_xor(q, 4); q += __shfl_xor(q, 8);
                if (l15 == 0) {
                    atomicAdd(&rep[j0 + r], s);
                    atomicAdd(&rep[128 + j0 + r], q);
                }
            }
        }
    }
}

// ---------------- fused mlp3: gather-concat [send|recv|skip] (K=384) -> L1(ELU, LDS) -> L2(ELU) -> f32 + stats ----
__global__ __launch_bounds__(256) void k_mlp3x(const float* __restrict__ xn,
                                               const float* __restrict__ bufB,
                                               const int* __restrict__ sidx,
                                               const int* __restrict__ ridx,
                                               const float* __restrict__ repm1,
                                               const float* __restrict__ repm2,
                                               const float* __restrict__ m1g,
                                               const float* __restrict__ m1bb,
                                               const float* __restrict__ m2g,
                                               const float* __restrict__ m2bb,
                                               const _Float16* __restrict__ wp1,
                                               const float* __restrict__ b1,
                                               const _Float16* __restrict__ wp2,
                                               const float* __restrict__ b2,
                                               float* __restrict__ out,
                                               float* __restrict__ repm3) {
    __shared__ __align__(16) _Float16 s_b[64 * 392];
    __shared__ __align__(16) _Float16 s_mid[64 * 136];
    __shared__ float s_st[4][128];
    __shared__ int s_s[64], s_r[64];
    int tid = threadIdx.x;
    long long r0 = (long long)blockIdx.x * 64;
    if (tid < 128) {
        float s = 0.f, q = 0.f;
        for (int i = 0; i < NREP; ++i) {
            s += repm2[i * 256 + tid];
            q += repm2[i * 256 + 128 + tid];
        }
        float mm = s * (1.0f / (float)(BB * NN));
        float vv = fmaxf(q * (1.0f / (float)(BB * NN)) - mm * mm, 0.f);
        float sc = m2g[tid] * rsqrtf(vv + EPS);
        s_st[0][tid] = sc;
        s_st[1][tid] = m2bb[tid] - mm * sc;
        s = 0.f; q = 0.f;
        for (int i = 0; i < NREP; ++i) {
            s += repm1[i * 256 + tid];
            q += repm1[i * 256 + 128 + tid];
        }
        mm = s * (1.0f / (float)BE);
        vv = fmaxf(q * (1.0f / (float)BE) - mm * mm, 0.f);
        sc = m1g[tid] * rsqrtf(vv + EPS);
        s_st[2][tid] = sc;
        s_st[3][tid] = m1bb[tid] - mm * sc;
    }
    if (tid < 64) {
        int r = (int)r0 + tid, b = r / EE, ed = r - b * EE;
        s_s[tid] = (b * NN + sidx[ed]) * 128;
        s_r[tid] = (b * NN + ridx[ed]) * 128;
    }
    __syncthreads();
    for (int i = tid; i < 8192; i += 256) {
        int row = i >> 7, j = i & 127;
        float sc2 = s_st[0][j], sh2 = s_st[1][j];
        s_b[row * 392 + j] = (_Float16)fmaf(xn[s_s[row] + j], sc2, sh2);
        s_b[row * 392 + 128 + j] = (_Float16)fmaf(xn[s_r[row] + j], sc2, sh2);
        s_b[row * 392 + 256 + j] = (_Float16)fmaf(bufB[(r0 + row) * 128 + j], s_st[2][j], s_st[3][j]);
    }
    __syncthreads();
    int w = tid >> 6, lane = tid & 63, quad = lane >> 4, l15 = lane & 15;
    // layer 1 (K=384)
    {
        f32x4 acc[2][4];
#pragma unroll
        for (int m = 0; m < 2; ++m)
#pragma unroll
            for (int nt = 0; nt < 4; ++nt) acc[m][nt] = (f32x4){0.f, 0.f, 0.f, 0.f};
        const f16x8* Ap = (const f16x8*)wp1;
#pragma unroll
        for (int s = 0; s < 12; ++s) {
            f16x8 a0 = Ap[(s * 8 + 2 * w) * 64 + lane];
            f16x8 a1 = Ap[(s * 8 + 2 * w + 1) * 64 + lane];
#pragma unroll
            for (int nt = 0; nt < 4; ++nt) {
                f16x8 bfr = *(const f16x8*)((const char*)s_b + (nt * 16 + l15) * 784 + 64 * s + quad * 16);
                acc[0][nt] = __builtin_amdgcn_mfma_f32_16x16x32_f16(a0, bfr, acc[0][nt], 0, 0, 0);
                acc[1][nt] = __builtin_amdgcn_mfma_f32_16x16x32_f16(a1, bfr, acc[1][nt], 0, 0, 0);
            }
        }
#pragma unroll
        for (int m = 0; m < 2; ++m) {
            int j0 = (2 * w + m) * 16 + quad * 4;
            float4 bs = *(const float4*)(b1 + j0);
#pragma unroll
            for (int nt = 0; nt < 4; ++nt) {
                int row = nt * 16 + l15;
                f16x4 o = {(_Float16)eluf(acc[m][nt][0] + bs.x),
                           (_Float16)eluf(acc[m][nt][1] + bs.y),
                           (_Float16)eluf(acc[m][nt][2] + bs.z),
                           (_Float16)eluf(acc[m][nt][3] + bs.w)};
                *(f16x4*)(&s_mid[row * 136 + j0]) = o;
            }
        }
    }
    __syncthreads();
    // layer 2 + stats
    {
        f32x4 acc[2][4];
#pragma unroll
        for (int m = 0; m < 2; ++m)
#pragma unroll
            for (int nt = 0; nt < 4; ++nt) acc[m][nt] = (f32x4){0.f, 0.f, 0.f, 0.f};
        const f16x8* Ap = (const f16x8*)wp2;
#pragma unroll
        for (int s = 0; s < 4; ++s) {
            f16x8 a0 = Ap[(s * 8 + 2 * w) * 64 + lane];
            f16x8 a1 = Ap[(s * 8 + 2 * w + 1) * 64 + lane];
#pragma unroll
            for (int nt = 0; nt < 4; ++nt) {
                f16x8 bfr = *(const f16x8*)((const char*)s_mid + (nt * 16 + l15) * 272 + 64 * s + quad * 16);
                acc[0][nt] = __builtin_amdgcn_mfma_f32_16x16x32_f16(a0, bfr, acc[0][nt], 0, 0, 0);
                acc[1][nt] = __builtin_amdgcn_mfma_f32_16x16x32_f16(a1, bfr, acc[1][nt], 0, 0, 0);
            }
        }
#pragma unroll
        for (int m = 0; m < 2; ++m) {
            int j0 = (2 * w + m) * 16 + quad * 4;
            float4 bs = *(const float4*)(b2 + j0);
            float ss[4] = {0.f, 0.f, 0.f, 0.f}, qq[4] = {0.f, 0.f, 0.f, 0.f};
#pragma unroll
            for (int nt = 0; nt < 4; ++nt) {
                int row = nt * 16 + l15;
                float v0 = eluf(acc[m][nt][0] + bs.x);
                float v1 = eluf(acc[m][nt][1] + bs.y);
                float v2 = eluf(acc[m][nt][2] + bs.z);
                float v3 = eluf(acc[m][nt][3] + bs.w);
                float4 o = {v0, v1, v2, v3};
                *(float4*)(out + (r0 + row) * 128 + j0) = o;
                ss[0] += v0; qq[0] += v0 * v0;
                ss[1] += v1; qq[1] += v1 * v1;
                ss[2] += v2; qq[2] += v2 * v2;
                ss[3] += v3; qq[3] += v3 * v3;
            }
            float* rep = repm3 + (blockIdx.x & (NREP - 1)) * 256;
#pragma unroll
            for (int r = 0; r < 4; ++r) {
                float s = ss[r], q = qq[r];
                s += __shfl_xor(s, 1); s += __shfl_xor(s, 2); s += __shfl_xor(s, 4); s += __shfl_xor(s, 8);
                q += __shfl_xor(q, 1); q += __shfl_xor(q, 2); q += __shfl_xor(q, 4); q += __shfl_xor(q, 8);
                if (l15 == 0) {
                    atomicAdd(&rep[j0 + r], s);
                    atomicAdd(&rep[128 + j0 + r], q);
                }
            }
        }
    }
}

// ---------------- edge2node scatter-mean with inline BN-M1 (finalize folded, bit-identical) ----------------
__global__ __launch_bounds__(128) void k_e2n(const float* __restrict__ bufB,
                                             const int* __restrict__ inc,
                                             const float* __restrict__ repm1,
                                             const float* __restrict__ m1g,
                                             const float* __restrict__ m1bb,
                                             float* __restrict__ xn) {
    int bn = blockIdx.x;
    int b = bn / NN, n = bn - b * NN;
    int j = threadIdx.x;
    float s0 = 0.f, q0 = 0.f;
    for (int i = 0; i < NREP; ++i) {
        s0 += repm1[i * 256 + j];
        q0 += repm1[i * 256 + 128 + j];
    }
    float mm = s0 * (1.0f / (float)BE);
    float vv = fmaxf(q0 * (1.0f / (float)BE) - mm * mm, 0.f);
    float sc = m1g[j] * rsqrtf(vv + EPS);
    float sh = m1bb[j] - mm * sc;
    float s = 0.f;
    for (int k = 0; k < NN - 1; ++k) {
        int e = inc[n * (NN - 1) + k];
        s += bufB[(long long)(b * EE + e) * 128 + j];
    }
    xn[bn * 128 + j] = (s * sc + (float)(NN - 1) * sh) * (1.0f / (float)NN);
}

// ---------------- BN3 apply + fc_out (128 -> 16); BN-M3 finalize folded (bit-identical) ----------------
__global__ __launch_bounds__(256) void k_fcout(const float* __restrict__ h2,
                                               const float* __restrict__ repm3,
                                               const float* __restrict__ m3g,
                                               const float* __restrict__ m3bb,
                                               const float* __restrict__ fcw,
                                               const float* __restrict__ fcb,
                                               float* __restrict__ out) {
    __shared__ float s_x[16 * 129];
    __shared__ float s_w[16 * 129];
    __shared__ float s_sc[128], s_sh[128];
    int r0 = blockIdx.x * 16;
    int tid = threadIdx.x;
    if (tid < 128) {
        float s = 0.f, q = 0.f;
        for (int i = 0; i < NREP; ++i) {
            s += repm3[i * 256 + tid];
            q += repm3[i * 256 + 128 + tid];
        }
        float mm = s * (1.0f / (float)BE);
        float vv = fmaxf(q * (1.0f / (float)BE) - mm * mm, 0.f);
        float sc = m3g[tid] * rsqrtf(vv + EPS);
        s_sc[tid] = sc;
        s_sh[tid] = m3bb[tid] - mm * sc;
    }
    __syncthreads();
    for (int i = tid; i < 16 * 128; i += 256) {
        int rr = i >> 7, j = i & 127;
        s_x[rr * 129 + j] = fmaf(h2[(long long)(r0 + rr) * 128 + j], s_sc[j], s_sh[j]);
    }
    for (int i = tid; i < 16 * 128; i += 256) {
        int o = i >> 7, j = i & 127;
        s_w[o * 129 + j] = fcw[i];
    }
    __syncthreads();
    int rl = tid >> 4, o = tid & 15;
    float a = fcb[o];
    for (int j = 0; j < 128; ++j) a = fmaf(s_x[rl * 129 + j], s_w[o * 129 + j], a);
    out[(long long)(r0 + rl) * 16 + o] = a;
}

// ---------------- host launcher ----------------
extern "C" void kernel_launch(void* const* d_in, const int* in_sizes, int n_in,
                              void* d_out, int out_size, void* d_ws, size_t ws_size,
                              hipStream_t stream) {
    const float* inputs = (const float*)d_in[0];
    const float* rel_rec = (const float*)d_in[1];
    const float* rel_send = (const float*)d_in[2];
    const float* conv1_w = (const float*)d_in[3];
    const float* conv1_b = (const float*)d_in[4];
    const float* bn1_g = (const float*)d_in[5];
    const float* bn1_b = (const float*)d_in[6];
    const float* conv2_w = (const float*)d_in[7];
    const float* conv2_b = (const float*)d_in[8];
    const float* bn2_g = (const float*)d_in[9];
    const float* bn2_b = (const float*)d_in[10];
    const float* pred_w = (const float*)d_in[11];
    const float* pred_b = (const float*)d_in[12];
    const float* att_w = (const float*)d_in[13];
    const float* att_b = (const float*)d_in[14];
    const float* m1w1 = (const float*)d_in[15];
    const float* m1b1 = (const float*)d_in[16];
    const float* m1w2 = (const float*)d_in[17];
    const float* m1b2 = (const float*)d_in[18];
    const float* m1g = (const float*)d_in[19];
    const float* m1bb = (const float*)d_in[20];
    const float* m2w1 = (const float*)d_in[21];
    const float* m2b1 = (const float*)d_in[22];
    const float* m2w2 = (const float*)d_in[23];
    const float* m2b2 = (const float*)d_in[24];
    const float* m2g = (const float*)d_in[25];
    const float* m2bb = (const float*)d_in[26];
    const float* m3w1 = (const float*)d_in[27];
    const float* m3b1 = (const float*)d_in[28];
    const float* m3w2 = (const float*)d_in[29];
    const float* m3b2 = (const float*)d_in[30];
    const float* m3g = (const float*)d_in[31];
    const float* m3bb = (const float*)d_in[32];
    const float* fcw = (const float*)d_in[33];
    const float* fcb = (const float*)d_in[34];

    char* ws = (char*)d_ws;
    float* stats = (float*)(ws + OFF_STATS);
    int* sidx = (int*)(ws + OFF_SIDX);
    int* ridx = (int*)(ws + OFF_RIDX);
    int* inc = (int*)(ws + OFF_INC);
    _Float16* y23 = (_Float16*)(ws + OFF_Y23);
    float* x = (float*)(ws + OFF_X);
    float* bufB = (float*)(ws + OFF_BUFB);
    float* xn = (float*)(ws + OFF_XN);
    _Float16* apack = (_Float16*)(ws + OFF_APACK);
    _Float16* apack1 = (_Float16*)(ws + OFF_APACK1);
    float* pwt = (float*)(ws + OFF_PWT);
    _Float16* mpred = (_Float16*)(ws + OFF_PWT);   // reuses pwt region post-BN2
    float* w2sum = (float*)(ws + OFF_W2SUM);
    float* rep1 = (float*)(ws + OFF_REP1);
    float* rep2 = (float*)(ws + OFF_REP2);
    float* repm1 = (float*)(ws + OFF_REPM);
    float* repm2 = (float*)(ws + OFF_REPM + 65536ULL);
    float* repm3 = (float*)(ws + OFF_REPM + 131072ULL);
    _Float16* mp = (_Float16*)(ws + OFF_MP);
    float* outp = (float*)d_out;

    hipLaunchKernelGGL(k_prep, dim3(125), dim3(256), 0, stream,
                       rel_rec, rel_send, conv2_w, conv1_w, pred_w,
                       m1w1, m1w2, m2w1, m2w2, m3w1, m3w2,
                       apack, apack1, pwt, w2sum, mp, rep1, rep2, repm1, sidx, ridx, inc);
    hipLaunchKernelGGL(k_conv1_stats, dim3(BE), dim3(256), 0, stream,
                       inputs, apack1, conv1_b, sidx, ridx, rep1, y23);
    hipLaunchKernelGGL(k_finalize_bn1, dim3(1), dim3(128), 0, stream,
                       rep1, stats, bn1_g, bn1_b, w2sum, conv2_b, 1.0f / (float)(BE * L1));
    hipLaunchKernelGGL(k_scale, dim3(40), dim3(256), 0, stream, apack, stats);
    hipLaunchKernelGGL(k_conv2, dim3(BE / 2), dim3(256), 0, stream,
                       y23, apack, stats, rep2);
    hipLaunchKernelGGL(k_finalize_rep, dim3(1), dim3(128), 0, stream,
                       rep2, stats, S_BN2_SC, bn2_g, bn2_b, 1.0f / (float)(BE * L2));
    // BN2-folded pred pack (pw2, pb2, aw2)
    hipLaunchKernelGGL(k_predpack, dim3(9), dim3(256), 0, stream,
                       stats, pred_w, pred_b, att_w, mpred);
    // attention-pool on raw y3 -> pr
    hipLaunchKernelGGL(k_predatt, dim3(BE), dim3(256), 0, stream, y23, stats, x);
    // mlp1 as 3-layer MFMA (pred layer0 + L1 + L2) -> stats into repm1
    hipLaunchKernelGGL(k_mlp1x, dim3(BE / 64), dim3(256), 0, stream,
                       x, mpred, stats, mp + MP_M1W1, m1b1, mp + MP_M1W2, m1b2, bufB, repm1);
    // edge2node (BN-M1 inline, finalize folded) + mlp2 (fused) -> stats into repm2
    hipLaunchKernelGGL(k_e2n, dim3(BB * NN), dim3(128), 0, stream, bufB, inc, repm1, m1g, m1bb, xn);
    hipLaunchKernelGGL(k_mlp2x, dim3(BB * NN / 64), dim3(256), 0, stream,
                       xn, mp + MP_M2W1, m2b1, mp + MP_M2W2, m2b2, xn, repm2);
    // node2edge + mlp3 (fused gather + 2-layer; BN-M1/M2 finalize folded) -> stats into repm3
    hipLaunchKernelGGL(k_mlp3x, dim3(BE / 64), dim3(256), 0, stream,
                       xn, bufB, sidx, ridx, repm1, repm2, m1g, m1bb, m2g, m2bb,
                       mp + MP_M3W1, m3b1, mp + MP_M3W2, m3b2, bufB, repm3);
    // fc_out (BN-M3 inline, finalize folded)
    hipLaunchKernelGGL(k_fcout, dim3(BE / 16), dim3(256), 0, stream,
                       bufB, repm3, m3g, m3bb, fcw, fcb, outp);
    (void)in_sizes; (void)n_in; (void)out_size; (void)ws_size;
    (void)att_b;
}

// Round 7
// 588.078 us; speedup vs baseline: 1.0539x; 1.0539x over previous
//
#include <hip/hip_runtime.h>
#include <hip/hip_bf16.h>
#include <hip/hip_fp16.h>

// ---------------- problem constants ----------------
#define BB 32
#define NN 20
#define TT 100
#define DD 4
#define HH 128
#define EE 380          // N*(N-1)
#define BE 12160        // B*E
#define L1 96           // conv1 out length
#define LP 48           // after maxpool
#define L2 44           // conv2 out length
#define NOUT 16
#define EPS 1e-5f
#define NREP 64         // stats replicas (atomic de-contention)

typedef _Float16 f16x8 __attribute__((ext_vector_type(8)));
typedef _Float16 f16x4 __attribute__((ext_vector_type(4)));
typedef _Float16 f16x2 __attribute__((ext_vector_type(2)));
typedef float f32x4 __attribute__((ext_vector_type(4)));

// stats slot indices (floats): SC at base, SH at base+128. Slots 0..127 = conv2 bias2 (BN1-fold).
#define S_BIAS2 0
#define S_BN1_SC 256
#define S_BN2_SC 768

// workspace offsets (bytes)
#define OFF_STATS 0ULL
#define OFF_SIDX 16384ULL
#define OFF_RIDX 18432ULL
#define OFF_INC 20480ULL
#define OFF_Y23 24576ULL                     // f16 [BE] slots of 6144: y2pre [48][128] then y3 t-major [44][128]
#define OFF_X 149446656ULL                   // f32 [BE][128]
#define OFF_BUFA 155672576ULL                // f32 [BE][128]; rep1/rep2 live here during conv phase
#define OFF_BUFB 161898496ULL                // f32 [BE][128]
#define OFF_XN 168124416ULL                  // f32 [640][128]
#define OFF_T640 168452096ULL                // conv-phase: apack(160K)+apack1(16K)+pwt(64K)+w2sum(64K)
#define OFF_REPM 168779776ULL                // f32 3x[64][256] MLP stats replicas (repm1/repm2/repm3)
#define OFF_MP 171958272ULL                  // f16 MLP weight packs (256 KB)
#define OFF_APACK OFF_T640
#define OFF_APACK1 (OFF_T640 + 163840ULL)
#define OFF_PWT (OFF_T640 + 180224ULL)
#define OFF_W2SUM (OFF_T640 + 245760ULL)
#define OFF_REP1 OFF_BUFA
#define OFF_REP2 (OFF_BUFA + 65536ULL)
// MP pack offsets in f16 units
#define MP_M1W1 0
#define MP_M1W2 16384
#define MP_M2W1 32768
#define MP_M2W2 49152
#define MP_M3W2 65536
#define MP_M3W1 81920

__device__ __forceinline__ float eluf(float v) { return v > 0.f ? v : expm1f(v); }

// ---------------- K prep: pack all MFMA weights, transpose pred_w, w2 tap-sums, init tables ----------------
// conv1 A-pack K-order c' = k*8 + ci (direct-from-time-major B, no im2col).
__global__ __launch_bounds__(256) void k_prep(const float* __restrict__ rel_rec,
                                              const float* __restrict__ rel_send,
                                              const float* __restrict__ w2,
                                              const float* __restrict__ w1,
                                              const float* __restrict__ pred_w,
                                              const float* __restrict__ m1w1,
                                              const float* __restrict__ m1w2,
                                              const float* __restrict__ m2w1,
                                              const float* __restrict__ m2w2,
                                              const float* __restrict__ m3w1,
                                              const float* __restrict__ m3w2,
                                              _Float16* __restrict__ apack,
                                              _Float16* __restrict__ apack1,
                                              float* __restrict__ pwt,
                                              float* __restrict__ w2sum,
                                              _Float16* __restrict__ mp,
                                              float* rep1, float* rep2, float* repm,
                                              int* sidx, int* ridx, int* inc) {
    int b = blockIdx.x;
    int tid = threadIdx.x;
    int l = tid & 63;
    if (b < 40) {            // conv2_w frags (raw; BN1 scale applied later by k_scale)
        int f = b * 4 + (tid >> 6);
        int m0 = f & 7, ks = f >> 3, s = ks & 3, k = ks >> 2;
        int m = m0 * 16 + (l & 15);
        int cbase = 32 * s + (l >> 4) * 8;
#pragma unroll
        for (int j = 0; j < 8; ++j)
            apack[(f * 64 + l) * 8 + j] = (_Float16)w2[m * 640 + (cbase + j) * 5 + k];
    } else if (b < 44) {     // conv1_w frags: c' = k*8+ci, taps k>=5 zero-padded
        int f = (b - 40) * 4 + (tid >> 6);
        int m0 = f & 7, s = f >> 3;
        int m = m0 * 16 + (l & 15);
        int cbase = 32 * s + (l >> 4) * 8;
#pragma unroll
        for (int j = 0; j < 8; ++j) {
            int c = cbase + j;
            int k = c >> 3, ci = c & 7;
            apack1[(f * 64 + l) * 8 + j] = (k < 5) ? (_Float16)w1[m * 40 + ci * 5 + k]
                                                   : (_Float16)0.f;
        }
    } else if (b == 44) {    // init: zero replicas (incl. 3 MLP replica sets), build edge tables
        for (int i = tid; i < NREP * 256; i += 256) { rep1[i] = 0.f; rep2[i] = 0.f; }
        for (int i = tid; i < 3 * NREP * 256; i += 256) repm[i] = 0.f;
        for (int e = tid; e < EE; e += 256) {
            int s = 0, r = 0;
            for (int n = 0; n < NN; ++n) {
                if (rel_send[e * NN + n] > 0.5f) s = n;
                if (rel_rec[e * NN + n] > 0.5f) r = n;
            }
            sidx[e] = s; ridx[e] = r;
        }
        __syncthreads();
        if (tid < NN) {
            int k = 0;
            for (int e = 0; e < EE; ++e)
                if (ridx[e] == tid) inc[tid * (NN - 1) + (k++)] = e;
        }
    } else if (b < 53) {     // transpose pred_w -> pwt[c][o]
        int idx = (b - 45) * 2048 + tid;
        for (int rep = 0; rep < 8; ++rep, idx += 256) {
            int o = idx >> 7, c = idx & 127;
            pwt[c * 128 + o] = pred_w[idx];
        }
    } else if (b < 117) {    // MLP weight packs: generic [128][K] -> A-frag-linear
        int idx = b - 53;    // 0..63
        const float* W; _Float16* dst; int K;
        if (idx < 8)       { W = m1w1; dst = mp + MP_M1W1; K = 128; }
        else if (idx < 16) { W = m1w2; dst = mp + MP_M1W2; K = 128; idx -= 8; }
        else if (idx < 24) { W = m2w1; dst = mp + MP_M2W1; K = 128; idx -= 16; }
        else if (idx < 32) { W = m2w2; dst = mp + MP_M2W2; K = 128; idx -= 24; }
        else if (idx < 40) { W = m3w2; dst = mp + MP_M3W2; K = 128; idx -= 32; }
        else               { W = m3w1; dst = mp + MP_M3W1; K = 384; idx -= 40; }
        int f = idx * 4 + (tid >> 6);
        int s = f >> 3, m0 = f & 7;
        int m = m0 * 16 + (l & 15);
        int cb = 32 * s + (l >> 4) * 8;
#pragma unroll
        for (int j = 0; j < 8; ++j)
            dst[(f * 64 + l) * 8 + j] = (_Float16)W[m * K + cb + j];
    } else {                 // w2 tap-sums: w2sum[co][ci] = sum_k w2[co][ci][k]
        int idx = (b - 117) * 2048 + tid;
        for (int rep = 0; rep < 8; ++rep, idx += 256) {
            const float* wr = w2 + idx * 5;
            w2sum[idx] = wr[0] + wr[1] + wr[2] + wr[3] + wr[4];
        }
    }
}

// ---------------- K1: conv1 (MFMA, direct-from-LDS B) + relu -> BN1 stats + PRE-BN maxpool ----------------
// pool-before-BN exact: bn1_g=1 -> BN scale>0 -> max commutes with fma.
__global__ __launch_bounds__(256) void k_conv1_stats(const float* __restrict__ inputs,
                                                     const _Float16* __restrict__ apack1,
                                                     const float* __restrict__ conv1_b,
                                                     const int* __restrict__ sidx,
                                                     const int* __restrict__ ridx,
                                                     float* rep1,
                                                     _Float16* __restrict__ y2p) {
    __shared__ __align__(16) _Float16 s_edgesT[104 * 8];
    __shared__ __align__(16) _Float16 s_y2t[48 * 136];
    int be = blockIdx.x;
    int b = be / EE, e = be - b * EE;
    int sn = sidx[e], rn = ridx[e];
    float* rep = rep1 + (be & (NREP - 1)) * 256;
    for (int i = threadIdx.x; i < 200; i += 256) {
        int side = (i >= 100) ? 1 : 0;
        int t = i - side * 100;
        int n = side ? rn : sn;
        float4 v = *(const float4*)(inputs + ((long long)(b * NN + n) * TT + t) * DD);
        f16x4 o = {(_Float16)v.x, (_Float16)v.y, (_Float16)v.z, (_Float16)v.w};
        *(f16x4*)(&s_edgesT[t * 8 + side * 4]) = o;
    }
    if (threadIdx.x < 32) s_edgesT[800 + threadIdx.x] = (_Float16)0.f;
    __syncthreads();
    int w = threadIdx.x >> 6, lane = threadIdx.x & 63;
    int quad = lane >> 4, l15 = lane & 15;
    f32x4 acc1[2][6];
#pragma unroll
    for (int m = 0; m < 2; ++m)
#pragma unroll
        for (int nt = 0; nt < 6; ++nt) acc1[m][nt] = (f32x4){0.f, 0.f, 0.f, 0.f};
    {
        const f16x8* Ap = (const f16x8*)apack1;
#pragma unroll
        for (int s = 0; s < 2; ++s) {
            f16x8 a0 = Ap[(s * 8 + 2 * w) * 64 + lane];
            f16x8 a1 = Ap[(s * 8 + 2 * w + 1) * 64 + lane];
#pragma unroll
            for (int nt = 0; nt < 6; ++nt) {
                f16x8 bfr = *(const f16x8*)(&s_edgesT[(nt * 16 + l15 + 4 * s + quad) * 8]);
                acc1[0][nt] = __builtin_amdgcn_mfma_f32_16x16x32_f16(a0, bfr, acc1[0][nt], 0, 0, 0);
                acc1[1][nt] = __builtin_amdgcn_mfma_f32_16x16x32_f16(a1, bfr, acc1[1][nt], 0, 0, 0);
            }
        }
    }
#pragma unroll
    for (int m = 0; m < 2; ++m) {
        int co0 = (2 * w + m) * 16 + quad * 4;
        float ss[4] = {0.f, 0.f, 0.f, 0.f}, qq[4] = {0.f, 0.f, 0.f, 0.f};
#pragma unroll
        for (int nt = 0; nt < 6; ++nt) {
            int t = nt * 16 + l15;
#pragma unroll
            for (int r = 0; r < 4; ++r) {
                float v = fmaxf(acc1[m][nt][r] + conv1_b[co0 + r], 0.f);
                ss[r] += v; qq[r] += v * v;
                float p = __shfl_xor(v, 1);
                if ((l15 & 1) == 0)
                    s_y2t[(t >> 1) * 136 + co0 + r] = (_Float16)fmaxf(v, p);
            }
        }
#pragma unroll
        for (int r = 0; r < 4; ++r) {
            float s = ss[r], q = qq[r];
            s += __shfl_xor(s, 1); s += __shfl_xor(s, 2); s += __shfl_xor(s, 4); s += __shfl_xor(s, 8);
            q += __shfl_xor(q, 1); q += __shfl_xor(q, 2); q += __shfl_xor(q, 4); q += __shfl_xor(q, 8);
            if (l15 == 0) {
                atomicAdd(&rep[co0 + r], s);
                atomicAdd(&rep[128 + co0 + r], q);
            }
        }
    }
    __syncthreads();
    _Float16* dst = y2p + (long long)be * 6144;
    for (int chunk = threadIdx.x; chunk < 768; chunk += 256) {
        int row = chunk >> 4, off = (chunk & 15) * 8;
        *(f16x8*)(dst + row * 128 + off) = *(const f16x8*)(&s_y2t[row * 136 + off]);
    }
}

// ---------------- finalize BN from 64 replicas -> scale/shift (re-zero replicas) ----------------
// (still used for BN2 only; MLP BN finalize is folded bit-identically into consumers)
__global__ void k_finalize_rep(float* __restrict__ rep, float* stats, int scIdx,
                               const float* __restrict__ g, const float* __restrict__ bb,
                               float inv_count) {
    int j = threadIdx.x;
    float s = 0.f, q = 0.f;
    for (int i = 0; i < NREP; ++i) {
        s += rep[i * 256 + j];
        q += rep[i * 256 + 128 + j];
    }
    for (int i = 0; i < NREP; ++i) {
        rep[i * 256 + j] = 0.f;
        rep[i * 256 + 128 + j] = 0.f;
    }
    float m = s * inv_count;
    float v = fmaxf(q * inv_count - m * m, 0.f);
    float sc = g[j] * rsqrtf(v + EPS);
    stats[scIdx + j] = sc;
    stats[scIdx + 128 + j] = bb[j] - m * sc;
}

// ---------------- finalize BN1 + conv2 fused bias2[co] = conv2_b + sum_ci w2sum*sh ----------------
// Valid: every conv2 output t uses all 5 taps (VALID conv over 48 rows).
__global__ void k_finalize_bn1(float* __restrict__ rep, float* stats,
                               const float* __restrict__ g, const float* __restrict__ bb,
                               const float* __restrict__ w2sum, const float* __restrict__ conv2_b,
                               float inv_count) {
    __shared__ float s_sh[128];
    int j = threadIdx.x;  // 128
    float s = 0.f, q = 0.f;
    for (int i = 0; i < NREP; ++i) {
        s += rep[i * 256 + j];
        q += rep[i * 256 + 128 + j];
    }
    for (int i = 0; i < NREP; ++i) {
        rep[i * 256 + j] = 0.f;
        rep[i * 256 + 128 + j] = 0.f;
    }
    float m = s * inv_count;
    float v = fmaxf(q * inv_count - m * m, 0.f);
    float sc = g[j] * rsqrtf(v + EPS);
    float sh = bb[j] - m * sc;
    stats[S_BN1_SC + j] = sc;
    stats[S_BN1_SC + 128 + j] = sh;
    s_sh[j] = sh;
    __syncthreads();
    float acc = conv2_b[j];
    for (int ci = 0; ci < 128; ++ci)
        acc = fmaf(w2sum[j * 128 + ci], s_sh[ci], acc);
    stats[S_BIAS2 + j] = acc;
}

// ---------------- K scale: apack *= BN1 scale (per input channel), in place ----------------
// Deterministic per call: k_prep rewrites apack raw before this every launch.
__global__ __launch_bounds__(256) void k_scale(_Float16* __restrict__ apack,
                                               const float* __restrict__ stats) {
    int tid = threadIdx.x, l = tid & 63;
    int f = blockIdx.x * 4 + (tid >> 6);
    int s = (f >> 3) & 3;
    int cbase = 32 * s + (l >> 4) * 8;
    _Float16* p = apack + (f * 64 + l) * 8;
#pragma unroll
    for (int j = 0; j < 8; ++j)
        p[j] = (_Float16)((float)p[j] * stats[S_BN1_SC + cbase + j]);
}

// ---------------- K3 (best-measured): 2 edges/block, 256 threads, 48-row clamp tile ----------------
// [FINAL plateau ledger: r1 4-edge ILP 161us; r2 8-thin-wave occ 58% 152us (2x LDS reads, same
//  time => not LDS-BW-bound); r3 reg pipeline SPILLED 650us; r4/r6 cross-session shows conv2
//  151us (fast session) vs 159us (slow session) for IDENTICAL code => setprio was noise, clock
//  variance ~5%. Bank conflicts 5.8M cyc / 1024 SIMD = 1.6% of runtime => not a lever.
//  151us invariant across occupancy/A-traffic/LDS-traffic/registers => structural plateau.]
__global__ __launch_bounds__(256) void k_conv2(_Float16* __restrict__ y23,
                                               const _Float16* __restrict__ apack,
                                               const float* __restrict__ stats,
                                               float* rep2) {
    __shared__ __align__(16) _Float16 s_y2t[2][48 * 136];
    int tid = threadIdx.x;
    int be0 = blockIdx.x * 2;
    for (int i = tid; i < 1536; i += 256) {
        int ed = i / 768, rem = i - ed * 768;
        int row = rem >> 4, c0 = (rem & 15) * 8;
        *(f16x8*)(&s_y2t[ed][row * 136 + c0]) =
            *(const f16x8*)(y23 + (long long)(be0 + ed) * 6144 + rem * 8);
    }
    __syncthreads();
    int w = tid >> 6, lane = tid & 63;
    int quad = lane >> 4, l15 = lane & 15;
    int g = w & 1, e = w >> 1;
    f32x4 acc[4][3];
#pragma unroll
    for (int m = 0; m < 4; ++m)
#pragma unroll
        for (int nt = 0; nt < 3; ++nt) acc[m][nt] = (f32x4){0.f, 0.f, 0.f, 0.f};
    const f16x8* Ap = (const f16x8*)apack;
    const char* base = (const char*)&s_y2t[e][0];
#pragma unroll
    for (int k = 0; k < 5; ++k) {
#pragma unroll
        for (int s = 0; s < 4; ++s) {
            f16x8 am[4];
#pragma unroll
            for (int m = 0; m < 4; ++m)
                am[m] = Ap[((k * 4 + s) * 8 + g * 4 + m) * 64 + lane];
#pragma unroll
            for (int nt = 0; nt < 3; ++nt) {
                int r = nt * 16 + l15 + k;
                if (nt == 2) r = (r > 47) ? 47 : r;   // clamp: t>=44 outputs are discarded
                f16x8 bfr = *(const f16x8*)(base + r * 272 + 64 * s + quad * 16);
#pragma unroll
                for (int m = 0; m < 4; ++m)
                    acc[m][nt] = __builtin_amdgcn_mfma_f32_16x16x32_f16(am[m], bfr, acc[m][nt], 0, 0, 0);
            }
        }
    }
    // epilogue: bias2 + relu, store y3 t-major [44][128] (f16x4), BN2 stats
    int be = be0 + e;
    _Float16* y3 = y23 + (long long)be * 6144;
    float* rep = rep2 + (be & (NREP - 1)) * 256;
#pragma unroll
    for (int m = 0; m < 4; ++m) {
        int co0 = (g * 4 + m) * 16 + quad * 4;
        float4 bs = *(const float4*)(stats + S_BIAS2 + co0);
        float ssum[4] = {0.f, 0.f, 0.f, 0.f}, qsum[4] = {0.f, 0.f, 0.f, 0.f};
#pragma unroll
        for (int nt = 0; nt < 3; ++nt) {
            int t = nt * 16 + l15;
            if (t < 44) {
                float v0 = fmaxf(acc[m][nt][0] + bs.x, 0.f);
                float v1 = fmaxf(acc[m][nt][1] + bs.y, 0.f);
                float v2 = fmaxf(acc[m][nt][2] + bs.z, 0.f);
                float v3 = fmaxf(acc[m][nt][3] + bs.w, 0.f);
                f16x4 o = {(_Float16)v0, (_Float16)v1, (_Float16)v2, (_Float16)v3};
                *(f16x4*)(y3 + t * 128 + co0) = o;
                ssum[0] += v0; qsum[0] += v0 * v0;
                ssum[1] += v1; qsum[1] += v1 * v1;
                ssum[2] += v2; qsum[2] += v2 * v2;
                ssum[3] += v3; qsum[3] += v3 * v3;
            }
        }
#pragma unroll
        for (int r = 0; r < 4; ++r) {
            float s = ssum[r], q = qsum[r];
            s += __shfl_xor(s, 1); s += __shfl_xor(s, 2); s += __shfl_xor(s, 4); s += __shfl_xor(s, 8);
            q += __shfl_xor(q, 1); q += __shfl_xor(q, 2); q += __shfl_xor(q, 4); q += __shfl_xor(q, 8);
            if (l15 == 0) {
                atomicAdd(&rep[co0 + r], s);
                atomicAdd(&rep[128 + co0 + r], q);
            }
        }
    }
}

// ---------------- K5: BN2 apply + attention-pool -> x [BE][128] (y3 t-major input) ----------------
// [r5 refactor (BN2-fold + pred GEMV -> MFMA in mlp1) measured +10us NET WORSE: the pred layer
//  moved into a 190-block kernel (<1 block/CU) whose serial-layer cost exceeded the VALU saved
//  here. Keeping the proven shape.]
__global__ __launch_bounds__(256) void k_predatt(const _Float16* __restrict__ y23,
                                                 const float* __restrict__ stats,
                                                 const float* __restrict__ att_w,
                                                 const float* __restrict__ att_b,
                                                 const float* __restrict__ pwt,
                                                 const float* __restrict__ pred_b,
                                                 float* __restrict__ x) {
    __shared__ float h[44 * 132];   // h[t][c], stride 132 (pad 4)
    __shared__ float s_att[48];
    __shared__ float s_p1[256];
    __shared__ float s_p2[256];
    __shared__ float s_sc[128], s_sh[128];
    int be = blockIdx.x, tid = threadIdx.x;
    if (tid < 128) {
        s_sc[tid] = stats[S_BN2_SC + tid];
        s_sh[tid] = stats[S_BN2_SC + 128 + tid];
    }
    __syncthreads();
    const _Float16* yp = y23 + (long long)be * 6144;
    for (int i = tid; i < 704; i += 256) {   // 44 rows x 16 chunks of 8
        int t = i >> 4, c0 = (i & 15) * 8;
        f16x8 v = *(const f16x8*)(yp + i * 8);
        float4 a, bq;
        a.x = fmaf((float)v[0], s_sc[c0 + 0], s_sh[c0 + 0]);
        a.y = fmaf((float)v[1], s_sc[c0 + 1], s_sh[c0 + 1]);
        a.z = fmaf((float)v[2], s_sc[c0 + 2], s_sh[c0 + 2]);
        a.w = fmaf((float)v[3], s_sc[c0 + 3], s_sh[c0 + 3]);
        bq.x = fmaf((float)v[4], s_sc[c0 + 4], s_sh[c0 + 4]);
        bq.y = fmaf((float)v[5], s_sc[c0 + 5], s_sh[c0 + 5]);
        bq.z = fmaf((float)v[6], s_sc[c0 + 6], s_sh[c0 + 6]);
        bq.w = fmaf((float)v[7], s_sc[c0 + 7], s_sh[c0 + 7]);
        *(float4*)(&h[t * 132 + c0]) = a;
        *(float4*)(&h[t * 132 + c0 + 4]) = bq;
    }
    __syncthreads();
    int w = tid >> 6, lane = tid & 63;
    {
        float aw0 = att_w[lane], aw1 = att_w[64 + lane];
        for (int tt = 0; tt < 11; ++tt) {
            int t = w * 11 + tt;
            float p = h[t * 132 + lane] * aw0 + h[t * 132 + 64 + lane] * aw1;
            p += __shfl_xor(p, 1); p += __shfl_xor(p, 2); p += __shfl_xor(p, 4);
            p += __shfl_xor(p, 8); p += __shfl_xor(p, 16); p += __shfl_xor(p, 32);
            if (lane == 0) s_att[t] = p + att_b[0];
        }
    }
    __syncthreads();
    if (w == 0) {
        float v = (lane < 44) ? s_att[lane] : -1e30f;
        float m = v;
        m = fmaxf(m, __shfl_xor(m, 1)); m = fmaxf(m, __shfl_xor(m, 2));
        m = fmaxf(m, __shfl_xor(m, 4)); m = fmaxf(m, __shfl_xor(m, 8));
        m = fmaxf(m, __shfl_xor(m, 16)); m = fmaxf(m, __shfl_xor(m, 32));
        float ev = (lane < 44) ? expf(v - m) : 0.f;
        float ss = ev;
        ss += __shfl_xor(ss, 1); ss += __shfl_xor(ss, 2); ss += __shfl_xor(ss, 4);
        ss += __shfl_xor(ss, 8); ss += __shfl_xor(ss, 16); ss += __shfl_xor(ss, 32);
        if (lane < 44) s_att[lane] = ev / ss;
    }
    __syncthreads();
    {
        int c = tid & 127, hh = tid >> 7;
        float a = 0.f;
        for (int t = hh * 22; t < hh * 22 + 22; ++t) a = fmaf(h[t * 132 + c], s_att[t], a);
        s_p1[tid] = a;
    }
    __syncthreads();
    {
        int o = tid & 127, hh = tid >> 7;
        float a = 0.f;
        for (int c = hh * 64; c < hh * 64 + 64; ++c) {
            float hw = s_p1[c] + s_p1[128 + c];
            a = fmaf(pwt[c * 128 + o], hw, a);
        }
        s_p2[tid] = a;
    }
    __syncthreads();
    if (tid < 128) {
        float a = s_p2[tid] + s_p2[128 + tid] + pred_b[tid];
        x[(long long)be * 128 + tid] = a * (1.0f / 44.0f);
    }
}

// ---------------- fused 2-layer MFMA MLP (128->128->128), 64 rows/block ----------------
// in f32 -> L1(ELU) kept in LDS f16 -> L2(ELU) -> out f32 + fused col stats.
__global__ __launch_bounds__(256) void k_mlp2x(const float* __restrict__ in,
                                               const _Float16* __restrict__ wp1,
                                               const float* __restrict__ b1,
                                               const _Float16* __restrict__ wp2,
                                               const float* __restrict__ b2,
                                               float* __restrict__ out,
                                               float* __restrict__ repm) {
    __shared__ __align__(16) _Float16 s_in[64 * 136];
    __shared__ __align__(16) _Float16 s_mid[64 * 136];
    int tid = threadIdx.x;
    long long r0 = (long long)blockIdx.x * 64;
    {
        const float4* src = (const float4*)(in + r0 * 128);
        for (int i = tid; i < 2048; i += 256) {
            int row = i >> 5, c0 = (i & 31) * 4;
            float4 v = src[i];
            f16x4 o = {(_Float16)v.x, (_Float16)v.y, (_Float16)v.z, (_Float16)v.w};
            *(f16x4*)(&s_in[row * 136 + c0]) = o;
        }
    }
    __syncthreads();
    int w = tid >> 6, lane = tid & 63, quad = lane >> 4, l15 = lane & 15;
    // layer 1
    {
        f32x4 acc[2][4];
#pragma unroll
        for (int m = 0; m < 2; ++m)
#pragma unroll
            for (int nt = 0; nt < 4; ++nt) acc[m][nt] = (f32x4){0.f, 0.f, 0.f, 0.f};
        const f16x8* Ap = (const f16x8*)wp1;
#pragma unroll
        for (int s = 0; s < 4; ++s) {
            f16x8 a0 = Ap[(s * 8 + 2 * w) * 64 + lane];
            f16x8 a1 = Ap[(s * 8 + 2 * w + 1) * 64 + lane];
#pragma unroll
            for (int nt = 0; nt < 4; ++nt) {
                f16x8 bfr = *(const f16x8*)((const char*)s_in + (nt * 16 + l15) * 272 + 64 * s + quad * 16);
                acc[0][nt] = __builtin_amdgcn_mfma_f32_16x16x32_f16(a0, bfr, acc[0][nt], 0, 0, 0);
                acc[1][nt] = __builtin_amdgcn_mfma_f32_16x16x32_f16(a1, bfr, acc[1][nt], 0, 0, 0);
            }
        }
#pragma unroll
        for (int m = 0; m < 2; ++m) {
            int j0 = (2 * w + m) * 16 + quad * 4;
            float4 bs = *(const float4*)(b1 + j0);
#pragma unroll
            for (int nt = 0; nt < 4; ++nt) {
                int row = nt * 16 + l15;
                f16x4 o = {(_Float16)eluf(acc[m][nt][0] + bs.x),
                           (_Float16)eluf(acc[m][nt][1] + bs.y),
                           (_Float16)eluf(acc[m][nt][2] + bs.z),
                           (_Float16)eluf(acc[m][nt][3] + bs.w)};
                *(f16x4*)(&s_mid[row * 136 + j0]) = o;
            }
        }
    }
    __syncthreads();
    // layer 2 + stats
    {
        f32x4 acc[2][4];
#pragma unroll
        for (int m = 0; m < 2; ++m)
#pragma unroll
            for (int nt = 0; nt < 4; ++nt) acc[m][nt] = (f32x4){0.f, 0.f, 0.f, 0.f};
        const f16x8* Ap = (const f16x8*)wp2;
#pragma unroll
        for (int s = 0; s < 4; ++s) {
            f16x8 a0 = Ap[(s * 8 + 2 * w) * 64 + lane];
            f16x8 a1 = Ap[(s * 8 + 2 * w + 1) * 64 + lane];
#pragma unroll
            for (int nt = 0; nt < 4; ++nt) {
                f16x8 bfr = *(const f16x8*)((const char*)s_mid + (nt * 16 + l15) * 272 + 64 * s + quad * 16);
                acc[0][nt] = __builtin_amdgcn_mfma_f32_16x16x32_f16(a0, bfr, acc[0][nt], 0, 0, 0);
                acc[1][nt] = __builtin_amdgcn_mfma_f32_16x16x32_f16(a1, bfr, acc[1][nt], 0, 0, 0);
            }
        }
#pragma unroll
        for (int m = 0; m < 2; ++m) {
            int j0 = (2 * w + m) * 16 + quad * 4;
            float4 bs = *(const float4*)(b2 + j0);
            float ss[4] = {0.f, 0.f, 0.f, 0.f}, qq[4] = {0.f, 0.f, 0.f, 0.f};
#pragma unroll
            for (int nt = 0; nt < 4; ++nt) {
                int row = nt * 16 + l15;
                float v0 = eluf(acc[m][nt][0] + bs.x);
                float v1 = eluf(acc[m][nt][1] + bs.y);
                float v2 = eluf(acc[m][nt][2] + bs.z);
                float v3 = eluf(acc[m][nt][3] + bs.w);
                float4 o = {v0, v1, v2, v3};
                *(float4*)(out + (r0 + row) * 128 + j0) = o;
                ss[0] += v0; qq[0] += v0 * v0;
                ss[1] += v1; qq[1] += v1 * v1;
                ss[2] += v2; qq[2] += v2 * v2;
                ss[3] += v3; qq[3] += v3 * v3;
            }
            float* rep = repm + (blockIdx.x & (NREP - 1)) * 256;
#pragma unroll
            for (int r = 0; r < 4; ++r) {
                float s = ss[r], q = qq[r];
                s += __shfl_xor(s, 1); s += __shfl_xor(s, 2); s += __shfl_xor(s, 4); s += __shfl_xor(s, 8);
                q += __shfl_xor(q, 1); q += __shfl_xor(q, 2); q += __shfl_xor(q, 4); q += __shfl_xor(q, 8);
                if (l15 == 0) {
                    atomicAdd(&rep[j0 + r], s);
                    atomicAdd(&rep[128 + j0 + r], q);
                }
            }
        }
    }
}

// ---------------- fused mlp3: gather-concat [send|recv|skip] (K=384) -> L1(ELU, LDS) -> L2(ELU) -> f32 + stats ----
// BN-M1/BN-M2 finalize folded in (bit-identical to k_finalize_rep: same i-order, rsqrtf).
__global__ __launch_bounds__(256) void k_mlp3x(const float* __restrict__ xn,
                                               const float* __restrict__ bufB,
                                               const int* __restrict__ sidx,
                                               const int* __restrict__ ridx,
                                               const float* __restrict__ repm1,
                                               const float* __restrict__ repm2,
                                               const float* __restrict__ m1g,
                                               const float* __restrict__ m1bb,
                                               const float* __restrict__ m2g,
                                               const float* __restrict__ m2bb,
                                               const _Float16* __restrict__ wp1,
                                               const float* __restrict__ b1,
                                               const _Float16* __restrict__ wp2,
                                               const float* __restrict__ b2,
                                               float* __restrict__ out,
                                               float* __restrict__ repm3) {
    __shared__ __align__(16) _Float16 s_b[64 * 392];
    __shared__ __align__(16) _Float16 s_mid[64 * 136];
    __shared__ float s_st[4][128];
    __shared__ int s_s[64], s_r[64];
    int tid = threadIdx.x;
    long long r0 = (long long)blockIdx.x * 64;
    if (tid < 128) {
        float s = 0.f, q = 0.f;
        for (int i = 0; i < NREP; ++i) {
            s += repm2[i * 256 + tid];
            q += repm2[i * 256 + 128 + tid];
        }
        float mm = s * (1.0f / (float)(BB * NN));
        float vv = fmaxf(q * (1.0f / (float)(BB * NN)) - mm * mm, 0.f);
        float sc = m2g[tid] * rsqrtf(vv + EPS);
        s_st[0][tid] = sc;
        s_st[1][tid] = m2bb[tid] - mm * sc;
        s = 0.f; q = 0.f;
        for (int i = 0; i < NREP; ++i) {
            s += repm1[i * 256 + tid];
            q += repm1[i * 256 + 128 + tid];
        }
        mm = s * (1.0f / (float)BE);
        vv = fmaxf(q * (1.0f / (float)BE) - mm * mm, 0.f);
        sc = m1g[tid] * rsqrtf(vv + EPS);
        s_st[2][tid] = sc;
        s_st[3][tid] = m1bb[tid] - mm * sc;
    }
    if (tid < 64) {
        int r = (int)r0 + tid, b = r / EE, ed = r - b * EE;
        s_s[tid] = (b * NN + sidx[ed]) * 128;
        s_r[tid] = (b * NN + ridx[ed]) * 128;
    }
    __syncthreads();
    for (int i = tid; i < 8192; i += 256) {
        int row = i >> 7, j = i & 127;
        float sc2 = s_st[0][j], sh2 = s_st[1][j];
        s_b[row * 392 + j] = (_Float16)fmaf(xn[s_s[row] + j], sc2, sh2);
        s_b[row * 392 + 128 + j] = (_Float16)fmaf(xn[s_r[row] + j], sc2, sh2);
        s_b[row * 392 + 256 + j] = (_Float16)fmaf(bufB[(r0 + row) * 128 + j], s_st[2][j], s_st[3][j]);
    }
    __syncthreads();
    int w = tid >> 6, lane = tid & 63, quad = lane >> 4, l15 = lane & 15;
    // layer 1 (K=384)
    {
        f32x4 acc[2][4];
#pragma unroll
        for (int m = 0; m < 2; ++m)
#pragma unroll
            for (int nt = 0; nt < 4; ++nt) acc[m][nt] = (f32x4){0.f, 0.f, 0.f, 0.f};
        const f16x8* Ap = (const f16x8*)wp1;
#pragma unroll
        for (int s = 0; s < 12; ++s) {
            f16x8 a0 = Ap[(s * 8 + 2 * w) * 64 + lane];
            f16x8 a1 = Ap[(s * 8 + 2 * w + 1) * 64 + lane];
#pragma unroll
            for (int nt = 0; nt < 4; ++nt) {
                f16x8 bfr = *(const f16x8*)((const char*)s_b + (nt * 16 + l15) * 784 + 64 * s + quad * 16);
                acc[0][nt] = __builtin_amdgcn_mfma_f32_16x16x32_f16(a0, bfr, acc[0][nt], 0, 0, 0);
                acc[1][nt] = __builtin_amdgcn_mfma_f32_16x16x32_f16(a1, bfr, acc[1][nt], 0, 0, 0);
            }
        }
#pragma unroll
        for (int m = 0; m < 2; ++m) {
            int j0 = (2 * w + m) * 16 + quad * 4;
            float4 bs = *(const float4*)(b1 + j0);
#pragma unroll
            for (int nt = 0; nt < 4; ++nt) {
                int row = nt * 16 + l15;
                f16x4 o = {(_Float16)eluf(acc[m][nt][0] + bs.x),
                           (_Float16)eluf(acc[m][nt][1] + bs.y),
                           (_Float16)eluf(acc[m][nt][2] + bs.z),
                           (_Float16)eluf(acc[m][nt][3] + bs.w)};
                *(f16x4*)(&s_mid[row * 136 + j0]) = o;
            }
        }
    }
    __syncthreads();
    // layer 2 + stats
    {
        f32x4 acc[2][4];
#pragma unroll
        for (int m = 0; m < 2; ++m)
#pragma unroll
            for (int nt = 0; nt < 4; ++nt) acc[m][nt] = (f32x4){0.f, 0.f, 0.f, 0.f};
        const f16x8* Ap = (const f16x8*)wp2;
#pragma unroll
        for (int s = 0; s < 4; ++s) {
            f16x8 a0 = Ap[(s * 8 + 2 * w) * 64 + lane];
            f16x8 a1 = Ap[(s * 8 + 2 * w + 1) * 64 + lane];
#pragma unroll
            for (int nt = 0; nt < 4; ++nt) {
                f16x8 bfr = *(const f16x8*)((const char*)s_mid + (nt * 16 + l15) * 272 + 64 * s + quad * 16);
                acc[0][nt] = __builtin_amdgcn_mfma_f32_16x16x32_f16(a0, bfr, acc[0][nt], 0, 0, 0);
                acc[1][nt] = __builtin_amdgcn_mfma_f32_16x16x32_f16(a1, bfr, acc[1][nt], 0, 0, 0);
            }
        }
#pragma unroll
        for (int m = 0; m < 2; ++m) {
            int j0 = (2 * w + m) * 16 + quad * 4;
            float4 bs = *(const float4*)(b2 + j0);
            float ss[4] = {0.f, 0.f, 0.f, 0.f}, qq[4] = {0.f, 0.f, 0.f, 0.f};
#pragma unroll
            for (int nt = 0; nt < 4; ++nt) {
                int row = nt * 16 + l15;
                float v0 = eluf(acc[m][nt][0] + bs.x);
                float v1 = eluf(acc[m][nt][1] + bs.y);
                float v2 = eluf(acc[m][nt][2] + bs.z);
                float v3 = eluf(acc[m][nt][3] + bs.w);
                float4 o = {v0, v1, v2, v3};
                *(float4*)(out + (r0 + row) * 128 + j0) = o;
                ss[0] += v0; qq[0] += v0 * v0;
                ss[1] += v1; qq[1] += v1 * v1;
                ss[2] += v2; qq[2] += v2 * v2;
                ss[3] += v3; qq[3] += v3 * v3;
            }
            float* rep = repm3 + (blockIdx.x & (NREP - 1)) * 256;
#pragma unroll
            for (int r = 0; r < 4; ++r) {
                float s = ss[r], q = qq[r];
                s += __shfl_xor(s, 1); s += __shfl_xor(s, 2); s += __shfl_xor(s, 4); s += __shfl_xor(s, 8);
                q += __shfl_xor(q, 1); q += __shfl_xor(q, 2); q += __shfl_xor(q, 4); q += __shfl_xor(q, 8);
                if (l15 == 0) {
                    atomicAdd(&rep[j0 + r], s);
                    atomicAdd(&rep[128 + j0 + r], q);
                }
            }
        }
    }
}

// ---------------- edge2node scatter-mean with inline BN-M1 (finalize folded, bit-identical) ----------------
__global__ __launch_bounds__(128) void k_e2n(const float* __restrict__ bufB,
                                             const int* __restrict__ inc,
                                             const float* __restrict__ repm1,
                                             const float* __restrict__ m1g,
                                             const float* __restrict__ m1bb,
                                             float* __restrict__ xn) {
    int bn = blockIdx.x;
    int b = bn / NN, n = bn - b * NN;
    int j = threadIdx.x;
    float s0 = 0.f, q0 = 0.f;
    for (int i = 0; i < NREP; ++i) {
        s0 += repm1[i * 256 + j];
        q0 += repm1[i * 256 + 128 + j];
    }
    float mm = s0 * (1.0f / (float)BE);
    float vv = fmaxf(q0 * (1.0f / (float)BE) - mm * mm, 0.f);
    float sc = m1g[j] * rsqrtf(vv + EPS);
    float sh = m1bb[j] - mm * sc;
    float s = 0.f;
    for (int k = 0; k < NN - 1; ++k) {
        int e = inc[n * (NN - 1) + k];
        s += bufB[(long long)(b * EE + e) * 128 + j];
    }
    xn[bn * 128 + j] = (s * sc + (float)(NN - 1) * sh) * (1.0f / (float)NN);
}

// ---------------- BN3 apply + fc_out (128 -> 16); BN-M3 finalize folded (bit-identical) ----------------
__global__ __launch_bounds__(256) void k_fcout(const float* __restrict__ h2,
                                               const float* __restrict__ repm3,
                                               const float* __restrict__ m3g,
                                               const float* __restrict__ m3bb,
                                               const float* __restrict__ fcw,
                                               const float* __restrict__ fcb,
                                               float* __restrict__ out) {
    __shared__ float s_x[16 * 129];
    __shared__ float s_w[16 * 129];
    __shared__ float s_sc[128], s_sh[128];
    int r0 = blockIdx.x * 16;
    int tid = threadIdx.x;
    if (tid < 128) {
        float s = 0.f, q = 0.f;
        for (int i = 0; i < NREP; ++i) {
            s += repm3[i * 256 + tid];
            q += repm3[i * 256 + 128 + tid];
        }
        float mm = s * (1.0f / (float)BE);
        float vv = fmaxf(q * (1.0f / (float)BE) - mm * mm, 0.f);
        float sc = m3g[tid] * rsqrtf(vv + EPS);
        s_sc[tid] = sc;
        s_sh[tid] = m3bb[tid] - mm * sc;
    }
    __syncthreads();
    for (int i = tid; i < 16 * 128; i += 256) {
        int rr = i >> 7, j = i & 127;
        s_x[rr * 129 + j] = fmaf(h2[(long long)(r0 + rr) * 128 + j], s_sc[j], s_sh[j]);
    }
    for (int i = tid; i < 16 * 128; i += 256) {
        int o = i >> 7, j = i & 127;
        s_w[o * 129 + j] = fcw[i];
    }
    __syncthreads();
    int rl = tid >> 4, o = tid & 15;
    float a = fcb[o];
    for (int j = 0; j < 128; ++j) a = fmaf(s_x[rl * 129 + j], s_w[o * 129 + j], a);
    out[(long long)(r0 + rl) * 16 + o] = a;
}

// ---------------- host launcher ----------------
extern "C" void kernel_launch(void* const* d_in, const int* in_sizes, int n_in,
                              void* d_out, int out_size, void* d_ws, size_t ws_size,
                              hipStream_t stream) {
    const float* inputs = (const float*)d_in[0];
    const float* rel_rec = (const float*)d_in[1];
    const float* rel_send = (const float*)d_in[2];
    const float* conv1_w = (const float*)d_in[3];
    const float* conv1_b = (const float*)d_in[4];
    const float* bn1_g = (const float*)d_in[5];
    const float* bn1_b = (const float*)d_in[6];
    const float* conv2_w = (const float*)d_in[7];
    const float* conv2_b = (const float*)d_in[8];
    const float* bn2_g = (const float*)d_in[9];
    const float* bn2_b = (const float*)d_in[10];
    const float* pred_w = (const float*)d_in[11];
    const float* pred_b = (const float*)d_in[12];
    const float* att_w = (const float*)d_in[13];
    const float* att_b = (const float*)d_in[14];
    const float* m1w1 = (const float*)d_in[15];
    const float* m1b1 = (const float*)d_in[16];
    const float* m1w2 = (const float*)d_in[17];
    const float* m1b2 = (const float*)d_in[18];
    const float* m1g = (const float*)d_in[19];
    const float* m1bb = (const float*)d_in[20];
    const float* m2w1 = (const float*)d_in[21];
    const float* m2b1 = (const float*)d_in[22];
    const float* m2w2 = (const float*)d_in[23];
    const float* m2b2 = (const float*)d_in[24];
    const float* m2g = (const float*)d_in[25];
    const float* m2bb = (const float*)d_in[26];
    const float* m3w1 = (const float*)d_in[27];
    const float* m3b1 = (const float*)d_in[28];
    const float* m3w2 = (const float*)d_in[29];
    const float* m3b2 = (const float*)d_in[30];
    const float* m3g = (const float*)d_in[31];
    const float* m3bb = (const float*)d_in[32];
    const float* fcw = (const float*)d_in[33];
    const float* fcb = (const float*)d_in[34];

    char* ws = (char*)d_ws;
    float* stats = (float*)(ws + OFF_STATS);
    int* sidx = (int*)(ws + OFF_SIDX);
    int* ridx = (int*)(ws + OFF_RIDX);
    int* inc = (int*)(ws + OFF_INC);
    _Float16* y23 = (_Float16*)(ws + OFF_Y23);
    float* x = (float*)(ws + OFF_X);
    float* bufB = (float*)(ws + OFF_BUFB);
    float* xn = (float*)(ws + OFF_XN);
    _Float16* apack = (_Float16*)(ws + OFF_APACK);
    _Float16* apack1 = (_Float16*)(ws + OFF_APACK1);
    float* pwt = (float*)(ws + OFF_PWT);
    float* w2sum = (float*)(ws + OFF_W2SUM);
    float* rep1 = (float*)(ws + OFF_REP1);
    float* rep2 = (float*)(ws + OFF_REP2);
    float* repm1 = (float*)(ws + OFF_REPM);
    float* repm2 = (float*)(ws + OFF_REPM + 65536ULL);
    float* repm3 = (float*)(ws + OFF_REPM + 131072ULL);
    _Float16* mp = (_Float16*)(ws + OFF_MP);
    float* outp = (float*)d_out;

    hipLaunchKernelGGL(k_prep, dim3(125), dim3(256), 0, stream,
                       rel_rec, rel_send, conv2_w, conv1_w, pred_w,
                       m1w1, m1w2, m2w1, m2w2, m3w1, m3w2,
                       apack, apack1, pwt, w2sum, mp, rep1, rep2, repm1, sidx, ridx, inc);
    hipLaunchKernelGGL(k_conv1_stats, dim3(BE), dim3(256), 0, stream,
                       inputs, apack1, conv1_b, sidx, ridx, rep1, y23);
    hipLaunchKernelGGL(k_finalize_bn1, dim3(1), dim3(128), 0, stream,
                       rep1, stats, bn1_g, bn1_b, w2sum, conv2_b, 1.0f / (float)(BE * L1));
    hipLaunchKernelGGL(k_scale, dim3(40), dim3(256), 0, stream, apack, stats);
    hipLaunchKernelGGL(k_conv2, dim3(BE / 2), dim3(256), 0, stream,
                       y23, apack, stats, rep2);
    hipLaunchKernelGGL(k_finalize_rep, dim3(1), dim3(128), 0, stream,
                       rep2, stats, S_BN2_SC, bn2_g, bn2_b, 1.0f / (float)(BE * L2));
    hipLaunchKernelGGL(k_predatt, dim3(BE), dim3(256), 0, stream,
                       y23, stats, att_w, att_b, pwt, pred_b, x);
    // mlp1 (fused 2-layer MFMA) -> stats into repm1 (finalize folded into consumers)
    hipLaunchKernelGGL(k_mlp2x, dim3(BE / 64), dim3(256), 0, stream,
                       x, mp + MP_M1W1, m1b1, mp + MP_M1W2, m1b2, bufB, repm1);
    // edge2node (BN-M1 inline, finalize folded) + mlp2 (fused) -> stats into repm2
    hipLaunchKernelGGL(k_e2n, dim3(BB * NN), dim3(128), 0, stream, bufB, inc, repm1, m1g, m1bb, xn);
    hipLaunchKernelGGL(k_mlp2x, dim3(BB * NN / 64), dim3(256), 0, stream,
                       xn, mp + MP_M2W1, m2b1, mp + MP_M2W2, m2b2, xn, repm2);
    // node2edge + mlp3 (fused gather + 2-layer; BN-M1/M2 finalize folded) -> stats into repm3
    hipLaunchKernelGGL(k_mlp3x, dim3(BE / 64), dim3(256), 0, stream,
                       xn, bufB, sidx, ridx, repm1, repm2, m1g, m1bb, m2g, m2bb,
                       mp + MP_M3W1, m3b1, mp + MP_M3W2, m3b2, bufB, repm3);
    // fc_out (BN-M3 inline, finalize folded)
    hipLaunchKernelGGL(k_fcout, dim3(BE / 16), dim3(256), 0, stream,
                       bufB, repm3, m3g, m3bb, fcw, fcb, outp);
    (void)in_sizes; (void)n_in; (void)out_size; (void)ws_size;
}

// Round 8
// 567.081 us; speedup vs baseline: 1.0929x; 1.0370x over previous
//
#include <hip/hip_runtime.h>
#include <hip/hip_bf16.h>
#include <hip/hip_fp16.h>

// ---------------- problem constants ----------------
#define BB 32
#define NN 20
#define TT 100
#define DD 4
#define HH 128
#define EE 380          // N*(N-1)
#define BE 12160        // B*E
#define L1 96           // conv1 out length
#define LP 48           // after maxpool
#define L2 44           // conv2 out length
#define NOUT 16
#define EPS 1e-5f
#define NREP 64         // stats replicas (atomic de-contention)

typedef _Float16 f16x8 __attribute__((ext_vector_type(8)));
typedef _Float16 f16x4 __attribute__((ext_vector_type(4)));
typedef _Float16 f16x2 __attribute__((ext_vector_type(2)));
typedef float f32x4 __attribute__((ext_vector_type(4)));

// stats slot indices (floats): SC at base, SH at base+128. Slots 0..127 = conv2 bias2 (BN1-fold).
#define S_BIAS2 0
#define S_BN1_SC 256
#define S_BN2_SC 768

// workspace offsets (bytes)
#define OFF_STATS 0ULL
#define OFF_SIDX 16384ULL
#define OFF_RIDX 18432ULL
#define OFF_INC 20480ULL
#define OFF_Y23 24576ULL                     // f16 [BE] slots of 6144: y3 t-major [44][128] (y2 no longer materialized)
#define OFF_X 149446656ULL                   // f32 [BE][128]
#define OFF_BUFA 155672576ULL                // f32 [BE][128]; rep1/rep2 live here during conv phase
#define OFF_BUFB 161898496ULL                // f32 [BE][128]
#define OFF_XN 168124416ULL                  // f32 [640][128]
#define OFF_T640 168452096ULL                // conv-phase: apack(160K)+apack1(16K)+pwt(64K)+w2sum(64K)
#define OFF_REPM 168779776ULL                // f32 3x[64][256] MLP stats replicas (repm1/repm2/repm3)
#define OFF_MP 171958272ULL                  // f16 MLP weight packs (256 KB)
#define OFF_APACK OFF_T640
#define OFF_APACK1 (OFF_T640 + 163840ULL)
#define OFF_PWT (OFF_T640 + 180224ULL)
#define OFF_W2SUM (OFF_T640 + 245760ULL)
#define OFF_REP1 OFF_BUFA
#define OFF_REP2 (OFF_BUFA + 65536ULL)
// MP pack offsets in f16 units
#define MP_M1W1 0
#define MP_M1W2 16384
#define MP_M2W1 32768
#define MP_M2W2 49152
#define MP_M3W2 65536
#define MP_M3W1 81920

__device__ __forceinline__ float eluf(float v) { return v > 0.f ? v : expm1f(v); }

// ---------------- K prep: pack all MFMA weights, transpose pred_w, w2 tap-sums, init tables ----------------
// conv1 A-pack K-order c' = k*8 + ci (direct-from-time-major B, no im2col).
__global__ __launch_bounds__(256) void k_prep(const float* __restrict__ rel_rec,
                                              const float* __restrict__ rel_send,
                                              const float* __restrict__ w2,
                                              const float* __restrict__ w1,
                                              const float* __restrict__ pred_w,
                                              const float* __restrict__ m1w1,
                                              const float* __restrict__ m1w2,
                                              const float* __restrict__ m2w1,
                                              const float* __restrict__ m2w2,
                                              const float* __restrict__ m3w1,
                                              const float* __restrict__ m3w2,
                                              _Float16* __restrict__ apack,
                                              _Float16* __restrict__ apack1,
                                              float* __restrict__ pwt,
                                              float* __restrict__ w2sum,
                                              _Float16* __restrict__ mp,
                                              float* rep1, float* rep2, float* repm,
                                              int* sidx, int* ridx, int* inc) {
    int b = blockIdx.x;
    int tid = threadIdx.x;
    int l = tid & 63;
    if (b < 40) {            // conv2_w frags (raw; BN1 scale applied later by k_scale)
        int f = b * 4 + (tid >> 6);
        int m0 = f & 7, ks = f >> 3, s = ks & 3, k = ks >> 2;
        int m = m0 * 16 + (l & 15);
        int cbase = 32 * s + (l >> 4) * 8;
#pragma unroll
        for (int j = 0; j < 8; ++j)
            apack[(f * 64 + l) * 8 + j] = (_Float16)w2[m * 640 + (cbase + j) * 5 + k];
    } else if (b < 44) {     // conv1_w frags: c' = k*8+ci, taps k>=5 zero-padded
        int f = (b - 40) * 4 + (tid >> 6);
        int m0 = f & 7, s = f >> 3;
        int m = m0 * 16 + (l & 15);
        int cbase = 32 * s + (l >> 4) * 8;
#pragma unroll
        for (int j = 0; j < 8; ++j) {
            int c = cbase + j;
            int k = c >> 3, ci = c & 7;
            apack1[(f * 64 + l) * 8 + j] = (k < 5) ? (_Float16)w1[m * 40 + ci * 5 + k]
                                                   : (_Float16)0.f;
        }
    } else if (b == 44) {    // init: zero replicas (incl. 3 MLP replica sets), build edge tables
        for (int i = tid; i < NREP * 256; i += 256) { rep1[i] = 0.f; rep2[i] = 0.f; }
        for (int i = tid; i < 3 * NREP * 256; i += 256) repm[i] = 0.f;
        for (int e = tid; e < EE; e += 256) {
            int s = 0, r = 0;
            for (int n = 0; n < NN; ++n) {
                if (rel_send[e * NN + n] > 0.5f) s = n;
                if (rel_rec[e * NN + n] > 0.5f) r = n;
            }
            sidx[e] = s; ridx[e] = r;
        }
        __syncthreads();
        if (tid < NN) {
            int k = 0;
            for (int e = 0; e < EE; ++e)
                if (ridx[e] == tid) inc[tid * (NN - 1) + (k++)] = e;
        }
    } else if (b < 53) {     // transpose pred_w -> pwt[c][o]
        int idx = (b - 45) * 2048 + tid;
        for (int rep = 0; rep < 8; ++rep, idx += 256) {
            int o = idx >> 7, c = idx & 127;
            pwt[c * 128 + o] = pred_w[idx];
        }
    } else if (b < 117) {    // MLP weight packs: generic [128][K] -> A-frag-linear
        int idx = b - 53;    // 0..63
        const float* W; _Float16* dst; int K;
        if (idx < 8)       { W = m1w1; dst = mp + MP_M1W1; K = 128; }
        else if (idx < 16) { W = m1w2; dst = mp + MP_M1W2; K = 128; idx -= 8; }
        else if (idx < 24) { W = m2w1; dst = mp + MP_M2W1; K = 128; idx -= 16; }
        else if (idx < 32) { W = m2w2; dst = mp + MP_M2W2; K = 128; idx -= 24; }
        else if (idx < 40) { W = m3w2; dst = mp + MP_M3W2; K = 128; idx -= 32; }
        else               { W = m3w1; dst = mp + MP_M3W1; K = 384; idx -= 40; }
        int f = idx * 4 + (tid >> 6);
        int s = f >> 3, m0 = f & 7;
        int m = m0 * 16 + (l & 15);
        int cb = 32 * s + (l >> 4) * 8;
#pragma unroll
        for (int j = 0; j < 8; ++j)
            dst[(f * 64 + l) * 8 + j] = (_Float16)W[m * K + cb + j];
    } else {                 // w2 tap-sums: w2sum[co][ci] = sum_k w2[co][ci][k]
        int idx = (b - 117) * 2048 + tid;
        for (int rep = 0; rep < 8; ++rep, idx += 256) {
            const float* wr = w2 + idx * 5;
            w2sum[idx] = wr[0] + wr[1] + wr[2] + wr[3] + wr[4];
        }
    }
}

// ---------------- K1: conv1 (MFMA) + relu -> BN1 stats ONLY (y2 no longer written to global;
// conv2 recomputes conv1 from the 1MB L2-resident inputs). Stats math bit-identical to before
// (ss/qq accumulate pre-pool v in the same order); pool/LDS/global-write phases removed. ----------------
__global__ __launch_bounds__(256) void k_conv1_stats(const float* __restrict__ inputs,
                                                     const _Float16* __restrict__ apack1,
                                                     const float* __restrict__ conv1_b,
                                                     const int* __restrict__ sidx,
                                                     const int* __restrict__ ridx,
                                                     float* rep1) {
    __shared__ __align__(16) _Float16 s_edgesT[104 * 8];
    int be = blockIdx.x;
    int b = be / EE, e = be - b * EE;
    int sn = sidx[e], rn = ridx[e];
    float* rep = rep1 + (be & (NREP - 1)) * 256;
    for (int i = threadIdx.x; i < 200; i += 256) {
        int side = (i >= 100) ? 1 : 0;
        int t = i - side * 100;
        int n = side ? rn : sn;
        float4 v = *(const float4*)(inputs + ((long long)(b * NN + n) * TT + t) * DD);
        f16x4 o = {(_Float16)v.x, (_Float16)v.y, (_Float16)v.z, (_Float16)v.w};
        *(f16x4*)(&s_edgesT[t * 8 + side * 4]) = o;
    }
    if (threadIdx.x < 32) s_edgesT[800 + threadIdx.x] = (_Float16)0.f;
    __syncthreads();
    int w = threadIdx.x >> 6, lane = threadIdx.x & 63;
    int quad = lane >> 4, l15 = lane & 15;
    f32x4 acc1[2][6];
#pragma unroll
    for (int m = 0; m < 2; ++m)
#pragma unroll
        for (int nt = 0; nt < 6; ++nt) acc1[m][nt] = (f32x4){0.f, 0.f, 0.f, 0.f};
    {
        const f16x8* Ap = (const f16x8*)apack1;
#pragma unroll
        for (int s = 0; s < 2; ++s) {
            f16x8 a0 = Ap[(s * 8 + 2 * w) * 64 + lane];
            f16x8 a1 = Ap[(s * 8 + 2 * w + 1) * 64 + lane];
#pragma unroll
            for (int nt = 0; nt < 6; ++nt) {
                f16x8 bfr = *(const f16x8*)(&s_edgesT[(nt * 16 + l15 + 4 * s + quad) * 8]);
                acc1[0][nt] = __builtin_amdgcn_mfma_f32_16x16x32_f16(a0, bfr, acc1[0][nt], 0, 0, 0);
                acc1[1][nt] = __builtin_amdgcn_mfma_f32_16x16x32_f16(a1, bfr, acc1[1][nt], 0, 0, 0);
            }
        }
    }
#pragma unroll
    for (int m = 0; m < 2; ++m) {
        int co0 = (2 * w + m) * 16 + quad * 4;
        float ss[4] = {0.f, 0.f, 0.f, 0.f}, qq[4] = {0.f, 0.f, 0.f, 0.f};
#pragma unroll
        for (int nt = 0; nt < 6; ++nt) {
#pragma unroll
            for (int r = 0; r < 4; ++r) {
                float v = fmaxf(acc1[m][nt][r] + conv1_b[co0 + r], 0.f);
                ss[r] += v; qq[r] += v * v;
            }
        }
#pragma unroll
        for (int r = 0; r < 4; ++r) {
            float s = ss[r], q = qq[r];
            s += __shfl_xor(s, 1); s += __shfl_xor(s, 2); s += __shfl_xor(s, 4); s += __shfl_xor(s, 8);
            q += __shfl_xor(q, 1); q += __shfl_xor(q, 2); q += __shfl_xor(q, 4); q += __shfl_xor(q, 8);
            if (l15 == 0) {
                atomicAdd(&rep[co0 + r], s);
                atomicAdd(&rep[128 + co0 + r], q);
            }
        }
    }
}

// ---------------- finalize BN from 64 replicas -> scale/shift (re-zero replicas) ----------------
__global__ void k_finalize_rep(float* __restrict__ rep, float* stats, int scIdx,
                               const float* __restrict__ g, const float* __restrict__ bb,
                               float inv_count) {
    int j = threadIdx.x;
    float s = 0.f, q = 0.f;
    for (int i = 0; i < NREP; ++i) {
        s += rep[i * 256 + j];
        q += rep[i * 256 + 128 + j];
    }
    for (int i = 0; i < NREP; ++i) {
        rep[i * 256 + j] = 0.f;
        rep[i * 256 + 128 + j] = 0.f;
    }
    float m = s * inv_count;
    float v = fmaxf(q * inv_count - m * m, 0.f);
    float sc = g[j] * rsqrtf(v + EPS);
    stats[scIdx + j] = sc;
    stats[scIdx + 128 + j] = bb[j] - m * sc;
}

// ---------------- finalize BN1 + conv2 fused bias2[co] = conv2_b + sum_ci w2sum*sh ----------------
// Valid: every conv2 output t uses all 5 taps (VALID conv over 48 rows).
__global__ void k_finalize_bn1(float* __restrict__ rep, float* stats,
                               const float* __restrict__ g, const float* __restrict__ bb,
                               const float* __restrict__ w2sum, const float* __restrict__ conv2_b,
                               float inv_count) {
    __shared__ float s_sh[128];
    int j = threadIdx.x;  // 128
    float s = 0.f, q = 0.f;
    for (int i = 0; i < NREP; ++i) {
        s += rep[i * 256 + j];
        q += rep[i * 256 + 128 + j];
    }
    for (int i = 0; i < NREP; ++i) {
        rep[i * 256 + j] = 0.f;
        rep[i * 256 + 128 + j] = 0.f;
    }
    float m = s * inv_count;
    float v = fmaxf(q * inv_count - m * m, 0.f);
    float sc = g[j] * rsqrtf(v + EPS);
    float sh = bb[j] - m * sc;
    stats[S_BN1_SC + j] = sc;
    stats[S_BN1_SC + 128 + j] = sh;
    s_sh[j] = sh;
    __syncthreads();
    float acc = conv2_b[j];
    for (int ci = 0; ci < 128; ++ci)
        acc = fmaf(w2sum[j * 128 + ci], s_sh[ci], acc);
    stats[S_BIAS2 + j] = acc;
}

// ---------------- K scale: apack *= BN1 scale (per input channel), in place ----------------
__global__ __launch_bounds__(256) void k_scale(_Float16* __restrict__ apack,
                                               const float* __restrict__ stats) {
    int tid = threadIdx.x, l = tid & 63;
    int f = blockIdx.x * 4 + (tid >> 6);
    int s = (f >> 3) & 3;
    int cbase = 32 * s + (l >> 4) * 8;
    _Float16* p = apack + (f * 64 + l) * 8;
#pragma unroll
    for (int j = 0; j < 8; ++j)
        p[j] = (_Float16)((float)p[j] * stats[S_BN1_SC + cbase + j]);
}

// ---------------- K3 v5: FUSED conv1-recompute + conv2. 512 threads / 8 waves, 2 edges/block. ----------------
// [Eliminates the 300MB y2 round-trip: conv2 recomputes conv1 from 1MB L2-resident inputs
//  (24 extra MFMA vs 240, +10% matrix work) instead of reading 149MB y2pre. Phase 1 is
//  bit-identical to the old conv1 y2 path (same fragments, FP order, f16 rounding); phase 2
//  is the r2-verified thin-wave conv2 (acc[2][3], A double-buffer). Stats: BN1 stays in
//  k_conv1_stats (write-free now); BN2 epilogue identical to r2.]
__global__ __launch_bounds__(512, 4) void k_conv2(const float* __restrict__ inputs,
                                                  const int* __restrict__ sidx,
                                                  const int* __restrict__ ridx,
                                                  const _Float16* __restrict__ apack1,
                                                  const float* __restrict__ conv1_b,
                                                  _Float16* __restrict__ y23,
                                                  const _Float16* __restrict__ apack,
                                                  const float* __restrict__ stats,
                                                  float* rep2) {
    __shared__ __align__(16) _Float16 s_edgesT[2][104 * 8];
    __shared__ __align__(16) _Float16 s_y2t[2][48 * 136];
    int tid = threadIdx.x;
    long long be0 = (long long)blockIdx.x * 2;
    // stage inputs for both edges (inputs = 1MB, L2-resident across the grid)
    for (int i = tid; i < 400; i += 512) {
        int ed = i / 200, rem = i - ed * 200;
        int side = (rem >= 100) ? 1 : 0;
        int t = rem - side * 100;
        int be = (int)be0 + ed;
        int b = be / EE, e = be - b * EE;
        int n = side ? ridx[e] : sidx[e];
        float4 v = *(const float4*)(inputs + ((long long)(b * NN + n) * TT + t) * DD);
        f16x4 o = {(_Float16)v.x, (_Float16)v.y, (_Float16)v.z, (_Float16)v.w};
        *(f16x4*)(&s_edgesT[ed][t * 8 + side * 4]) = o;
    }
    if (tid < 64) s_edgesT[tid >> 5][800 + (tid & 31)] = (_Float16)0.f;
    __syncthreads();
    int w = tid >> 6, lane = tid & 63;
    int quad = lane >> 4, l15 = lane & 15;
    int w4 = w & 3, ep = w >> 2;     // 4 waves per edge (phase 1); same split reused in phase 2
    // ---- phase 1: conv1 recompute -> s_y2t[ep] (bit-identical to old y2 path; no stats here) ----
    {
        f32x4 acc1[2][6];
#pragma unroll
        for (int m = 0; m < 2; ++m)
#pragma unroll
            for (int nt = 0; nt < 6; ++nt) acc1[m][nt] = (f32x4){0.f, 0.f, 0.f, 0.f};
        const f16x8* Ap1 = (const f16x8*)apack1;
#pragma unroll
        for (int s = 0; s < 2; ++s) {
            f16x8 a0 = Ap1[(s * 8 + 2 * w4) * 64 + lane];
            f16x8 a1 = Ap1[(s * 8 + 2 * w4 + 1) * 64 + lane];
#pragma unroll
            for (int nt = 0; nt < 6; ++nt) {
                f16x8 bfr = *(const f16x8*)(&s_edgesT[ep][(nt * 16 + l15 + 4 * s + quad) * 8]);
                acc1[0][nt] = __builtin_amdgcn_mfma_f32_16x16x32_f16(a0, bfr, acc1[0][nt], 0, 0, 0);
                acc1[1][nt] = __builtin_amdgcn_mfma_f32_16x16x32_f16(a1, bfr, acc1[1][nt], 0, 0, 0);
            }
        }
#pragma unroll
        for (int m = 0; m < 2; ++m) {
            int co0 = (2 * w4 + m) * 16 + quad * 4;
#pragma unroll
            for (int nt = 0; nt < 6; ++nt) {
                int t = nt * 16 + l15;
#pragma unroll
                for (int r = 0; r < 4; ++r) {
                    float v = fmaxf(acc1[m][nt][r] + conv1_b[co0 + r], 0.f);
                    float p = __shfl_xor(v, 1);
                    if ((l15 & 1) == 0)
                        s_y2t[ep][(t >> 1) * 136 + co0 + r] = (_Float16)fmaxf(v, p);
                }
            }
        }
    }
    __syncthreads();
    // ---- phase 2: conv2 (r2-verified thin-wave shape: acc[2][3], A double-buffer) ----
    int g2 = w & 3;                  // co-group of 32 (note: different wave->role split than phase 1;
    int ep2 = w >> 2;                //  both cover all work, LDS barrier decouples them)
    const char* base = (const char*)&s_y2t[ep2][0];
    int rb0 = quad * 16 + l15 * 272;
    f32x4 acc[2][3];
#pragma unroll
    for (int m = 0; m < 2; ++m)
#pragma unroll
        for (int nt = 0; nt < 3; ++nt) acc[m][nt] = (f32x4){0.f, 0.f, 0.f, 0.f};
    const f16x8* Ap = (const f16x8*)apack;
    f16x8 amA[2], amB[2];
#pragma unroll
    for (int m = 0; m < 2; ++m) amA[m] = Ap[(g2 * 2 + m) * 64 + lane];
#define C2_STEP(AM, IT)                                                               \
    do {                                                                              \
        int k = (IT) >> 2, s = (IT) & 3;                                              \
        int rbase = k * 272 + s * 64 + rb0;                                           \
        _Pragma("unroll")                                                             \
        for (int nt = 0; nt < 3; ++nt) {                                              \
            int ro = rbase + nt * (16 * 272);                                         \
            if (nt == 2) { int rr = 32 + l15 + k; if (rr > 47) ro -= (rr - 47) * 272; } \
            f16x8 bfr = *(const f16x8*)(base + ro);                                   \
            acc[0][nt] = __builtin_amdgcn_mfma_f32_16x16x32_f16(AM[0], bfr, acc[0][nt], 0, 0, 0); \
            acc[1][nt] = __builtin_amdgcn_mfma_f32_16x16x32_f16(AM[1], bfr, acc[1][nt], 0, 0, 0); \
        }                                                                             \
    } while (0)
    for (int it = 0; it < 20; it += 2) {
#pragma unroll
        for (int m = 0; m < 2; ++m) amB[m] = Ap[((it + 1) * 8 + g2 * 2 + m) * 64 + lane];
        C2_STEP(amA, it);
        if (it + 2 < 20) {
#pragma unroll
            for (int m = 0; m < 2; ++m) amA[m] = Ap[((it + 2) * 8 + g2 * 2 + m) * 64 + lane];
        }
        C2_STEP(amB, it + 1);
    }
#undef C2_STEP
    // epilogue: bias2 + relu, store y3 t-major [44][128] (f16x4), BN2 stats
    long long be = be0 + ep2;
    _Float16* y3 = y23 + be * 6144;
    float* rep = rep2 + ((int)(be & (NREP - 1))) * 256;
#pragma unroll
    for (int m = 0; m < 2; ++m) {
        int co0 = (g2 * 2 + m) * 16 + quad * 4;
        float4 bs = *(const float4*)(stats + S_BIAS2 + co0);
        float ssum[4] = {0.f, 0.f, 0.f, 0.f}, qsum[4] = {0.f, 0.f, 0.f, 0.f};
#pragma unroll
        for (int nt = 0; nt < 3; ++nt) {
            int t = nt * 16 + l15;
            if (t < 44) {
                float v0 = fmaxf(acc[m][nt][0] + bs.x, 0.f);
                float v1 = fmaxf(acc[m][nt][1] + bs.y, 0.f);
                float v2 = fmaxf(acc[m][nt][2] + bs.z, 0.f);
                float v3 = fmaxf(acc[m][nt][3] + bs.w, 0.f);
                f16x4 o = {(_Float16)v0, (_Float16)v1, (_Float16)v2, (_Float16)v3};
                *(f16x4*)(y3 + t * 128 + co0) = o;
                ssum[0] += v0; qsum[0] += v0 * v0;
                ssum[1] += v1; qsum[1] += v1 * v1;
                ssum[2] += v2; qsum[2] += v2 * v2;
                ssum[3] += v3; qsum[3] += v3 * v3;
            }
        }
#pragma unroll
        for (int r = 0; r < 4; ++r) {
            float s = ssum[r], q = qsum[r];
            s += __shfl_xor(s, 1); s += __shfl_xor(s, 2); s += __shfl_xor(s, 4); s += __shfl_xor(s, 8);
            q += __shfl_xor(q, 1); q += __shfl_xor(q, 2); q += __shfl_xor(q, 4); q += __shfl_xor(q, 8);
            if (l15 == 0) {
                atomicAdd(&rep[co0 + r], s);
                atomicAdd(&rep[128 + co0 + r], q);
            }
        }
    }
}

// ---------------- K5: BN2 apply + attention-pool -> x [BE][128] (y3 t-major input) ----------------
__global__ __launch_bounds__(256) void k_predatt(const _Float16* __restrict__ y23,
                                                 const float* __restrict__ stats,
                                                 const float* __restrict__ att_w,
                                                 const float* __restrict__ att_b,
                                                 const float* __restrict__ pwt,
                                                 const float* __restrict__ pred_b,
                                                 float* __restrict__ x) {
    __shared__ float h[44 * 132];   // h[t][c], stride 132 (pad 4)
    __shared__ float s_att[48];
    __shared__ float s_p1[256];
    __shared__ float s_p2[256];
    __shared__ float s_sc[128], s_sh[128];
    int be = blockIdx.x, tid = threadIdx.x;
    if (tid < 128) {
        s_sc[tid] = stats[S_BN2_SC + tid];
        s_sh[tid] = stats[S_BN2_SC + 128 + tid];
    }
    __syncthreads();
    const _Float16* yp = y23 + (long long)be * 6144;
    for (int i = tid; i < 704; i += 256) {   // 44 rows x 16 chunks of 8
        int t = i >> 4, c0 = (i & 15) * 8;
        f16x8 v = *(const f16x8*)(yp + i * 8);
        float4 a, bq;
        a.x = fmaf((float)v[0], s_sc[c0 + 0], s_sh[c0 + 0]);
        a.y = fmaf((float)v[1], s_sc[c0 + 1], s_sh[c0 + 1]);
        a.z = fmaf((float)v[2], s_sc[c0 + 2], s_sh[c0 + 2]);
        a.w = fmaf((float)v[3], s_sc[c0 + 3], s_sh[c0 + 3]);
        bq.x = fmaf((float)v[4], s_sc[c0 + 4], s_sh[c0 + 4]);
        bq.y = fmaf((float)v[5], s_sc[c0 + 5], s_sh[c0 + 5]);
        bq.z = fmaf((float)v[6], s_sc[c0 + 6], s_sh[c0 + 6]);
        bq.w = fmaf((float)v[7], s_sc[c0 + 7], s_sh[c0 + 7]);
        *(float4*)(&h[t * 132 + c0]) = a;
        *(float4*)(&h[t * 132 + c0 + 4]) = bq;
    }
    __syncthreads();
    int w = tid >> 6, lane = tid & 63;
    {
        float aw0 = att_w[lane], aw1 = att_w[64 + lane];
        for (int tt = 0; tt < 11; ++tt) {
            int t = w * 11 + tt;
            float p = h[t * 132 + lane] * aw0 + h[t * 132 + 64 + lane] * aw1;
            p += __shfl_xor(p, 1); p += __shfl_xor(p, 2); p += __shfl_xor(p, 4);
            p += __shfl_xor(p, 8); p += __shfl_xor(p, 16); p += __shfl_xor(p, 32);
            if (lane == 0) s_att[t] = p + att_b[0];
        }
    }
    __syncthreads();
    if (w == 0) {
        float v = (lane < 44) ? s_att[lane] : -1e30f;
        float m = v;
        m = fmaxf(m, __shfl_xor(m, 1)); m = fmaxf(m, __shfl_xor(m, 2));
        m = fmaxf(m, __shfl_xor(m, 4)); m = fmaxf(m, __shfl_xor(m, 8));
        m = fmaxf(m, __shfl_xor(m, 16)); m = fmaxf(m, __shfl_xor(m, 32));
        float ev = (lane < 44) ? expf(v - m) : 0.f;
        float ss = ev;
        ss += __shfl_xor(ss, 1); ss += __shfl_xor(ss, 2); ss += __shfl_xor(ss, 4);
        ss += __shfl_xor(ss, 8); ss += __shfl_xor(ss, 16); ss += __shfl_xor(ss, 32);
        if (lane < 44) s_att[lane] = ev / ss;
    }
    __syncthreads();
    {
        int c = tid & 127, hh = tid >> 7;
        float a = 0.f;
        for (int t = hh * 22; t < hh * 22 + 22; ++t) a = fmaf(h[t * 132 + c], s_att[t], a);
        s_p1[tid] = a;
    }
    __syncthreads();
    {
        int o = tid & 127, hh = tid >> 7;
        float a = 0.f;
        for (int c = hh * 64; c < hh * 64 + 64; ++c) {
            float hw = s_p1[c] + s_p1[128 + c];
            a = fmaf(pwt[c * 128 + o], hw, a);
        }
        s_p2[tid] = a;
    }
    __syncthreads();
    if (tid < 128) {
        float a = s_p2[tid] + s_p2[128 + tid] + pred_b[tid];
        x[(long long)be * 128 + tid] = a * (1.0f / 44.0f);
    }
}

// ---------------- fused 2-layer MFMA MLP (128->128->128), 64 rows/block ----------------
// in f32 -> L1(ELU) kept in LDS f16 -> L2(ELU) -> out f32 + fused col stats.
__global__ __launch_bounds__(256) void k_mlp2x(const float* __restrict__ in,
                                               const _Float16* __restrict__ wp1,
                                               const float* __restrict__ b1,
                                               const _Float16* __restrict__ wp2,
                                               const float* __restrict__ b2,
                                               float* __restrict__ out,
                                               float* __restrict__ repm) {
    __shared__ __align__(16) _Float16 s_in[64 * 136];
    __shared__ __align__(16) _Float16 s_mid[64 * 136];
    int tid = threadIdx.x;
    long long r0 = (long long)blockIdx.x * 64;
    {
        const float4* src = (const float4*)(in + r0 * 128);
        for (int i = tid; i < 2048; i += 256) {
            int row = i >> 5, c0 = (i & 31) * 4;
            float4 v = src[i];
            f16x4 o = {(_Float16)v.x, (_Float16)v.y, (_Float16)v.z, (_Float16)v.w};
            *(f16x4*)(&s_in[row * 136 + c0]) = o;
        }
    }
    __syncthreads();
    int w = tid >> 6, lane = tid & 63, quad = lane >> 4, l15 = lane & 15;
    // layer 1
    {
        f32x4 acc[2][4];
#pragma unroll
        for (int m = 0; m < 2; ++m)
#pragma unroll
            for (int nt = 0; nt < 4; ++nt) acc[m][nt] = (f32x4){0.f, 0.f, 0.f, 0.f};
        const f16x8* Ap = (const f16x8*)wp1;
#pragma unroll
        for (int s = 0; s < 4; ++s) {
            f16x8 a0 = Ap[(s * 8 + 2 * w) * 64 + lane];
            f16x8 a1 = Ap[(s * 8 + 2 * w + 1) * 64 + lane];
#pragma unroll
            for (int nt = 0; nt < 4; ++nt) {
                f16x8 bfr = *(const f16x8*)((const char*)s_in + (nt * 16 + l15) * 272 + 64 * s + quad * 16);
                acc[0][nt] = __builtin_amdgcn_mfma_f32_16x16x32_f16(a0, bfr, acc[0][nt], 0, 0, 0);
                acc[1][nt] = __builtin_amdgcn_mfma_f32_16x16x32_f16(a1, bfr, acc[1][nt], 0, 0, 0);
            }
        }
#pragma unroll
        for (int m = 0; m < 2; ++m) {
            int j0 = (2 * w + m) * 16 + quad * 4;
            float4 bs = *(const float4*)(b1 + j0);
#pragma unroll
            for (int nt = 0; nt < 4; ++nt) {
                int row = nt * 16 + l15;
                f16x4 o = {(_Float16)eluf(acc[m][nt][0] + bs.x),
                           (_Float16)eluf(acc[m][nt][1] + bs.y),
                           (_Float16)eluf(acc[m][nt][2] + bs.z),
                           (_Float16)eluf(acc[m][nt][3] + bs.w)};
                *(f16x4*)(&s_mid[row * 136 + j0]) = o;
            }
        }
    }
    __syncthreads();
    // layer 2 + stats
    {
        f32x4 acc[2][4];
#pragma unroll
        for (int m = 0; m < 2; ++m)
#pragma unroll
            for (int nt = 0; nt < 4; ++nt) acc[m][nt] = (f32x4){0.f, 0.f, 0.f, 0.f};
        const f16x8* Ap = (const f16x8*)wp2;
#pragma unroll
        for (int s = 0; s < 4; ++s) {
            f16x8 a0 = Ap[(s * 8 + 2 * w) * 64 + lane];
            f16x8 a1 = Ap[(s * 8 + 2 * w + 1) * 64 + lane];
#pragma unroll
            for (int nt = 0; nt < 4; ++nt) {
                f16x8 bfr = *(const f16x8*)((const char*)s_mid + (nt * 16 + l15) * 272 + 64 * s + quad * 16);
                acc[0][nt] = __builtin_amdgcn_mfma_f32_16x16x32_f16(a0, bfr, acc[0][nt], 0, 0, 0);
                acc[1][nt] = __builtin_amdgcn_mfma_f32_16x16x32_f16(a1, bfr, acc[1][nt], 0, 0, 0);
            }
        }
#pragma unroll
        for (int m = 0; m < 2; ++m) {
            int j0 = (2 * w + m) * 16 + quad * 4;
            float4 bs = *(const float4*)(b2 + j0);
            float ss[4] = {0.f, 0.f, 0.f, 0.f}, qq[4] = {0.f, 0.f, 0.f, 0.f};
#pragma unroll
            for (int nt = 0; nt < 4; ++nt) {
                int row = nt * 16 + l15;
                float v0 = eluf(acc[m][nt][0] + bs.x);
                float v1 = eluf(acc[m][nt][1] + bs.y);
                float v2 = eluf(acc[m][nt][2] + bs.z);
                float v3 = eluf(acc[m][nt][3] + bs.w);
                float4 o = {v0, v1, v2, v3};
                *(float4*)(out + (r0 + row) * 128 + j0) = o;
                ss[0] += v0; qq[0] += v0 * v0;
                ss[1] += v1; qq[1] += v1 * v1;
                ss[2] += v2; qq[2] += v2 * v2;
                ss[3] += v3; qq[3] += v3 * v3;
            }
            float* rep = repm + (blockIdx.x & (NREP - 1)) * 256;
#pragma unroll
            for (int r = 0; r < 4; ++r) {
                float s = ss[r], q = qq[r];
                s += __shfl_xor(s, 1); s += __shfl_xor(s, 2); s += __shfl_xor(s, 4); s += __shfl_xor(s, 8);
                q += __shfl_xor(q, 1); q += __shfl_xor(q, 2); q += __shfl_xor(q, 4); q += __shfl_xor(q, 8);
                if (l15 == 0) {
                    atomicAdd(&rep[j0 + r], s);
                    atomicAdd(&rep[128 + j0 + r], q);
                }
            }
        }
    }
}

// ---------------- fused mlp3: gather-concat [send|recv|skip] (K=384) -> L1(ELU, LDS) -> L2(ELU) -> f32 + stats ----
// BN-M1/BN-M2 finalize folded in (bit-identical to k_finalize_rep: same i-order, rsqrtf).
__global__ __launch_bounds__(256) void k_mlp3x(const float* __restrict__ xn,
                                               const float* __restrict__ bufB,
                                               const int* __restrict__ sidx,
                                               const int* __restrict__ ridx,
                                               const float* __restrict__ repm1,
                                               const float* __restrict__ repm2,
                                               const float* __restrict__ m1g,
                                               const float* __restrict__ m1bb,
                                               const float* __restrict__ m2g,
                                               const float* __restrict__ m2bb,
                                               const _Float16* __restrict__ wp1,
                                               const float* __restrict__ b1,
                                               const _Float16* __restrict__ wp2,
                                               const float* __restrict__ b2,
                                               float* __restrict__ out,
                                               float* __restrict__ repm3) {
    __shared__ __align__(16) _Float16 s_b[64 * 392];
    __shared__ __align__(16) _Float16 s_mid[64 * 136];
    __shared__ float s_st[4][128];
    __shared__ int s_s[64], s_r[64];
    int tid = threadIdx.x;
    long long r0 = (long long)blockIdx.x * 64;
    if (tid < 128) {
        float s = 0.f, q = 0.f;
        for (int i = 0; i < NREP; ++i) {
            s += repm2[i * 256 + tid];
            q += repm2[i * 256 + 128 + tid];
        }
        float mm = s * (1.0f / (float)(BB * NN));
        float vv = fmaxf(q * (1.0f / (float)(BB * NN)) - mm * mm, 0.f);
        float sc = m2g[tid] * rsqrtf(vv + EPS);
        s_st[0][tid] = sc;
        s_st[1][tid] = m2bb[tid] - mm * sc;
        s = 0.f; q = 0.f;
        for (int i = 0; i < NREP; ++i) {
            s += repm1[i * 256 + tid];
            q += repm1[i * 256 + 128 + tid];
        }
        mm = s * (1.0f / (float)BE);
        vv = fmaxf(q * (1.0f / (float)BE) - mm * mm, 0.f);
        sc = m1g[tid] * rsqrtf(vv + EPS);
        s_st[2][tid] = sc;
        s_st[3][tid] = m1bb[tid] - mm * sc;
    }
    if (tid < 64) {
        int r = (int)r0 + tid, b = r / EE, ed = r - b * EE;
        s_s[tid] = (b * NN + sidx[ed]) * 128;
        s_r[tid] = (b * NN + ridx[ed]) * 128;
    }
    __syncthreads();
    for (int i = tid; i < 8192; i += 256) {
        int row = i >> 7, j = i & 127;
        float sc2 = s_st[0][j], sh2 = s_st[1][j];
        s_b[row * 392 + j] = (_Float16)fmaf(xn[s_s[row] + j], sc2, sh2);
        s_b[row * 392 + 128 + j] = (_Float16)fmaf(xn[s_r[row] + j], sc2, sh2);
        s_b[row * 392 + 256 + j] = (_Float16)fmaf(bufB[(r0 + row) * 128 + j], s_st[2][j], s_st[3][j]);
    }
    __syncthreads();
    int w = tid >> 6, lane = tid & 63, quad = lane >> 4, l15 = lane & 15;
    // layer 1 (K=384)
    {
        f32x4 acc[2][4];
#pragma unroll
        for (int m = 0; m < 2; ++m)
#pragma unroll
            for (int nt = 0; nt < 4; ++nt) acc[m][nt] = (f32x4){0.f, 0.f, 0.f, 0.f};
        const f16x8* Ap = (const f16x8*)wp1;
#pragma unroll
        for (int s = 0; s < 12; ++s) {
            f16x8 a0 = Ap[(s * 8 + 2 * w) * 64 + lane];
            f16x8 a1 = Ap[(s * 8 + 2 * w + 1) * 64 + lane];
#pragma unroll
            for (int nt = 0; nt < 4; ++nt) {
                f16x8 bfr = *(const f16x8*)((const char*)s_b + (nt * 16 + l15) * 784 + 64 * s + quad * 16);
                acc[0][nt] = __builtin_amdgcn_mfma_f32_16x16x32_f16(a0, bfr, acc[0][nt], 0, 0, 0);
                acc[1][nt] = __builtin_amdgcn_mfma_f32_16x16x32_f16(a1, bfr, acc[1][nt], 0, 0, 0);
            }
        }
#pragma unroll
        for (int m = 0; m < 2; ++m) {
            int j0 = (2 * w + m) * 16 + quad * 4;
            float4 bs = *(const float4*)(b1 + j0);
#pragma unroll
            for (int nt = 0; nt < 4; ++nt) {
                int row = nt * 16 + l15;
                f16x4 o = {(_Float16)eluf(acc[m][nt][0] + bs.x),
                           (_Float16)eluf(acc[m][nt][1] + bs.y),
                           (_Float16)eluf(acc[m][nt][2] + bs.z),
                           (_Float16)eluf(acc[m][nt][3] + bs.w)};
                *(f16x4*)(&s_mid[row * 136 + j0]) = o;
            }
        }
    }
    __syncthreads();
    // layer 2 + stats
    {
        f32x4 acc[2][4];
#pragma unroll
        for (int m = 0; m < 2; ++m)
#pragma unroll
            for (int nt = 0; nt < 4; ++nt) acc[m][nt] = (f32x4){0.f, 0.f, 0.f, 0.f};
        const f16x8* Ap = (const f16x8*)wp2;
#pragma unroll
        for (int s = 0; s < 4; ++s) {
            f16x8 a0 = Ap[(s * 8 + 2 * w) * 64 + lane];
            f16x8 a1 = Ap[(s * 8 + 2 * w + 1) * 64 + lane];
#pragma unroll
            for (int nt = 0; nt < 4; ++nt) {
                f16x8 bfr = *(const f16x8*)((const char*)s_mid + (nt * 16 + l15) * 272 + 64 * s + quad * 16);
                acc[0][nt] = __builtin_amdgcn_mfma_f32_16x16x32_f16(a0, bfr, acc[0][nt], 0, 0, 0);
                acc[1][nt] = __builtin_amdgcn_mfma_f32_16x16x32_f16(a1, bfr, acc[1][nt], 0, 0, 0);
            }
        }
#pragma unroll
        for (int m = 0; m < 2; ++m) {
            int j0 = (2 * w + m) * 16 + quad * 4;
            float4 bs = *(const float4*)(b2 + j0);
            float ss[4] = {0.f, 0.f, 0.f, 0.f}, qq[4] = {0.f, 0.f, 0.f, 0.f};
#pragma unroll
            for (int nt = 0; nt < 4; ++nt) {
                int row = nt * 16 + l15;
                float v0 = eluf(acc[m][nt][0] + bs.x);
                float v1 = eluf(acc[m][nt][1] + bs.y);
                float v2 = eluf(acc[m][nt][2] + bs.z);
                float v3 = eluf(acc[m][nt][3] + bs.w);
                float4 o = {v0, v1, v2, v3};
                *(float4*)(out + (r0 + row) * 128 + j0) = o;
                ss[0] += v0; qq[0] += v0 * v0;
                ss[1] += v1; qq[1] += v1 * v1;
                ss[2] += v2; qq[2] += v2 * v2;
                ss[3] += v3; qq[3] += v3 * v3;
            }
            float* rep = repm3 + (blockIdx.x & (NREP - 1)) * 256;
#pragma unroll
            for (int r = 0; r < 4; ++r) {
                float s = ss[r], q = qq[r];
                s += __shfl_xor(s, 1); s += __shfl_xor(s, 2); s += __shfl_xor(s, 4); s += __shfl_xor(s, 8);
                q += __shfl_xor(q, 1); q += __shfl_xor(q, 2); q += __shfl_xor(q, 4); q += __shfl_xor(q, 8);
                if (l15 == 0) {
                    atomicAdd(&rep[j0 + r], s);
                    atomicAdd(&rep[128 + j0 + r], q);
                }
            }
        }
    }
}

// ---------------- edge2node scatter-mean with inline BN-M1 (finalize folded, bit-identical) ----------------
__global__ __launch_bounds__(128) void k_e2n(const float* __restrict__ bufB,
                                             const int* __restrict__ inc,
                                             const float* __restrict__ repm1,
                                             const float* __restrict__ m1g,
                                             const float* __restrict__ m1bb,
                                             float* __restrict__ xn) {
    int bn = blockIdx.x;
    int b = bn / NN, n = bn - b * NN;
    int j = threadIdx.x;
    float s0 = 0.f, q0 = 0.f;
    for (int i = 0; i < NREP; ++i) {
        s0 += repm1[i * 256 + j];
        q0 += repm1[i * 256 + 128 + j];
    }
    float mm = s0 * (1.0f / (float)BE);
    float vv = fmaxf(q0 * (1.0f / (float)BE) - mm * mm, 0.f);
    float sc = m1g[j] * rsqrtf(vv + EPS);
    float sh = m1bb[j] - mm * sc;
    float s = 0.f;
    for (int k = 0; k < NN - 1; ++k) {
        int e = inc[n * (NN - 1) + k];
        s += bufB[(long long)(b * EE + e) * 128 + j];
    }
    xn[bn * 128 + j] = (s * sc + (float)(NN - 1) * sh) * (1.0f / (float)NN);
}

// ---------------- BN3 apply + fc_out (128 -> 16); BN-M3 finalize folded (bit-identical) ----------------
__global__ __launch_bounds__(256) void k_fcout(const float* __restrict__ h2,
                                               const float* __restrict__ repm3,
                                               const float* __restrict__ m3g,
                                               const float* __restrict__ m3bb,
                                               const float* __restrict__ fcw,
                                               const float* __restrict__ fcb,
                                               float* __restrict__ out) {
    __shared__ float s_x[16 * 129];
    __shared__ float s_w[16 * 129];
    __shared__ float s_sc[128], s_sh[128];
    int r0 = blockIdx.x * 16;
    int tid = threadIdx.x;
    if (tid < 128) {
        float s = 0.f, q = 0.f;
        for (int i = 0; i < NREP; ++i) {
            s += repm3[i * 256 + tid];
            q += repm3[i * 256 + 128 + tid];
        }
        float mm = s * (1.0f / (float)BE);
        float vv = fmaxf(q * (1.0f / (float)BE) - mm * mm, 0.f);
        float sc = m3g[tid] * rsqrtf(vv + EPS);
        s_sc[tid] = sc;
        s_sh[tid] = m3bb[tid] - mm * sc;
    }
    __syncthreads();
    for (int i = tid; i < 16 * 128; i += 256) {
        int rr = i >> 7, j = i & 127;
        s_x[rr * 129 + j] = fmaf(h2[(long long)(r0 + rr) * 128 + j], s_sc[j], s_sh[j]);
    }
    for (int i = tid; i < 16 * 128; i += 256) {
        int o = i >> 7, j = i & 127;
        s_w[o * 129 + j] = fcw[i];
    }
    __syncthreads();
    int rl = tid >> 4, o = tid & 15;
    float a = fcb[o];
    for (int j = 0; j < 128; ++j) a = fmaf(s_x[rl * 129 + j], s_w[o * 129 + j], a);
    out[(long long)(r0 + rl) * 16 + o] = a;
}

// ---------------- host launcher ----------------
extern "C" void kernel_launch(void* const* d_in, const int* in_sizes, int n_in,
                              void* d_out, int out_size, void* d_ws, size_t ws_size,
                              hipStream_t stream) {
    const float* inputs = (const float*)d_in[0];
    const float* rel_rec = (const float*)d_in[1];
    const float* rel_send = (const float*)d_in[2];
    const float* conv1_w = (const float*)d_in[3];
    const float* conv1_b = (const float*)d_in[4];
    const float* bn1_g = (const float*)d_in[5];
    const float* bn1_b = (const float*)d_in[6];
    const float* conv2_w = (const float*)d_in[7];
    const float* conv2_b = (const float*)d_in[8];
    const float* bn2_g = (const float*)d_in[9];
    const float* bn2_b = (const float*)d_in[10];
    const float* pred_w = (const float*)d_in[11];
    const float* pred_b = (const float*)d_in[12];
    const float* att_w = (const float*)d_in[13];
    const float* att_b = (const float*)d_in[14];
    const float* m1w1 = (const float*)d_in[15];
    const float* m1b1 = (const float*)d_in[16];
    const float* m1w2 = (const float*)d_in[17];
    const float* m1b2 = (const float*)d_in[18];
    const float* m1g = (const float*)d_in[19];
    const float* m1bb = (const float*)d_in[20];
    const float* m2w1 = (const float*)d_in[21];
    const float* m2b1 = (const float*)d_in[22];
    const float* m2w2 = (const float*)d_in[23];
    const float* m2b2 = (const float*)d_in[24];
    const float* m2g = (const float*)d_in[25];
    const float* m2bb = (const float*)d_in[26];
    const float* m3w1 = (const float*)d_in[27];
    const float* m3b1 = (const float*)d_in[28];
    const float* m3w2 = (const float*)d_in[29];
    const float* m3b2 = (const float*)d_in[30];
    const float* m3g = (const float*)d_in[31];
    const float* m3bb = (const float*)d_in[32];
    const float* fcw = (const float*)d_in[33];
    const float* fcb = (const float*)d_in[34];

    char* ws = (char*)d_ws;
    float* stats = (float*)(ws + OFF_STATS);
    int* sidx = (int*)(ws + OFF_SIDX);
    int* ridx = (int*)(ws + OFF_RIDX);
    int* inc = (int*)(ws + OFF_INC);
    _Float16* y23 = (_Float16*)(ws + OFF_Y23);
    float* x = (float*)(ws + OFF_X);
    float* bufB = (float*)(ws + OFF_BUFB);
    float* xn = (float*)(ws + OFF_XN);
    _Float16* apack = (_Float16*)(ws + OFF_APACK);
    _Float16* apack1 = (_Float16*)(ws + OFF_APACK1);
    float* pwt = (float*)(ws + OFF_PWT);
    float* w2sum = (float*)(ws + OFF_W2SUM);
    float* rep1 = (float*)(ws + OFF_REP1);
    float* rep2 = (float*)(ws + OFF_REP2);
    float* repm1 = (float*)(ws + OFF_REPM);
    float* repm2 = (float*)(ws + OFF_REPM + 65536ULL);
    float* repm3 = (float*)(ws + OFF_REPM + 131072ULL);
    _Float16* mp = (_Float16*)(ws + OFF_MP);
    float* outp = (float*)d_out;

    hipLaunchKernelGGL(k_prep, dim3(125), dim3(256), 0, stream,
                       rel_rec, rel_send, conv2_w, conv1_w, pred_w,
                       m1w1, m1w2, m2w1, m2w2, m3w1, m3w2,
                       apack, apack1, pwt, w2sum, mp, rep1, rep2, repm1, sidx, ridx, inc);
    // conv1 stats only (no y2 write)
    hipLaunchKernelGGL(k_conv1_stats, dim3(BE), dim3(256), 0, stream,
                       inputs, apack1, conv1_b, sidx, ridx, rep1);
    hipLaunchKernelGGL(k_finalize_bn1, dim3(1), dim3(128), 0, stream,
                       rep1, stats, bn1_g, bn1_b, w2sum, conv2_b, 1.0f / (float)(BE * L1));
    hipLaunchKernelGGL(k_scale, dim3(40), dim3(256), 0, stream, apack, stats);
    // fused conv1-recompute + conv2 (y2 never touches global memory)
    hipLaunchKernelGGL(k_conv2, dim3(BE / 2), dim3(512), 0, stream,
                       inputs, sidx, ridx, apack1, conv1_b, y23, apack, stats, rep2);
    hipLaunchKernelGGL(k_finalize_rep, dim3(1), dim3(128), 0, stream,
                       rep2, stats, S_BN2_SC, bn2_g, bn2_b, 1.0f / (float)(BE * L2));
    hipLaunchKernelGGL(k_predatt, dim3(BE), dim3(256), 0, stream,
                       y23, stats, att_w, att_b, pwt, pred_b, x);
    // mlp1 (fused 2-layer MFMA) -> stats into repm1 (finalize folded into consumers)
    hipLaunchKernelGGL(k_mlp2x, dim3(BE / 64), dim3(256), 0, stream,
                       x, mp + MP_M1W1, m1b1, mp + MP_M1W2, m1b2, bufB, repm1);
    // edge2node (BN-M1 inline, finalize folded) + mlp2 (fused) -> stats into repm2
    hipLaunchKernelGGL(k_e2n, dim3(BB * NN), dim3(128), 0, stream, bufB, inc, repm1, m1g, m1bb, xn);
    hipLaunchKernelGGL(k_mlp2x, dim3(BB * NN / 64), dim3(256), 0, stream,
                       xn, mp + MP_M2W1, m2b1, mp + MP_M2W2, m2b2, xn, repm2);
    // node2edge + mlp3 (fused gather + 2-layer; BN-M1/M2 finalize folded) -> stats into repm3
    hipLaunchKernelGGL(k_mlp3x, dim3(BE / 64), dim3(256), 0, stream,
                       xn, bufB, sidx, ridx, repm1, repm2, m1g, m1bb, m2g, m2bb,
                       mp + MP_M3W1, m3b1, mp + MP_M3W2, m3b2, bufB, repm3);
    // fc_out (BN-M3 inline, finalize folded)
    hipLaunchKernelGGL(k_fcout, dim3(BE / 16), dim3(256), 0, stream,
                       bufB, repm3, m3g, m3bb, fcw, fcb, outp);
    (void)in_sizes; (void)n_in; (void)out_size; (void)ws_size;
}

// Round 9
// 558.617 us; speedup vs baseline: 1.1095x; 1.0152x over previous
//
#include <hip/hip_runtime.h>
#include <hip/hip_bf16.h>
#include <hip/hip_fp16.h>

// ---------------- problem constants ----------------
#define BB 32
#define NN 20
#define TT 100
#define DD 4
#define HH 128
#define EE 380          // N*(N-1)
#define BE 12160        // B*E
#define L1 96           // conv1 out length
#define LP 48           // after maxpool
#define L2 44           // conv2 out length
#define NOUT 16
#define EPS 1e-5f
#define NREP 64         // stats replicas (atomic de-contention)

typedef _Float16 f16x8 __attribute__((ext_vector_type(8)));
typedef _Float16 f16x4 __attribute__((ext_vector_type(4)));
typedef _Float16 f16x2 __attribute__((ext_vector_type(2)));
typedef float f32x4 __attribute__((ext_vector_type(4)));

// stats slot indices (floats): SC at base, SH at base+128. Slots 0..127 = conv2 bias2 (BN1-fold).
#define S_BIAS2 0
#define S_BN1_SC 256
#define S_BN2_SC 768

// workspace offsets (bytes)
#define OFF_STATS 0ULL
#define OFF_SIDX 16384ULL
#define OFF_RIDX 18432ULL
#define OFF_INC 20480ULL
#define OFF_Y23 24576ULL                     // f16 [BE] slots of 6144: y3 t-major [44][128] (y2 not materialized)
#define OFF_X 149446656ULL                   // f32 [BE][128]
#define OFF_BUFA 155672576ULL                // f32 [BE][128]; rep1/rep2 live here during conv phase
#define OFF_BUFB 161898496ULL                // f32 [BE][128]
#define OFF_XN 168124416ULL                  // f32 [640][128]
#define OFF_T640 168452096ULL                // conv-phase: apack(160K)+apack1(16K)+pwt(64K)+w2sum(64K)
#define OFF_REPM 168779776ULL                // f32 3x[64][256] MLP stats replicas (repm1/repm2/repm3)
#define OFF_MP 171958272ULL                  // f16 MLP weight packs (256 KB)
#define OFF_APACK OFF_T640
#define OFF_APACK1 (OFF_T640 + 163840ULL)
#define OFF_PWT (OFF_T640 + 180224ULL)
#define OFF_W2SUM (OFF_T640 + 245760ULL)
#define OFF_REP1 OFF_BUFA
#define OFF_REP2 (OFF_BUFA + 65536ULL)
// MP pack offsets in f16 units
#define MP_M1W1 0
#define MP_M1W2 16384
#define MP_M2W1 32768
#define MP_M2W2 49152
#define MP_M3W2 65536
#define MP_M3W1 81920

__device__ __forceinline__ float eluf(float v) { return v > 0.f ? v : expm1f(v); }

// ---------------- K prep: pack all MFMA weights, transpose pred_w, w2 tap-sums, init tables ----------------
// conv1 A-pack K-order c' = k*8 + ci (direct-from-time-major B, no im2col).
__global__ __launch_bounds__(256) void k_prep(const float* __restrict__ rel_rec,
                                              const float* __restrict__ rel_send,
                                              const float* __restrict__ w2,
                                              const float* __restrict__ w1,
                                              const float* __restrict__ pred_w,
                                              const float* __restrict__ m1w1,
                                              const float* __restrict__ m1w2,
                                              const float* __restrict__ m2w1,
                                              const float* __restrict__ m2w2,
                                              const float* __restrict__ m3w1,
                                              const float* __restrict__ m3w2,
                                              _Float16* __restrict__ apack,
                                              _Float16* __restrict__ apack1,
                                              float* __restrict__ pwt,
                                              float* __restrict__ w2sum,
                                              _Float16* __restrict__ mp,
                                              float* rep1, float* rep2, float* repm,
                                              int* sidx, int* ridx, int* inc) {
    int b = blockIdx.x;
    int tid = threadIdx.x;
    int l = tid & 63;
    if (b < 40) {            // conv2_w frags (raw; BN1 scale applied later by k_scale)
        int f = b * 4 + (tid >> 6);
        int m0 = f & 7, ks = f >> 3, s = ks & 3, k = ks >> 2;
        int m = m0 * 16 + (l & 15);
        int cbase = 32 * s + (l >> 4) * 8;
#pragma unroll
        for (int j = 0; j < 8; ++j)
            apack[(f * 64 + l) * 8 + j] = (_Float16)w2[m * 640 + (cbase + j) * 5 + k];
    } else if (b < 44) {     // conv1_w frags: c' = k*8+ci, taps k>=5 zero-padded
        int f = (b - 40) * 4 + (tid >> 6);
        int m0 = f & 7, s = f >> 3;
        int m = m0 * 16 + (l & 15);
        int cbase = 32 * s + (l >> 4) * 8;
#pragma unroll
        for (int j = 0; j < 8; ++j) {
            int c = cbase + j;
            int k = c >> 3, ci = c & 7;
            apack1[(f * 64 + l) * 8 + j] = (k < 5) ? (_Float16)w1[m * 40 + ci * 5 + k]
                                                   : (_Float16)0.f;
        }
    } else if (b == 44) {    // init: zero replicas (incl. 3 MLP replica sets), build edge tables
        for (int i = tid; i < NREP * 256; i += 256) { rep1[i] = 0.f; rep2[i] = 0.f; }
        for (int i = tid; i < 3 * NREP * 256; i += 256) repm[i] = 0.f;
        for (int e = tid; e < EE; e += 256) {
            int s = 0, r = 0;
            for (int n = 0; n < NN; ++n) {
                if (rel_send[e * NN + n] > 0.5f) s = n;
                if (rel_rec[e * NN + n] > 0.5f) r = n;
            }
            sidx[e] = s; ridx[e] = r;
        }
        __syncthreads();
        if (tid < NN) {
            int k = 0;
            for (int e = 0; e < EE; ++e)
                if (ridx[e] == tid) inc[tid * (NN - 1) + (k++)] = e;
        }
    } else if (b < 53) {     // transpose pred_w -> pwt[c][o]
        int idx = (b - 45) * 2048 + tid;
        for (int rep = 0; rep < 8; ++rep, idx += 256) {
            int o = idx >> 7, c = idx & 127;
            pwt[c * 128 + o] = pred_w[idx];
        }
    } else if (b < 117) {    // MLP weight packs: generic [128][K] -> A-frag-linear
        int idx = b - 53;    // 0..63
        const float* W; _Float16* dst; int K;
        if (idx < 8)       { W = m1w1; dst = mp + MP_M1W1; K = 128; }
        else if (idx < 16) { W = m1w2; dst = mp + MP_M1W2; K = 128; idx -= 8; }
        else if (idx < 24) { W = m2w1; dst = mp + MP_M2W1; K = 128; idx -= 16; }
        else if (idx < 32) { W = m2w2; dst = mp + MP_M2W2; K = 128; idx -= 24; }
        else if (idx < 40) { W = m3w2; dst = mp + MP_M3W2; K = 128; idx -= 32; }
        else               { W = m3w1; dst = mp + MP_M3W1; K = 384; idx -= 40; }
        int f = idx * 4 + (tid >> 6);
        int s = f >> 3, m0 = f & 7;
        int m = m0 * 16 + (l & 15);
        int cb = 32 * s + (l >> 4) * 8;
#pragma unroll
        for (int j = 0; j < 8; ++j)
            dst[(f * 64 + l) * 8 + j] = (_Float16)W[m * K + cb + j];
    } else {                 // w2 tap-sums: w2sum[co][ci] = sum_k w2[co][ci][k]
        int idx = (b - 117) * 2048 + tid;
        for (int rep = 0; rep < 8; ++rep, idx += 256) {
            const float* wr = w2 + idx * 5;
            w2sum[idx] = wr[0] + wr[1] + wr[2] + wr[3] + wr[4];
        }
    }
}

// ---------------- K1: conv1 (MFMA) + relu -> BN1 stats ONLY (y2 never written to global). ----------------
__global__ __launch_bounds__(256) void k_conv1_stats(const float* __restrict__ inputs,
                                                     const _Float16* __restrict__ apack1,
                                                     const float* __restrict__ conv1_b,
                                                     const int* __restrict__ sidx,
                                                     const int* __restrict__ ridx,
                                                     float* rep1) {
    __shared__ __align__(16) _Float16 s_edgesT[104 * 8];
    int be = blockIdx.x;
    int b = be / EE, e = be - b * EE;
    int sn = sidx[e], rn = ridx[e];
    float* rep = rep1 + (be & (NREP - 1)) * 256;
    for (int i = threadIdx.x; i < 200; i += 256) {
        int side = (i >= 100) ? 1 : 0;
        int t = i - side * 100;
        int n = side ? rn : sn;
        float4 v = *(const float4*)(inputs + ((long long)(b * NN + n) * TT + t) * DD);
        f16x4 o = {(_Float16)v.x, (_Float16)v.y, (_Float16)v.z, (_Float16)v.w};
        *(f16x4*)(&s_edgesT[t * 8 + side * 4]) = o;
    }
    if (threadIdx.x < 32) s_edgesT[800 + threadIdx.x] = (_Float16)0.f;
    __syncthreads();
    int w = threadIdx.x >> 6, lane = threadIdx.x & 63;
    int quad = lane >> 4, l15 = lane & 15;
    f32x4 acc1[2][6];
#pragma unroll
    for (int m = 0; m < 2; ++m)
#pragma unroll
        for (int nt = 0; nt < 6; ++nt) acc1[m][nt] = (f32x4){0.f, 0.f, 0.f, 0.f};
    {
        const f16x8* Ap = (const f16x8*)apack1;
#pragma unroll
        for (int s = 0; s < 2; ++s) {
            f16x8 a0 = Ap[(s * 8 + 2 * w) * 64 + lane];
            f16x8 a1 = Ap[(s * 8 + 2 * w + 1) * 64 + lane];
#pragma unroll
            for (int nt = 0; nt < 6; ++nt) {
                f16x8 bfr = *(const f16x8*)(&s_edgesT[(nt * 16 + l15 + 4 * s + quad) * 8]);
                acc1[0][nt] = __builtin_amdgcn_mfma_f32_16x16x32_f16(a0, bfr, acc1[0][nt], 0, 0, 0);
                acc1[1][nt] = __builtin_amdgcn_mfma_f32_16x16x32_f16(a1, bfr, acc1[1][nt], 0, 0, 0);
            }
        }
    }
#pragma unroll
    for (int m = 0; m < 2; ++m) {
        int co0 = (2 * w + m) * 16 + quad * 4;
        float ss[4] = {0.f, 0.f, 0.f, 0.f}, qq[4] = {0.f, 0.f, 0.f, 0.f};
#pragma unroll
        for (int nt = 0; nt < 6; ++nt) {
#pragma unroll
            for (int r = 0; r < 4; ++r) {
                float v = fmaxf(acc1[m][nt][r] + conv1_b[co0 + r], 0.f);
                ss[r] += v; qq[r] += v * v;
            }
        }
#pragma unroll
        for (int r = 0; r < 4; ++r) {
            float s = ss[r], q = qq[r];
            s += __shfl_xor(s, 1); s += __shfl_xor(s, 2); s += __shfl_xor(s, 4); s += __shfl_xor(s, 8);
            q += __shfl_xor(q, 1); q += __shfl_xor(q, 2); q += __shfl_xor(q, 4); q += __shfl_xor(q, 8);
            if (l15 == 0) {
                atomicAdd(&rep[co0 + r], s);
                atomicAdd(&rep[128 + co0 + r], q);
            }
        }
    }
}

// ---------------- finalize BN from 64 replicas -> scale/shift (re-zero replicas) ----------------
__global__ void k_finalize_rep(float* __restrict__ rep, float* stats, int scIdx,
                               const float* __restrict__ g, const float* __restrict__ bb,
                               float inv_count) {
    int j = threadIdx.x;
    float s = 0.f, q = 0.f;
    for (int i = 0; i < NREP; ++i) {
        s += rep[i * 256 + j];
        q += rep[i * 256 + 128 + j];
    }
    for (int i = 0; i < NREP; ++i) {
        rep[i * 256 + j] = 0.f;
        rep[i * 256 + 128 + j] = 0.f;
    }
    float m = s * inv_count;
    float v = fmaxf(q * inv_count - m * m, 0.f);
    float sc = g[j] * rsqrtf(v + EPS);
    stats[scIdx + j] = sc;
    stats[scIdx + 128 + j] = bb[j] - m * sc;
}

// ---------------- finalize BN1 + conv2 fused bias2[co] = conv2_b + sum_ci w2sum*sh ----------------
__global__ void k_finalize_bn1(float* __restrict__ rep, float* stats,
                               const float* __restrict__ g, const float* __restrict__ bb,
                               const float* __restrict__ w2sum, const float* __restrict__ conv2_b,
                               float inv_count) {
    __shared__ float s_sh[128];
    int j = threadIdx.x;  // 128
    float s = 0.f, q = 0.f;
    for (int i = 0; i < NREP; ++i) {
        s += rep[i * 256 + j];
        q += rep[i * 256 + 128 + j];
    }
    for (int i = 0; i < NREP; ++i) {
        rep[i * 256 + j] = 0.f;
        rep[i * 256 + 128 + j] = 0.f;
    }
    float m = s * inv_count;
    float v = fmaxf(q * inv_count - m * m, 0.f);
    float sc = g[j] * rsqrtf(v + EPS);
    float sh = bb[j] - m * sc;
    stats[S_BN1_SC + j] = sc;
    stats[S_BN1_SC + 128 + j] = sh;
    s_sh[j] = sh;
    __syncthreads();
    float acc = conv2_b[j];
    for (int ci = 0; ci < 128; ++ci)
        acc = fmaf(w2sum[j * 128 + ci], s_sh[ci], acc);
    stats[S_BIAS2 + j] = acc;
}

// ---------------- K scale: apack *= BN1 scale (per input channel), in place ----------------
__global__ __launch_bounds__(256) void k_scale(_Float16* __restrict__ apack,
                                               const float* __restrict__ stats) {
    int tid = threadIdx.x, l = tid & 63;
    int f = blockIdx.x * 4 + (tid >> 6);
    int s = (f >> 3) & 3;
    int cbase = 32 * s + (l >> 4) * 8;
    _Float16* p = apack + (f * 64 + l) * 8;
#pragma unroll
    for (int j = 0; j < 8; ++j)
        p[j] = (_Float16)((float)p[j] * stats[S_BN1_SC + cbase + j]);
}

// ---------------- K3 v6: FUSED conv1-recompute + conv2 (r8 WIN: FETCH 74MB->5MB, total -21us).
// This round: packed-f16 pooling epilogue (2 shfl + 1 f16x4 store per (m,nt) instead of
// 4 shfl + 4 scalar stores; bit-identical since f16 cast is monotone: max(f16 a, f16 b) ==
// f16(max(a,b))) + float4 bias load + launch_bounds(512,6) (VGPR 56 << 85 cap, no spill risk).
__global__ __launch_bounds__(512, 6) void k_conv2(const float* __restrict__ inputs,
                                                  const int* __restrict__ sidx,
                                                  const int* __restrict__ ridx,
                                                  const _Float16* __restrict__ apack1,
                                                  const float* __restrict__ conv1_b,
                                                  _Float16* __restrict__ y23,
                                                  const _Float16* __restrict__ apack,
                                                  const float* __restrict__ stats,
                                                  float* rep2) {
    __shared__ __align__(16) _Float16 s_edgesT[2][104 * 8];
    __shared__ __align__(16) _Float16 s_y2t[2][48 * 136];
    int tid = threadIdx.x;
    long long be0 = (long long)blockIdx.x * 2;
    // stage inputs for both edges (inputs = 1MB, L2-resident across the grid)
    for (int i = tid; i < 400; i += 512) {
        int ed = i / 200, rem = i - ed * 200;
        int side = (rem >= 100) ? 1 : 0;
        int t = rem - side * 100;
        int be = (int)be0 + ed;
        int b = be / EE, e = be - b * EE;
        int n = side ? ridx[e] : sidx[e];
        float4 v = *(const float4*)(inputs + ((long long)(b * NN + n) * TT + t) * DD);
        f16x4 o = {(_Float16)v.x, (_Float16)v.y, (_Float16)v.z, (_Float16)v.w};
        *(f16x4*)(&s_edgesT[ed][t * 8 + side * 4]) = o;
    }
    if (tid < 64) s_edgesT[tid >> 5][800 + (tid & 31)] = (_Float16)0.f;
    __syncthreads();
    int w = tid >> 6, lane = tid & 63;
    int quad = lane >> 4, l15 = lane & 15;
    int w4 = w & 3, ep = w >> 2;     // 4 waves per edge (phase 1)
    // ---- phase 1: conv1 recompute -> s_y2t[ep] (pooled, f16; bit-identical to y2 path) ----
    {
        f32x4 acc1[2][6];
#pragma unroll
        for (int m = 0; m < 2; ++m)
#pragma unroll
            for (int nt = 0; nt < 6; ++nt) acc1[m][nt] = (f32x4){0.f, 0.f, 0.f, 0.f};
        const f16x8* Ap1 = (const f16x8*)apack1;
#pragma unroll
        for (int s = 0; s < 2; ++s) {
            f16x8 a0 = Ap1[(s * 8 + 2 * w4) * 64 + lane];
            f16x8 a1 = Ap1[(s * 8 + 2 * w4 + 1) * 64 + lane];
#pragma unroll
            for (int nt = 0; nt < 6; ++nt) {
                f16x8 bfr = *(const f16x8*)(&s_edgesT[ep][(nt * 16 + l15 + 4 * s + quad) * 8]);
                acc1[0][nt] = __builtin_amdgcn_mfma_f32_16x16x32_f16(a0, bfr, acc1[0][nt], 0, 0, 0);
                acc1[1][nt] = __builtin_amdgcn_mfma_f32_16x16x32_f16(a1, bfr, acc1[1][nt], 0, 0, 0);
            }
        }
#pragma unroll
        for (int m = 0; m < 2; ++m) {
            int co0 = (2 * w4 + m) * 16 + quad * 4;
            float4 bv = *(const float4*)(conv1_b + co0);
#pragma unroll
            for (int nt = 0; nt < 6; ++nt) {
                int t = nt * 16 + l15;
                f16x2 lo = {(_Float16)fmaxf(acc1[m][nt][0] + bv.x, 0.f),
                            (_Float16)fmaxf(acc1[m][nt][1] + bv.y, 0.f)};
                f16x2 hi = {(_Float16)fmaxf(acc1[m][nt][2] + bv.z, 0.f),
                            (_Float16)fmaxf(acc1[m][nt][3] + bv.w, 0.f)};
                int ilo = __builtin_bit_cast(int, lo);
                int ihi = __builtin_bit_cast(int, hi);
                int plo = __shfl_xor(ilo, 1);
                int phi = __shfl_xor(ihi, 1);
                if ((l15 & 1) == 0) {
                    f16x2 qlo = __builtin_bit_cast(f16x2, plo);
                    f16x2 qhi = __builtin_bit_cast(f16x2, phi);
                    f16x4 o = {lo[0] > qlo[0] ? lo[0] : qlo[0],
                               lo[1] > qlo[1] ? lo[1] : qlo[1],
                               hi[0] > qhi[0] ? hi[0] : qhi[0],
                               hi[1] > qhi[1] ? hi[1] : qhi[1]};
                    *(f16x4*)(&s_y2t[ep][(t >> 1) * 136 + co0]) = o;
                }
            }
        }
    }
    __syncthreads();
    // ---- phase 2: conv2 (r2-verified thin-wave shape: acc[2][3], A double-buffer) ----
    int g2 = w & 3;
    int ep2 = w >> 2;
    const char* base = (const char*)&s_y2t[ep2][0];
    int rb0 = quad * 16 + l15 * 272;
    f32x4 acc[2][3];
#pragma unroll
    for (int m = 0; m < 2; ++m)
#pragma unroll
        for (int nt = 0; nt < 3; ++nt) acc[m][nt] = (f32x4){0.f, 0.f, 0.f, 0.f};
    const f16x8* Ap = (const f16x8*)apack;
    f16x8 amA[2], amB[2];
#pragma unroll
    for (int m = 0; m < 2; ++m) amA[m] = Ap[(g2 * 2 + m) * 64 + lane];
#define C2_STEP(AM, IT)                                                               \
    do {                                                                              \
        int k = (IT) >> 2, s = (IT) & 3;                                              \
        int rbase = k * 272 + s * 64 + rb0;                                           \
        _Pragma("unroll")                                                             \
        for (int nt = 0; nt < 3; ++nt) {                                              \
            int ro = rbase + nt * (16 * 272);                                         \
            if (nt == 2) { int rr = 32 + l15 + k; if (rr > 47) ro -= (rr - 47) * 272; } \
            f16x8 bfr = *(const f16x8*)(base + ro);                                   \
            acc[0][nt] = __builtin_amdgcn_mfma_f32_16x16x32_f16(AM[0], bfr, acc[0][nt], 0, 0, 0); \
            acc[1][nt] = __builtin_amdgcn_mfma_f32_16x16x32_f16(AM[1], bfr, acc[1][nt], 0, 0, 0); \
        }                                                                             \
    } while (0)
    for (int it = 0; it < 20; it += 2) {
#pragma unroll
        for (int m = 0; m < 2; ++m) amB[m] = Ap[((it + 1) * 8 + g2 * 2 + m) * 64 + lane];
        C2_STEP(amA, it);
        if (it + 2 < 20) {
#pragma unroll
            for (int m = 0; m < 2; ++m) amA[m] = Ap[((it + 2) * 8 + g2 * 2 + m) * 64 + lane];
        }
        C2_STEP(amB, it + 1);
    }
#undef C2_STEP
    // epilogue: bias2 + relu, store y3 t-major [44][128] (f16x4), BN2 stats
    long long be = be0 + ep2;
    _Float16* y3 = y23 + be * 6144;
    float* rep = rep2 + ((int)(be & (NREP - 1))) * 256;
#pragma unroll
    for (int m = 0; m < 2; ++m) {
        int co0 = (g2 * 2 + m) * 16 + quad * 4;
        float4 bs = *(const float4*)(stats + S_BIAS2 + co0);
        float ssum[4] = {0.f, 0.f, 0.f, 0.f}, qsum[4] = {0.f, 0.f, 0.f, 0.f};
#pragma unroll
        for (int nt = 0; nt < 3; ++nt) {
            int t = nt * 16 + l15;
            if (t < 44) {
                float v0 = fmaxf(acc[m][nt][0] + bs.x, 0.f);
                float v1 = fmaxf(acc[m][nt][1] + bs.y, 0.f);
                float v2 = fmaxf(acc[m][nt][2] + bs.z, 0.f);
                float v3 = fmaxf(acc[m][nt][3] + bs.w, 0.f);
                f16x4 o = {(_Float16)v0, (_Float16)v1, (_Float16)v2, (_Float16)v3};
                *(f16x4*)(y3 + t * 128 + co0) = o;
                ssum[0] += v0; qsum[0] += v0 * v0;
                ssum[1] += v1; qsum[1] += v1 * v1;
                ssum[2] += v2; qsum[2] += v2 * v2;
                ssum[3] += v3; qsum[3] += v3 * v3;
            }
        }
#pragma unroll
        for (int r = 0; r < 4; ++r) {
            float s = ssum[r], q = qsum[r];
            s += __shfl_xor(s, 1); s += __shfl_xor(s, 2); s += __shfl_xor(s, 4); s += __shfl_xor(s, 8);
            q += __shfl_xor(q, 1); q += __shfl_xor(q, 2); q += __shfl_xor(q, 4); q += __shfl_xor(q, 8);
            if (l15 == 0) {
                atomicAdd(&rep[co0 + r], s);
                atomicAdd(&rep[128 + co0 + r], q);
            }
        }
    }
}

// ---------------- K5: BN2 apply + attention-pool -> x [BE][128] (y3 t-major input) ----------------
__global__ __launch_bounds__(256) void k_predatt(const _Float16* __restrict__ y23,
                                                 const float* __restrict__ stats,
                                                 const float* __restrict__ att_w,
                                                 const float* __restrict__ att_b,
                                                 const float* __restrict__ pwt,
                                                 const float* __restrict__ pred_b,
                                                 float* __restrict__ x) {
    __shared__ float h[44 * 132];   // h[t][c], stride 132 (pad 4)
    __shared__ float s_att[48];
    __shared__ float s_p1[256];
    __shared__ float s_p2[256];
    __shared__ float s_sc[128], s_sh[128];
    int be = blockIdx.x, tid = threadIdx.x;
    if (tid < 128) {
        s_sc[tid] = stats[S_BN2_SC + tid];
        s_sh[tid] = stats[S_BN2_SC + 128 + tid];
    }
    __syncthreads();
    const _Float16* yp = y23 + (long long)be * 6144;
    for (int i = tid; i < 704; i += 256) {   // 44 rows x 16 chunks of 8
        int t = i >> 4, c0 = (i & 15) * 8;
        f16x8 v = *(const f16x8*)(yp + i * 8);
        float4 a, bq;
        a.x = fmaf((float)v[0], s_sc[c0 + 0], s_sh[c0 + 0]);
        a.y = fmaf((float)v[1], s_sc[c0 + 1], s_sh[c0 + 1]);
        a.z = fmaf((float)v[2], s_sc[c0 + 2], s_sh[c0 + 2]);
        a.w = fmaf((float)v[3], s_sc[c0 + 3], s_sh[c0 + 3]);
        bq.x = fmaf((float)v[4], s_sc[c0 + 4], s_sh[c0 + 4]);
        bq.y = fmaf((float)v[5], s_sc[c0 + 5], s_sh[c0 + 5]);
        bq.z = fmaf((float)v[6], s_sc[c0 + 6], s_sh[c0 + 6]);
        bq.w = fmaf((float)v[7], s_sc[c0 + 7], s_sh[c0 + 7]);
        *(float4*)(&h[t * 132 + c0]) = a;
        *(float4*)(&h[t * 132 + c0 + 4]) = bq;
    }
    __syncthreads();
    int w = tid >> 6, lane = tid & 63;
    {
        float aw0 = att_w[lane], aw1 = att_w[64 + lane];
        for (int tt = 0; tt < 11; ++tt) {
            int t = w * 11 + tt;
            float p = h[t * 132 + lane] * aw0 + h[t * 132 + 64 + lane] * aw1;
            p += __shfl_xor(p, 1); p += __shfl_xor(p, 2); p += __shfl_xor(p, 4);
            p += __shfl_xor(p, 8); p += __shfl_xor(p, 16); p += __shfl_xor(p, 32);
            if (lane == 0) s_att[t] = p + att_b[0];
        }
    }
    __syncthreads();
    if (w == 0) {
        float v = (lane < 44) ? s_att[lane] : -1e30f;
        float m = v;
        m = fmaxf(m, __shfl_xor(m, 1)); m = fmaxf(m, __shfl_xor(m, 2));
        m = fmaxf(m, __shfl_xor(m, 4)); m = fmaxf(m, __shfl_xor(m, 8));
        m = fmaxf(m, __shfl_xor(m, 16)); m = fmaxf(m, __shfl_xor(m, 32));
        float ev = (lane < 44) ? expf(v - m) : 0.f;
        float ss = ev;
        ss += __shfl_xor(ss, 1); ss += __shfl_xor(ss, 2); ss += __shfl_xor(ss, 4);
        ss += __shfl_xor(ss, 8); ss += __shfl_xor(ss, 16); ss += __shfl_xor(ss, 32);
        if (lane < 44) s_att[lane] = ev / ss;
    }
    __syncthreads();
    {
        int c = tid & 127, hh = tid >> 7;
        float a = 0.f;
        for (int t = hh * 22; t < hh * 22 + 22; ++t) a = fmaf(h[t * 132 + c], s_att[t], a);
        s_p1[tid] = a;
    }
    __syncthreads();
    {
        int o = tid & 127, hh = tid >> 7;
        float a = 0.f;
        for (int c = hh * 64; c < hh * 64 + 64; ++c) {
            float hw = s_p1[c] + s_p1[128 + c];
            a = fmaf(pwt[c * 128 + o], hw, a);
        }
        s_p2[tid] = a;
    }
    __syncthreads();
    if (tid < 128) {
        float a = s_p2[tid] + s_p2[128 + tid] + pred_b[tid];
        x[(long long)be * 128 + tid] = a * (1.0f / 44.0f);
    }
}

// ---------------- fused 2-layer MFMA MLP (128->128->128), 64 rows/block ----------------
__global__ __launch_bounds__(256) void k_mlp2x(const float* __restrict__ in,
                                               const _Float16* __restrict__ wp1,
                                               const float* __restrict__ b1,
                                               const _Float16* __restrict__ wp2,
                                               const float* __restrict__ b2,
                                               float* __restrict__ out,
                                               float* __restrict__ repm) {
    __shared__ __align__(16) _Float16 s_in[64 * 136];
    __shared__ __align__(16) _Float16 s_mid[64 * 136];
    int tid = threadIdx.x;
    long long r0 = (long long)blockIdx.x * 64;
    {
        const float4* src = (const float4*)(in + r0 * 128);
        for (int i = tid; i < 2048; i += 256) {
            int row = i >> 5, c0 = (i & 31) * 4;
            float4 v = src[i];
            f16x4 o = {(_Float16)v.x, (_Float16)v.y, (_Float16)v.z, (_Float16)v.w};
            *(f16x4*)(&s_in[row * 136 + c0]) = o;
        }
    }
    __syncthreads();
    int w = tid >> 6, lane = tid & 63, quad = lane >> 4, l15 = lane & 15;
    // layer 1
    {
        f32x4 acc[2][4];
#pragma unroll
        for (int m = 0; m < 2; ++m)
#pragma unroll
            for (int nt = 0; nt < 4; ++nt) acc[m][nt] = (f32x4){0.f, 0.f, 0.f, 0.f};
        const f16x8* Ap = (const f16x8*)wp1;
#pragma unroll
        for (int s = 0; s < 4; ++s) {
            f16x8 a0 = Ap[(s * 8 + 2 * w) * 64 + lane];
            f16x8 a1 = Ap[(s * 8 + 2 * w + 1) * 64 + lane];
#pragma unroll
            for (int nt = 0; nt < 4; ++nt) {
                f16x8 bfr = *(const f16x8*)((const char*)s_in + (nt * 16 + l15) * 272 + 64 * s + quad * 16);
                acc[0][nt] = __builtin_amdgcn_mfma_f32_16x16x32_f16(a0, bfr, acc[0][nt], 0, 0, 0);
                acc[1][nt] = __builtin_amdgcn_mfma_f32_16x16x32_f16(a1, bfr, acc[1][nt], 0, 0, 0);
            }
        }
#pragma unroll
        for (int m = 0; m < 2; ++m) {
            int j0 = (2 * w + m) * 16 + quad * 4;
            float4 bs = *(const float4*)(b1 + j0);
#pragma unroll
            for (int nt = 0; nt < 4; ++nt) {
                int row = nt * 16 + l15;
                f16x4 o = {(_Float16)eluf(acc[m][nt][0] + bs.x),
                           (_Float16)eluf(acc[m][nt][1] + bs.y),
                           (_Float16)eluf(acc[m][nt][2] + bs.z),
                           (_Float16)eluf(acc[m][nt][3] + bs.w)};
                *(f16x4*)(&s_mid[row * 136 + j0]) = o;
            }
        }
    }
    __syncthreads();
    // layer 2 + stats
    {
        f32x4 acc[2][4];
#pragma unroll
        for (int m = 0; m < 2; ++m)
#pragma unroll
            for (int nt = 0; nt < 4; ++nt) acc[m][nt] = (f32x4){0.f, 0.f, 0.f, 0.f};
        const f16x8* Ap = (const f16x8*)wp2;
#pragma unroll
        for (int s = 0; s < 4; ++s) {
            f16x8 a0 = Ap[(s * 8 + 2 * w) * 64 + lane];
            f16x8 a1 = Ap[(s * 8 + 2 * w + 1) * 64 + lane];
#pragma unroll
            for (int nt = 0; nt < 4; ++nt) {
                f16x8 bfr = *(const f16x8*)((const char*)s_mid + (nt * 16 + l15) * 272 + 64 * s + quad * 16);
                acc[0][nt] = __builtin_amdgcn_mfma_f32_16x16x32_f16(a0, bfr, acc[0][nt], 0, 0, 0);
                acc[1][nt] = __builtin_amdgcn_mfma_f32_16x16x32_f16(a1, bfr, acc[1][nt], 0, 0, 0);
            }
        }
#pragma unroll
        for (int m = 0; m < 2; ++m) {
            int j0 = (2 * w + m) * 16 + quad * 4;
            float4 bs = *(const float4*)(b2 + j0);
            float ss[4] = {0.f, 0.f, 0.f, 0.f}, qq[4] = {0.f, 0.f, 0.f, 0.f};
#pragma unroll
            for (int nt = 0; nt < 4; ++nt) {
                int row = nt * 16 + l15;
                float v0 = eluf(acc[m][nt][0] + bs.x);
                float v1 = eluf(acc[m][nt][1] + bs.y);
                float v2 = eluf(acc[m][nt][2] + bs.z);
                float v3 = eluf(acc[m][nt][3] + bs.w);
                float4 o = {v0, v1, v2, v3};
                *(float4*)(out + (r0 + row) * 128 + j0) = o;
                ss[0] += v0; qq[0] += v0 * v0;
                ss[1] += v1; qq[1] += v1 * v1;
                ss[2] += v2; qq[2] += v2 * v2;
                ss[3] += v3; qq[3] += v3 * v3;
            }
            float* rep = repm + (blockIdx.x & (NREP - 1)) * 256;
#pragma unroll
            for (int r = 0; r < 4; ++r) {
                float s = ss[r], q = qq[r];
                s += __shfl_xor(s, 1); s += __shfl_xor(s, 2); s += __shfl_xor(s, 4); s += __shfl_xor(s, 8);
                q += __shfl_xor(q, 1); q += __shfl_xor(q, 2); q += __shfl_xor(q, 4); q += __shfl_xor(q, 8);
                if (l15 == 0) {
                    atomicAdd(&rep[j0 + r], s);
                    atomicAdd(&rep[128 + j0 + r], q);
                }
            }
        }
    }
}

// ---------------- fused mlp3: gather-concat [send|recv|skip] (K=384) -> L1(ELU, LDS) -> L2(ELU) -> f32 + stats ----
__global__ __launch_bounds__(256) void k_mlp3x(const float* __restrict__ xn,
                                               const float* __restrict__ bufB,
                                               const int* __restrict__ sidx,
                                               const int* __restrict__ ridx,
                                               const float* __restrict__ repm1,
                                               const float* __restrict__ repm2,
                                               const float* __restrict__ m1g,
                                               const float* __restrict__ m1bb,
                                               const float* __restrict__ m2g,
                                               const float* __restrict__ m2bb,
                                               const _Float16* __restrict__ wp1,
                                               const float* __restrict__ b1,
                                               const _Float16* __restrict__ wp2,
                                               const float* __restrict__ b2,
                                               float* __restrict__ out,
                                               float* __restrict__ repm3) {
    __shared__ __align__(16) _Float16 s_b[64 * 392];
    __shared__ __align__(16) _Float16 s_mid[64 * 136];
    __shared__ float s_st[4][128];
    __shared__ int s_s[64], s_r[64];
    int tid = threadIdx.x;
    long long r0 = (long long)blockIdx.x * 64;
    if (tid < 128) {
        float s = 0.f, q = 0.f;
        for (int i = 0; i < NREP; ++i) {
            s += repm2[i * 256 + tid];
            q += repm2[i * 256 + 128 + tid];
        }
        float mm = s * (1.0f / (float)(BB * NN));
        float vv = fmaxf(q * (1.0f / (float)(BB * NN)) - mm * mm, 0.f);
        float sc = m2g[tid] * rsqrtf(vv + EPS);
        s_st[0][tid] = sc;
        s_st[1][tid] = m2bb[tid] - mm * sc;
        s = 0.f; q = 0.f;
        for (int i = 0; i < NREP; ++i) {
            s += repm1[i * 256 + tid];
            q += repm1[i * 256 + 128 + tid];
        }
        mm = s * (1.0f / (float)BE);
        vv = fmaxf(q * (1.0f / (float)BE) - mm * mm, 0.f);
        sc = m1g[tid] * rsqrtf(vv + EPS);
        s_st[2][tid] = sc;
        s_st[3][tid] = m1bb[tid] - mm * sc;
    }
    if (tid < 64) {
        int r = (int)r0 + tid, b = r / EE, ed = r - b * EE;
        s_s[tid] = (b * NN + sidx[ed]) * 128;
        s_r[tid] = (b * NN + ridx[ed]) * 128;
    }
    __syncthreads();
    for (int i = tid; i < 8192; i += 256) {
        int row = i >> 7, j = i & 127;
        float sc2 = s_st[0][j], sh2 = s_st[1][j];
        s_b[row * 392 + j] = (_Float16)fmaf(xn[s_s[row] + j], sc2, sh2);
        s_b[row * 392 + 128 + j] = (_Float16)fmaf(xn[s_r[row] + j], sc2, sh2);
        s_b[row * 392 + 256 + j] = (_Float16)fmaf(bufB[(r0 + row) * 128 + j], s_st[2][j], s_st[3][j]);
    }
    __syncthreads();
    int w = tid >> 6, lane = tid & 63, quad = lane >> 4, l15 = lane & 15;
    // layer 1 (K=384)
    {
        f32x4 acc[2][4];
#pragma unroll
        for (int m = 0; m < 2; ++m)
#pragma unroll
            for (int nt = 0; nt < 4; ++nt) acc[m][nt] = (f32x4){0.f, 0.f, 0.f, 0.f};
        const f16x8* Ap = (const f16x8*)wp1;
#pragma unroll
        for (int s = 0; s < 12; ++s) {
            f16x8 a0 = Ap[(s * 8 + 2 * w) * 64 + lane];
            f16x8 a1 = Ap[(s * 8 + 2 * w + 1) * 64 + lane];
#pragma unroll
            for (int nt = 0; nt < 4; ++nt) {
                f16x8 bfr = *(const f16x8*)((const char*)s_b + (nt * 16 + l15) * 784 + 64 * s + quad * 16);
                acc[0][nt] = __builtin_amdgcn_mfma_f32_16x16x32_f16(a0, bfr, acc[0][nt], 0, 0, 0);
                acc[1][nt] = __builtin_amdgcn_mfma_f32_16x16x32_f16(a1, bfr, acc[1][nt], 0, 0, 0);
            }
        }
#pragma unroll
        for (int m = 0; m < 2; ++m) {
            int j0 = (2 * w + m) * 16 + quad * 4;
            float4 bs = *(const float4*)(b1 + j0);
#pragma unroll
            for (int nt = 0; nt < 4; ++nt) {
                int row = nt * 16 + l15;
                f16x4 o = {(_Float16)eluf(acc[m][nt][0] + bs.x),
                           (_Float16)eluf(acc[m][nt][1] + bs.y),
                           (_Float16)eluf(acc[m][nt][2] + bs.z),
                           (_Float16)eluf(acc[m][nt][3] + bs.w)};
                *(f16x4*)(&s_mid[row * 136 + j0]) = o;
            }
        }
    }
    __syncthreads();
    // layer 2 + stats
    {
        f32x4 acc[2][4];
#pragma unroll
        for (int m = 0; m < 2; ++m)
#pragma unroll
            for (int nt = 0; nt < 4; ++nt) acc[m][nt] = (f32x4){0.f, 0.f, 0.f, 0.f};
        const f16x8* Ap = (const f16x8*)wp2;
#pragma unroll
        for (int s = 0; s < 4; ++s) {
            f16x8 a0 = Ap[(s * 8 + 2 * w) * 64 + lane];
            f16x8 a1 = Ap[(s * 8 + 2 * w + 1) * 64 + lane];
#pragma unroll
            for (int nt = 0; nt < 4; ++nt) {
                f16x8 bfr = *(const f16x8*)((const char*)s_mid + (nt * 16 + l15) * 272 + 64 * s + quad * 16);
                acc[0][nt] = __builtin_amdgcn_mfma_f32_16x16x32_f16(a0, bfr, acc[0][nt], 0, 0, 0);
                acc[1][nt] = __builtin_amdgcn_mfma_f32_16x16x32_f16(a1, bfr, acc[1][nt], 0, 0, 0);
            }
        }
#pragma unroll
        for (int m = 0; m < 2; ++m) {
            int j0 = (2 * w + m) * 16 + quad * 4;
            float4 bs = *(const float4*)(b2 + j0);
            float ss[4] = {0.f, 0.f, 0.f, 0.f}, qq[4] = {0.f, 0.f, 0.f, 0.f};
#pragma unroll
            for (int nt = 0; nt < 4; ++nt) {
                int row = nt * 16 + l15;
                float v0 = eluf(acc[m][nt][0] + bs.x);
                float v1 = eluf(acc[m][nt][1] + bs.y);
                float v2 = eluf(acc[m][nt][2] + bs.z);
                float v3 = eluf(acc[m][nt][3] + bs.w);
                float4 o = {v0, v1, v2, v3};
                *(float4*)(out + (r0 + row) * 128 + j0) = o;
                ss[0] += v0; qq[0] += v0 * v0;
                ss[1] += v1; qq[1] += v1 * v1;
                ss[2] += v2; qq[2] += v2 * v2;
                ss[3] += v3; qq[3] += v3 * v3;
            }
            float* rep = repm3 + (blockIdx.x & (NREP - 1)) * 256;
#pragma unroll
            for (int r = 0; r < 4; ++r) {
                float s = ss[r], q = qq[r];
                s += __shfl_xor(s, 1); s += __shfl_xor(s, 2); s += __shfl_xor(s, 4); s += __shfl_xor(s, 8);
                q += __shfl_xor(q, 1); q += __shfl_xor(q, 2); q += __shfl_xor(q, 4); q += __shfl_xor(q, 8);
                if (l15 == 0) {
                    atomicAdd(&rep[j0 + r], s);
                    atomicAdd(&rep[128 + j0 + r], q);
                }
            }
        }
    }
}

// ---------------- edge2node scatter-mean with inline BN-M1 (finalize folded, bit-identical) ----------------
__global__ __launch_bounds__(128) void k_e2n(const float* __restrict__ bufB,
                                             const int* __restrict__ inc,
                                             const float* __restrict__ repm1,
                                             const float* __restrict__ m1g,
                                             const float* __restrict__ m1bb,
                                             float* __restrict__ xn) {
    int bn = blockIdx.x;
    int b = bn / NN, n = bn - b * NN;
    int j = threadIdx.x;
    float s0 = 0.f, q0 = 0.f;
    for (int i = 0; i < NREP; ++i) {
        s0 += repm1[i * 256 + j];
        q0 += repm1[i * 256 + 128 + j];
    }
    float mm = s0 * (1.0f / (float)BE);
    float vv = fmaxf(q0 * (1.0f / (float)BE) - mm * mm, 0.f);
    float sc = m1g[j] * rsqrtf(vv + EPS);
    float sh = m1bb[j] - mm * sc;
    float s = 0.f;
    for (int k = 0; k < NN - 1; ++k) {
        int e = inc[n * (NN - 1) + k];
        s += bufB[(long long)(b * EE + e) * 128 + j];
    }
    xn[bn * 128 + j] = (s * sc + (float)(NN - 1) * sh) * (1.0f / (float)NN);
}

// ---------------- BN3 apply + fc_out (128 -> 16); BN-M3 finalize folded (bit-identical) ----------------
__global__ __launch_bounds__(256) void k_fcout(const float* __restrict__ h2,
                                               const float* __restrict__ repm3,
                                               const float* __restrict__ m3g,
                                               const float* __restrict__ m3bb,
                                               const float* __restrict__ fcw,
                                               const float* __restrict__ fcb,
                                               float* __restrict__ out) {
    __shared__ float s_x[16 * 129];
    __shared__ float s_w[16 * 129];
    __shared__ float s_sc[128], s_sh[128];
    int r0 = blockIdx.x * 16;
    int tid = threadIdx.x;
    if (tid < 128) {
        float s = 0.f, q = 0.f;
        for (int i = 0; i < NREP; ++i) {
            s += repm3[i * 256 + tid];
            q += repm3[i * 256 + 128 + tid];
        }
        float mm = s * (1.0f / (float)BE);
        float vv = fmaxf(q * (1.0f / (float)BE) - mm * mm, 0.f);
        float sc = m3g[tid] * rsqrtf(vv + EPS);
        s_sc[tid] = sc;
        s_sh[tid] = m3bb[tid] - mm * sc;
    }
    __syncthreads();
    for (int i = tid; i < 16 * 128; i += 256) {
        int rr = i >> 7, j = i & 127;
        s_x[rr * 129 + j] = fmaf(h2[(long long)(r0 + rr) * 128 + j], s_sc[j], s_sh[j]);
    }
    for (int i = tid; i < 16 * 128; i += 256) {
        int o = i >> 7, j = i & 127;
        s_w[o * 129 + j] = fcw[i];
    }
    __syncthreads();
    int rl = tid >> 4, o = tid & 15;
    float a = fcb[o];
    for (int j = 0; j < 128; ++j) a = fmaf(s_x[rl * 129 + j], s_w[o * 129 + j], a);
    out[(long long)(r0 + rl) * 16 + o] = a;
}

// ---------------- host launcher ----------------
extern "C" void kernel_launch(void* const* d_in, const int* in_sizes, int n_in,
                              void* d_out, int out_size, void* d_ws, size_t ws_size,
                              hipStream_t stream) {
    const float* inputs = (const float*)d_in[0];
    const float* rel_rec = (const float*)d_in[1];
    const float* rel_send = (const float*)d_in[2];
    const float* conv1_w = (const float*)d_in[3];
    const float* conv1_b = (const float*)d_in[4];
    const float* bn1_g = (const float*)d_in[5];
    const float* bn1_b = (const float*)d_in[6];
    const float* conv2_w = (const float*)d_in[7];
    const float* conv2_b = (const float*)d_in[8];
    const float* bn2_g = (const float*)d_in[9];
    const float* bn2_b = (const float*)d_in[10];
    const float* pred_w = (const float*)d_in[11];
    const float* pred_b = (const float*)d_in[12];
    const float* att_w = (const float*)d_in[13];
    const float* att_b = (const float*)d_in[14];
    const float* m1w1 = (const float*)d_in[15];
    const float* m1b1 = (const float*)d_in[16];
    const float* m1w2 = (const float*)d_in[17];
    const float* m1b2 = (const float*)d_in[18];
    const float* m1g = (const float*)d_in[19];
    const float* m1bb = (const float*)d_in[20];
    const float* m2w1 = (const float*)d_in[21];
    const float* m2b1 = (const float*)d_in[22];
    const float* m2w2 = (const float*)d_in[23];
    const float* m2b2 = (const float*)d_in[24];
    const float* m2g = (const float*)d_in[25];
    const float* m2bb = (const float*)d_in[26];
    const float* m3w1 = (const float*)d_in[27];
    const float* m3b1 = (const float*)d_in[28];
    const float* m3w2 = (const float*)d_in[29];
    const float* m3b2 = (const float*)d_in[30];
    const float* m3g = (const float*)d_in[31];
    const float* m3bb = (const float*)d_in[32];
    const float* fcw = (const float*)d_in[33];
    const float* fcb = (const float*)d_in[34];

    char* ws = (char*)d_ws;
    float* stats = (float*)(ws + OFF_STATS);
    int* sidx = (int*)(ws + OFF_SIDX);
    int* ridx = (int*)(ws + OFF_RIDX);
    int* inc = (int*)(ws + OFF_INC);
    _Float16* y23 = (_Float16*)(ws + OFF_Y23);
    float* x = (float*)(ws + OFF_X);
    float* bufB = (float*)(ws + OFF_BUFB);
    float* xn = (float*)(ws + OFF_XN);
    _Float16* apack = (_Float16*)(ws + OFF_APACK);
    _Float16* apack1 = (_Float16*)(ws + OFF_APACK1);
    float* pwt = (float*)(ws + OFF_PWT);
    float* w2sum = (float*)(ws + OFF_W2SUM);
    float* rep1 = (float*)(ws + OFF_REP1);
    float* rep2 = (float*)(ws + OFF_REP2);
    float* repm1 = (float*)(ws + OFF_REPM);
    float* repm2 = (float*)(ws + OFF_REPM + 65536ULL);
    float* repm3 = (float*)(ws + OFF_REPM + 131072ULL);
    _Float16* mp = (_Float16*)(ws + OFF_MP);
    float* outp = (float*)d_out;

    hipLaunchKernelGGL(k_prep, dim3(125), dim3(256), 0, stream,
                       rel_rec, rel_send, conv2_w, conv1_w, pred_w,
                       m1w1, m1w2, m2w1, m2w2, m3w1, m3w2,
                       apack, apack1, pwt, w2sum, mp, rep1, rep2, repm1, sidx, ridx, inc);
    // conv1 stats only (no y2 write)
    hipLaunchKernelGGL(k_conv1_stats, dim3(BE), dim3(256), 0, stream,
                       inputs, apack1, conv1_b, sidx, ridx, rep1);
    hipLaunchKernelGGL(k_finalize_bn1, dim3(1), dim3(128), 0, stream,
                       rep1, stats, bn1_g, bn1_b, w2sum, conv2_b, 1.0f / (float)(BE * L1));
    hipLaunchKernelGGL(k_scale, dim3(40), dim3(256), 0, stream, apack, stats);
    // fused conv1-recompute + conv2 (y2 never touches global memory)
    hipLaunchKernelGGL(k_conv2, dim3(BE / 2), dim3(512), 0, stream,
                       inputs, sidx, ridx, apack1, conv1_b, y23, apack, stats, rep2);
    hipLaunchKernelGGL(k_finalize_rep, dim3(1), dim3(128), 0, stream,
                       rep2, stats, S_BN2_SC, bn2_g, bn2_b, 1.0f / (float)(BE * L2));
    hipLaunchKernelGGL(k_predatt, dim3(BE), dim3(256), 0, stream,
                       y23, stats, att_w, att_b, pwt, pred_b, x);
    // mlp1 (fused 2-layer MFMA) -> stats into repm1 (finalize folded into consumers)
    hipLaunchKernelGGL(k_mlp2x, dim3(BE / 64), dim3(256), 0, stream,
                       x, mp + MP_M1W1, m1b1, mp + MP_M1W2, m1b2, bufB, repm1);
    // edge2node (BN-M1 inline, finalize folded) + mlp2 (fused) -> stats into repm2
    hipLaunchKernelGGL(k_e2n, dim3(BB * NN), dim3(128), 0, stream, bufB, inc, repm1, m1g, m1bb, xn);
    hipLaunchKernelGGL(k_mlp2x, dim3(BB * NN / 64), dim3(256), 0, stream,
                       xn, mp + MP_M2W1, m2b1, mp + MP_M2W2, m2b2, xn, repm2);
    // node2edge + mlp3 (fused gather + 2-layer; BN-M1/M2 finalize folded) -> stats into repm3
    hipLaunchKernelGGL(k_mlp3x, dim3(BE / 64), dim3(256), 0, stream,
                       xn, bufB, sidx, ridx, repm1, repm2, m1g, m1bb, m2g, m2bb,
                       mp + MP_M3W1, m3b1, mp + MP_M3W2, m3b2, bufB, repm3);
    // fc_out (BN-M3 inline, finalize folded)
    hipLaunchKernelGGL(k_fcout, dim3(BE / 16), dim3(256), 0, stream,
                       bufB, repm3, m3g, m3bb, fcw, fcb, outp);
    (void)in_sizes; (void)n_in; (void)out_size; (void)ws_size;
}